// Round 1
// baseline (382.662 us; speedup 1.0000x reference)
//
#include <hip/hip_runtime.h>

// MambaLayer bidirectional selective-scan, fp32.
// Shapes: B=4, L=8192 (32*16*16), d_model=128, d_inner=256, d_state=16, dt_rank=8.
#define NB   4
#define LSEQ 8192
#define DM   128
#define DI   256
#define NS   16
#define RK   8
#define NCH  128          // chunks over L
#define LC   64           // L / NCH
#define LOG2E 1.44269504088896340736f
#define LN2f  0.69314718055994530942f

#if __has_builtin(__builtin_amdgcn_exp2f)
__device__ __forceinline__ float fexp2(float x){ return __builtin_amdgcn_exp2f(x); }
#else
__device__ __forceinline__ float fexp2(float x){ return exp2f(x); }
#endif
#if __has_builtin(__builtin_amdgcn_logf)
__device__ __forceinline__ float flog2(float x){ return __builtin_amdgcn_logf(x); }
#else
__device__ __forceinline__ float flog2(float x){ return log2f(x); }
#endif
#if __has_builtin(__builtin_amdgcn_rcpf)
__device__ __forceinline__ float frcp(float x){ return __builtin_amdgcn_rcpf(x); }
#else
__device__ __forceinline__ float frcp(float x){ return 1.f/x; }
#endif
__device__ __forceinline__ float fexpn(float x){ return fexp2(x*LOG2E); }
__device__ __forceinline__ float fsilu(float x){ return x*frcp(1.f + fexpn(-x)); }
__device__ __forceinline__ float fsoftplus(float x){
  return fmaxf(x,0.f) + flog2(1.f + fexpn(-fabsf(x)))*LN2f;
}

// ---------------------------------------------------------------------------
// K1: LN1 + in_proj GEMM. Tile: 64 rows(l) x 64 cols(of 512). Reads x [B,128,L]
// coalesced along L, LN per row in LDS, GEMM K=128 fully resident.
// ---------------------------------------------------------------------------
__global__ __launch_bounds__(256) void k_ln_inproj(
    const float* __restrict__ x, const float* __restrict__ ln1w, const float* __restrict__ ln1b,
    const float* __restrict__ wip, float* __restrict__ xi, float* __restrict__ zz)
{
  __shared__ float a_s[DM][68];    // [k=d_model][l], pad 68 for aligned float4 rows
  __shared__ float w_sT[DM][65];   // [k][col]
  __shared__ float mS[64], rS[64];
  const int tid = threadIdx.x;
  const int m0 = blockIdx.x * 64;
  const int b = m0 >> 13, l0 = m0 & (LSEQ-1);
  const int n0 = blockIdx.y * 64;
  const float* xb = x + b*DM*LSEQ;
#pragma unroll
  for (int i = 0; i < 32; ++i) {
    int idx = tid + i*256;
    int d = idx >> 6, l = idx & 63;
    a_s[d][l] = xb[d*LSEQ + l0 + l];
  }
  __syncthreads();
  {
    int p = tid & 3, l = tid >> 2;  // 4 threads per row l
    float s = 0.f, q = 0.f;
#pragma unroll
    for (int jj = 0; jj < 32; ++jj) {
      float v = a_s[p + 4*jj][l];
      s += v; q += v*v;
    }
    s += __shfl_xor(s,1); s += __shfl_xor(s,2);
    q += __shfl_xor(q,1); q += __shfl_xor(q,2);
    float m = s*(1.f/DM);
    float var = q*(1.f/DM) - m*m;
    if (p == 0) { mS[l] = m; rS[l] = rsqrtf(var + 1e-5f); }
  }
  __syncthreads();
#pragma unroll
  for (int i = 0; i < 32; ++i) {
    int idx = tid + i*256;
    int d = idx >> 6, l = idx & 63;
    a_s[d][l] = (a_s[d][l] - mS[l])*rS[l]*ln1w[d] + ln1b[d];
  }
#pragma unroll
  for (int i = 0; i < 32; ++i) {
    int idx = tid + i*256;
    int cc = idx >> 7, k = idx & 127;
    w_sT[k][cc] = wip[(n0+cc)*DM + k];
  }
  __syncthreads();
  const int ty = tid >> 4, tx = tid & 15;   // 16x16 threads, 4x4 outputs each
  float acc[4][4] = {};
  for (int k = 0; k < DM; ++k) {
    float4 a4 = *(const float4*)&a_s[k][ty*4];
    float av[4] = {a4.x, a4.y, a4.z, a4.w};
    float bv[4];
#pragma unroll
    for (int jj = 0; jj < 4; ++jj) bv[jj] = w_sT[k][tx*4+jj];
#pragma unroll
    for (int ii = 0; ii < 4; ++ii)
#pragma unroll
      for (int jj = 0; jj < 4; ++jj) acc[ii][jj] = fmaf(av[ii], bv[jj], acc[ii][jj]);
  }
#pragma unroll
  for (int ii = 0; ii < 4; ++ii) {
    int gr = m0 + ty*4 + ii;
    float4 v = make_float4(acc[ii][0], acc[ii][1], acc[ii][2], acc[ii][3]);
    if (n0 < 256) *(float4*)&xi[gr*DI + n0 + tx*4] = v;
    else          *(float4*)&zz[gr*DI + n0 - 256 + tx*4] = v;
  }
}

// ---------------------------------------------------------------------------
// K2: causal conv4 + SiLU (on the fly) + x_proj GEMM -> dt_r[8], B[16], C[16].
// Block: 64 internal rows of one (dir,b). Phase1: thread=channel computes xc
// into LDS. Phase2: lane=row, wave w owns 10 output cols, weights via uniform
// (scalar) loads.
// ---------------------------------------------------------------------------
__global__ __launch_bounds__(256) void k_conv_xproj(
  const float* __restrict__ xi,
  const float* __restrict__ cwf, const float* __restrict__ cbf,
  const float* __restrict__ cwb, const float* __restrict__ cbb,
  const float* __restrict__ xwf, const float* __restrict__ xwb,
  float* __restrict__ dtr, float* __restrict__ Bm, float* __restrict__ Cm)
{
  __shared__ float xcs[64][257];
  const int tid = threadIdx.x, bid = blockIdx.x;
  const int lt = bid & (LSEQ/64 - 1);
  const int b  = (bid >> 7) & 3;
  const int dir = bid >> 9;
  const int l0 = lt*64;
  const float* cw  = dir ? cwb : cwf;
  const float* cbp = dir ? cbb : cbf;
  const float* xw  = dir ? xwb : xwf;
  const int d = tid;
  const float w0 = cw[d*4+0], w1 = cw[d*4+1], w2 = cw[d*4+2], w3 = cw[d*4+3];
  const float bias = cbp[d];
  const int g0 = dir ? (LSEQ-1-l0) : l0;
  const int stp = dir ? -DI : DI;
  const float* xp = xi + (b*LSEQ)*DI + d + g0*DI;
  float h3 = 0.f, h2 = 0.f, h1 = 0.f;
  if (l0 >= 3) { h3 = xp[-3*stp]; h2 = xp[-2*stp]; h1 = xp[-1*stp]; }
  float r0 = xp[0], r1 = xp[stp], r2 = xp[2*stp], r3 = xp[3*stp];
  for (int j = 0; j < 64; j += 4) {
    float v0 = r0, v1 = r1, v2 = r2, v3 = r3;
    if (j + 4 < 64) {
      const float* q = xp + (j+4)*stp;
      r0 = q[0]; r1 = q[stp]; r2 = q[2*stp]; r3 = q[3*stp];
    }
    float a;
    a = bias + w0*h3 + w1*h2 + w2*h1 + w3*v0; xcs[j+0][d] = fsilu(a);
    a = bias + w0*h2 + w1*h1 + w2*v0 + w3*v1; xcs[j+1][d] = fsilu(a);
    a = bias + w0*h1 + w1*v0 + w2*v1 + w3*v2; xcs[j+2][d] = fsilu(a);
    a = bias + w0*v0 + w1*v1 + w2*v2 + w3*v3; xcs[j+3][d] = fsilu(a);
    h3 = v1; h2 = v2; h1 = v3;
  }
  __syncthreads();
  const int wv = __builtin_amdgcn_readfirstlane(tid >> 6);
  const int lane = tid & 63;
  const int t0 = wv*10;
  float acc[10] = {};
  for (int kc = 0; kc < DI; kc += 32) {
    float xcr[32];
#pragma unroll
    for (int kk = 0; kk < 32; ++kk) xcr[kk] = xcs[lane][kc+kk];
#pragma unroll
    for (int j = 0; j < 10; ++j) {
      const float* wr = xw + (t0+j)*DI + kc;
#pragma unroll
      for (int kk = 0; kk < 32; ++kk) acc[j] = fmaf(xcr[kk], wr[kk], acc[j]);
    }
  }
  const int base = (dir*NB + b)*LSEQ + l0 + lane;
#pragma unroll
  for (int j = 0; j < 10; ++j) {
    int t = t0 + j;
    if (t < 8)       dtr[base*RK + t] = acc[j];
    else if (t < 24) Bm[base*NS + t - 8] = acc[j];
    else             Cm[base*NS + t - 24] = acc[j];
  }
}

// ---------------------------------------------------------------------------
// K3: chunk-local scan (from h=0): produces h_local per chunk + sum(dt).
// Block = one (dir,b,chunk) of 64 steps; thread = channel d; 16 states in regs.
// conv+SiLU and dt=softplus(dt_r@W+b) recomputed on the fly.
// ---------------------------------------------------------------------------
__global__ __launch_bounds__(256) void k_scan_local(
  const float* __restrict__ xi, const float* __restrict__ dtr, const float* __restrict__ Bm,
  const float* __restrict__ cwf, const float* __restrict__ cbf,
  const float* __restrict__ cwb, const float* __restrict__ cbb,
  const float* __restrict__ dtwf, const float* __restrict__ dtbf,
  const float* __restrict__ dtwb, const float* __restrict__ dtbb,
  const float* __restrict__ alogf, const float* __restrict__ alogb,
  float* __restrict__ hloc, float* __restrict__ sumdt)
{
  __shared__ float Bc[LC][NS];
  __shared__ float dts[LC][RK];
  const int tid = threadIdx.x, bid = blockIdx.x;
  const int c = bid & (NCH-1), b = (bid>>7)&3, dir = bid>>9;
  const int db = dir*NB + b;
  const int l0 = c*LC;
  for (int i = tid; i < LC*NS; i += 256) (&Bc[0][0])[i]  = Bm[(db*LSEQ + l0)*NS + i];
  for (int i = tid; i < LC*RK; i += 256) (&dts[0][0])[i] = dtr[(db*LSEQ + l0)*RK + i];
  const float* cw  = dir ? cwb : cwf;
  const float* cbp = dir ? cbb : cbf;
  const float* dtw = dir ? dtwb : dtwf;
  const float* dtbp= dir ? dtbb : dtbf;
  const float* alog= dir ? alogb : alogf;
  const int d = tid;
  const float w0 = cw[d*4+0], w1 = cw[d*4+1], w2 = cw[d*4+2], w3 = cw[d*4+3];
  const float cbias = cbp[d];
  float dw[RK];
#pragma unroll
  for (int r = 0; r < RK; ++r) dw[r] = dtw[d*RK+r];
  const float dtbv = dtbp[d];
  float A2[NS];
#pragma unroll
  for (int n = 0; n < NS; ++n) A2[n] = -fexpn(alog[d*NS+n]) * LOG2E;
  float h[NS];
#pragma unroll
  for (int n = 0; n < NS; ++n) h[n] = 0.f;
  const int g0 = dir ? (LSEQ-1-l0) : l0;
  const int stp = dir ? -DI : DI;
  const float* xp = xi + (b*LSEQ)*DI + d + g0*DI;
  float h3=0.f, h2=0.f, h1=0.f;
  if (l0 >= 3) { h3 = xp[-3*stp]; h2 = xp[-2*stp]; h1 = xp[-1*stp]; }
  float r0 = xp[0], r1 = xp[stp], r2 = xp[2*stp], r3 = xp[3*stp];
  __syncthreads();
  float sac = 0.f;
  for (int j = 0; j < LC; j += 4) {
    float v0=r0, v1=r1, v2=r2, v3=r3;
    if (j + 4 < LC) { const float* q = xp + (j+4)*stp; r0=q[0]; r1=q[stp]; r2=q[2*stp]; r3=q[3*stp]; }
#pragma unroll
    for (int u = 0; u < 4; ++u) {
      float v = (u==0)?v0:(u==1)?v1:(u==2)?v2:v3;
      float a = cbias + w0*h3 + w1*h2 + w2*h1 + w3*v;
      float xc = fsilu(a);
      float dd8[RK];
      *(float4*)(dd8+0) = *(const float4*)&dts[j+u][0];
      *(float4*)(dd8+4) = *(const float4*)&dts[j+u][4];
      float sd = dtbv;
#pragma unroll
      for (int r = 0; r < RK; ++r) sd = fmaf(dw[r], dd8[r], sd);
      float dt = fsoftplus(sd);
      sac += dt;
      float dx = dt*xc;
      float bb[NS];
      *(float4*)(bb+0)  = *(const float4*)&Bc[j+u][0];
      *(float4*)(bb+4)  = *(const float4*)&Bc[j+u][4];
      *(float4*)(bb+8)  = *(const float4*)&Bc[j+u][8];
      *(float4*)(bb+12) = *(const float4*)&Bc[j+u][12];
#pragma unroll
      for (int n = 0; n < NS; ++n) {
        float e = fexp2(A2[n]*dt);
        h[n] = fmaf(h[n], e, dx*bb[n]);
      }
      h3 = h2; h2 = h1; h1 = v;
    }
  }
  const int hb = ((db*NCH + c)*DI + d)*NS;
#pragma unroll
  for (int n = 0; n < NS; ++n) hloc[hb+n] = h[n];
  sumdt[(db*NCH + c)*DI + d] = sac;
}

// ---------------------------------------------------------------------------
// K4: sequential prefix over chunks. h_in[c] = state entering chunk c.
// Composition: h' = exp(A*sum_dt[c]) * h + h_local[c]. Thread per (dir,b,d,n).
// ---------------------------------------------------------------------------
__global__ __launch_bounds__(64) void k_prefix(
  const float* __restrict__ hloc, const float* __restrict__ sumdt,
  const float* __restrict__ alogf, const float* __restrict__ alogb,
  float* __restrict__ hin)
{
  const int gid = blockIdx.x*64 + threadIdx.x;   // 32768
  const int n = gid & 15;
  const int d = (gid >> 4) & 255;
  const int db = gid >> 12;
  const float* alog = (db >= NB) ? alogb : alogf;
  const float a2 = -fexpn(alog[d*NS+n]) * LOG2E;
  float hr = 0.f;
  for (int c = 0; c < NCH; ++c) {
    int idx = ((db*NCH + c)*DI + d)*NS + n;
    hin[idx] = hr;
    float sd = sumdt[(db*NCH + c)*DI + d];
    hr = fmaf(fexp2(a2*sd), hr, hloc[idx]);
  }
}

// ---------------------------------------------------------------------------
// K5: rescan from h_in producing y, + D-skip, * SiLU(z). Writes s (internal
// row order per direction; K6 un-reverses the backward half on read).
// ---------------------------------------------------------------------------
__global__ __launch_bounds__(256) void k_scan_out(
  const float* __restrict__ xi, const float* __restrict__ zb,
  const float* __restrict__ dtr, const float* __restrict__ Bm, const float* __restrict__ Cm,
  const float* __restrict__ hin,
  const float* __restrict__ cwf, const float* __restrict__ cbf,
  const float* __restrict__ cwb, const float* __restrict__ cbb,
  const float* __restrict__ dtwf, const float* __restrict__ dtbf,
  const float* __restrict__ dtwb, const float* __restrict__ dtbb,
  const float* __restrict__ alogf, const float* __restrict__ alogb,
  const float* __restrict__ Dskf, const float* __restrict__ Dskb,
  float* __restrict__ s2)
{
  __shared__ float Bc[LC][NS];
  __shared__ float Cc[LC][NS];
  __shared__ float dts[LC][RK];
  const int tid = threadIdx.x, bid = blockIdx.x;
  const int c = bid & (NCH-1), b = (bid>>7)&3, dir = bid>>9;
  const int db = dir*NB + b;
  const int l0 = c*LC;
  for (int i = tid; i < LC*NS; i += 256) (&Bc[0][0])[i]  = Bm[(db*LSEQ + l0)*NS + i];
  for (int i = tid; i < LC*NS; i += 256) (&Cc[0][0])[i]  = Cm[(db*LSEQ + l0)*NS + i];
  for (int i = tid; i < LC*RK; i += 256) (&dts[0][0])[i] = dtr[(db*LSEQ + l0)*RK + i];
  const float* cw  = dir ? cwb : cwf;
  const float* cbp = dir ? cbb : cbf;
  const float* dtw = dir ? dtwb : dtwf;
  const float* dtbp= dir ? dtbb : dtbf;
  const float* alog= dir ? alogb : alogf;
  const int d = tid;
  const float w0 = cw[d*4+0], w1 = cw[d*4+1], w2 = cw[d*4+2], w3 = cw[d*4+3];
  const float cbias = cbp[d];
  const float Dd = (dir ? Dskb : Dskf)[d];
  float dw[RK];
#pragma unroll
  for (int r = 0; r < RK; ++r) dw[r] = dtw[d*RK+r];
  const float dtbv = dtbp[d];
  float A2[NS];
#pragma unroll
  for (int n = 0; n < NS; ++n) A2[n] = -fexpn(alog[d*NS+n]) * LOG2E;
  const int hb = ((db*NCH + c)*DI + d)*NS;
  float h[NS];
#pragma unroll
  for (int n = 0; n < NS; ++n) h[n] = hin[hb+n];
  const int g0 = dir ? (LSEQ-1-l0) : l0;
  const int stp = dir ? -DI : DI;
  const float* xp = xi + (b*LSEQ)*DI + d + g0*DI;
  const float* zp = zb + (b*LSEQ)*DI + d + g0*DI;
  float* sp = s2 + (db*LSEQ + l0)*DI + d;
  float h3=0.f, h2=0.f, h1=0.f;
  if (l0 >= 3) { h3 = xp[-3*stp]; h2 = xp[-2*stp]; h1 = xp[-1*stp]; }
  float r0 = xp[0], r1 = xp[stp], r2 = xp[2*stp], r3 = xp[3*stp];
  float z0 = zp[0], z1 = zp[stp], z2 = zp[2*stp], z3 = zp[3*stp];
  __syncthreads();
  for (int j = 0; j < LC; j += 4) {
    float v0=r0, v1=r1, v2=r2, v3=r3;
    float y0=z0, y1=z1, y2=z2, y3=z3;
    if (j + 4 < LC) {
      const float* q = xp + (j+4)*stp; r0=q[0]; r1=q[stp]; r2=q[2*stp]; r3=q[3*stp];
      const float* qz = zp + (j+4)*stp; z0=qz[0]; z1=qz[stp]; z2=qz[2*stp]; z3=qz[3*stp];
    }
#pragma unroll
    for (int u = 0; u < 4; ++u) {
      float v  = (u==0)?v0:(u==1)?v1:(u==2)?v2:v3;
      float zv = (u==0)?y0:(u==1)?y1:(u==2)?y2:y3;
      float a = cbias + w0*h3 + w1*h2 + w2*h1 + w3*v;
      float xc = fsilu(a);
      float dd8[RK];
      *(float4*)(dd8+0) = *(const float4*)&dts[j+u][0];
      *(float4*)(dd8+4) = *(const float4*)&dts[j+u][4];
      float sd = dtbv;
#pragma unroll
      for (int r = 0; r < RK; ++r) sd = fmaf(dw[r], dd8[r], sd);
      float dt = fsoftplus(sd);
      float dx = dt*xc;
      float bb[NS], ccv[NS];
      *(float4*)(bb+0)  = *(const float4*)&Bc[j+u][0];
      *(float4*)(bb+4)  = *(const float4*)&Bc[j+u][4];
      *(float4*)(bb+8)  = *(const float4*)&Bc[j+u][8];
      *(float4*)(bb+12) = *(const float4*)&Bc[j+u][12];
      *(float4*)(ccv+0)  = *(const float4*)&Cc[j+u][0];
      *(float4*)(ccv+4)  = *(const float4*)&Cc[j+u][4];
      *(float4*)(ccv+8)  = *(const float4*)&Cc[j+u][8];
      *(float4*)(ccv+12) = *(const float4*)&Cc[j+u][12];
      float yv = 0.f;
#pragma unroll
      for (int n = 0; n < NS; ++n) {
        float e = fexp2(A2[n]*dt);
        h[n] = fmaf(h[n], e, dx*bb[n]);
        yv = fmaf(h[n], ccv[n], yv);
      }
      yv = fmaf(xc, Dd, yv);
      sp[(j+u)*DI] = yv * fsilu(zv);
      h3 = h2; h2 = h1; h1 = v;
    }
  }
}

// ---------------------------------------------------------------------------
// K6: s = sF + rev(sB); out_proj GEMM (K=256); + residual x; LN2; transposed
// store to [B,128,L]. Block: 64 rows x 128 cols, 512 threads, 4x4 per thread.
// ---------------------------------------------------------------------------
__global__ __launch_bounds__(512) void k_out(
  const float* __restrict__ s2, const float* __restrict__ wop,
  const float* __restrict__ x, const float* __restrict__ ln2w, const float* __restrict__ ln2b,
  float* __restrict__ out)
{
  __shared__ float smem[64*65 + DM*65];   // 12480 floats; re-used as res[64][132]
  float (*s_s)[65] = (float(*)[65])smem;
  float (*w_s)[65] = (float(*)[65])(smem + 64*65);
  const int tid = threadIdx.x;
  const int m0 = blockIdx.x*64;
  const int b = m0 >> 13, l0 = m0 & (LSEQ-1);
  const int tx = tid & 31, ty = tid >> 5;
  const float* sF = s2 + (0*NB + b)*LSEQ*DI;
  const float* sB = s2 + (NB + b)*LSEQ*DI;
  float acc[4][4] = {};
  for (int kc = 0; kc < DI; kc += 64) {
#pragma unroll
    for (int i = 0; i < 8; ++i) {
      int idx = tid + i*512;
      int r = idx >> 6, kk = idx & 63;
      int l = l0 + r;
      s_s[r][kk] = sF[l*DI + kc + kk] + sB[(LSEQ-1-l)*DI + kc + kk];
    }
#pragma unroll
    for (int i = 0; i < 16; ++i) {
      int idx = tid + i*512;
      int nn = idx >> 6, kk = idx & 63;
      w_s[nn][kk] = wop[nn*DI + kc + kk];
    }
    __syncthreads();
    for (int kk = 0; kk < 64; ++kk) {
      float av[4], bv[4];
#pragma unroll
      for (int ii = 0; ii < 4; ++ii) av[ii] = s_s[ty*4+ii][kk];
#pragma unroll
      for (int jj = 0; jj < 4; ++jj) bv[jj] = w_s[tx*4+jj][kk];
#pragma unroll
      for (int ii = 0; ii < 4; ++ii)
#pragma unroll
        for (int jj = 0; jj < 4; ++jj) acc[ii][jj] = fmaf(av[ii], bv[jj], acc[ii][jj]);
    }
    __syncthreads();
  }
  // residual add: x[b, col, l0+row]
  const float* xb = x + b*DM*LSEQ + l0;
  float lw[4], lb[4];
#pragma unroll
  for (int jj = 0; jj < 4; ++jj) { lw[jj] = ln2w[tx*4+jj]; lb[jj] = ln2b[tx*4+jj]; }
#pragma unroll
  for (int ii = 0; ii < 4; ++ii)
#pragma unroll
    for (int jj = 0; jj < 4; ++jj)
      acc[ii][jj] += xb[(tx*4+jj)*LSEQ + ty*4 + ii];
  // LN2 per row (128 cols spread over the 32-lane tx group)
  float rm[4], rr[4];
#pragma unroll
  for (int ii = 0; ii < 4; ++ii) {
    float s = acc[ii][0]+acc[ii][1]+acc[ii][2]+acc[ii][3];
    float q = acc[ii][0]*acc[ii][0]+acc[ii][1]*acc[ii][1]+acc[ii][2]*acc[ii][2]+acc[ii][3]*acc[ii][3];
#pragma unroll
    for (int mk = 1; mk <= 16; mk <<= 1) { s += __shfl_xor(s, mk); q += __shfl_xor(q, mk); }
    float m = s*(1.f/DM);
    float var = q*(1.f/DM) - m*m;
    rm[ii] = m; rr[ii] = rsqrtf(var + 1e-5f);
  }
  float (*res)[132] = (float(*)[132])smem;
#pragma unroll
  for (int ii = 0; ii < 4; ++ii) {
    float4 v;
    v.x = (acc[ii][0]-rm[ii])*rr[ii]*lw[0] + lb[0];
    v.y = (acc[ii][1]-rm[ii])*rr[ii]*lw[1] + lb[1];
    v.z = (acc[ii][2]-rm[ii])*rr[ii]*lw[2] + lb[2];
    v.w = (acc[ii][3]-rm[ii])*rr[ii]*lw[3] + lb[3];
    *(float4*)&res[ty*4+ii][tx*4] = v;
  }
  __syncthreads();
  float* ob = out + b*DM*LSEQ + l0;
#pragma unroll
  for (int i = 0; i < 16; ++i) {
    int idx = tid + i*512;
    int col = idx >> 6, l = idx & 63;
    ob[col*LSEQ + l] = res[l][col];
  }
}

// ---------------------------------------------------------------------------
extern "C" void kernel_launch(void* const* d_in, const int* in_sizes, int n_in,
                              void* d_out, int out_size, void* d_ws, size_t ws_size,
                              hipStream_t stream)
{
  (void)in_sizes; (void)n_in; (void)out_size; (void)ws_size;
  const float* x     = (const float*)d_in[0];
  const float* ln1w  = (const float*)d_in[1];
  const float* ln1b  = (const float*)d_in[2];
  const float* ln2w  = (const float*)d_in[3];
  const float* ln2b  = (const float*)d_in[4];
  const float* wip   = (const float*)d_in[5];
  const float* wop   = (const float*)d_in[6];
  const float* cwf   = (const float*)d_in[7];
  const float* cbf   = (const float*)d_in[8];
  const float* xwf   = (const float*)d_in[9];
  const float* dtwf  = (const float*)d_in[10];
  const float* dtbf  = (const float*)d_in[11];
  const float* alogf = (const float*)d_in[12];
  const float* Dskf  = (const float*)d_in[13];
  const float* cwb   = (const float*)d_in[14];
  const float* cbb   = (const float*)d_in[15];
  const float* xwb   = (const float*)d_in[16];
  const float* dtwb  = (const float*)d_in[17];
  const float* dtbb  = (const float*)d_in[18];
  const float* alogb = (const float*)d_in[19];
  const float* Dskb  = (const float*)d_in[20];

  // workspace layout (floats); total 44,826,624 floats = ~171 MB
  float* ws    = (float*)d_ws;
  float* xi    = ws;
  float* zz    = xi   + 8388608;
  float* dtr   = zz   + 8388608;
  float* Bm    = dtr  + 524288;
  float* Cm    = Bm   + 1048576;
  float* s2    = Cm   + 1048576;
  float* hloc  = s2   + 16777216;
  float* hin   = hloc + 4194304;
  float* sumdt = hin  + 4194304;
  float* out   = (float*)d_out;

  k_ln_inproj<<<dim3(512,8), 256, 0, stream>>>(x, ln1w, ln1b, wip, xi, zz);
  k_conv_xproj<<<1024, 256, 0, stream>>>(xi, cwf,cbf,cwb,cbb, xwf,xwb, dtr, Bm, Cm);
  k_scan_local<<<1024, 256, 0, stream>>>(xi, dtr, Bm, cwf,cbf,cwb,cbb,
                                         dtwf,dtbf,dtwb,dtbb, alogf, alogb, hloc, sumdt);
  k_prefix<<<512, 64, 0, stream>>>(hloc, sumdt, alogf, alogb, hin);
  k_scan_out<<<1024, 256, 0, stream>>>(xi, zz, dtr, Bm, Cm, hin, cwf,cbf,cwb,cbb,
                                       dtwf,dtbf,dtwb,dtbb, alogf,alogb, Dskf, Dskb, s2);
  k_out<<<512, 512, 0, stream>>>(s2, wop, x, ln2w, ln2b, out);
}

// Round 3
// 297.734 us; speedup vs baseline: 1.2852x; 1.2852x over previous
//
#include <hip/hip_runtime.h>

// MambaLayer bidirectional selective-scan, fp32 (bf16-split MFMA for in_proj).
// Shapes: B=4, L=8192 (32*16*16), d_model=128, d_inner=256, d_state=16, dt_rank=8.
#define NB   4
#define LSEQ 8192
#define DM   128
#define DI   256
#define NS   16
#define RK   8
#define NCH  128          // chunks over L
#define LC   64           // L / NCH
#define MTOT (NB*LSEQ)    // 32768 rows
#define LOG2E 1.44269504088896340736f
#define LN2f  0.69314718055994530942f

#if __has_builtin(__builtin_amdgcn_exp2f)
__device__ __forceinline__ float fexp2(float x){ return __builtin_amdgcn_exp2f(x); }
#else
__device__ __forceinline__ float fexp2(float x){ return exp2f(x); }
#endif
#if __has_builtin(__builtin_amdgcn_logf)
__device__ __forceinline__ float flog2(float x){ return __builtin_amdgcn_logf(x); }
#else
__device__ __forceinline__ float flog2(float x){ return log2f(x); }
#endif
#if __has_builtin(__builtin_amdgcn_rcpf)
__device__ __forceinline__ float frcp(float x){ return __builtin_amdgcn_rcpf(x); }
#else
__device__ __forceinline__ float frcp(float x){ return 1.f/x; }
#endif
__device__ __forceinline__ float fexpn(float x){ return fexp2(x*LOG2E); }
__device__ __forceinline__ float fsilu(float x){ return x*frcp(1.f + fexpn(-x)); }
__device__ __forceinline__ float fsoftplus(float x){
  return fmaxf(x,0.f) + flog2(1.f + fexpn(-fabsf(x)))*LN2f;
}

__device__ __forceinline__ unsigned short f2bf(float v){
  unsigned int u = __float_as_uint(v);
  return (unsigned short)((u + 0x7FFFu + ((u >> 16) & 1u)) >> 16);
}
__device__ __forceinline__ float bf2f(unsigned short h){
  return __uint_as_float(((unsigned int)h) << 16);
}

typedef __attribute__((ext_vector_type(8))) short bf16x8;
typedef __attribute__((ext_vector_type(4))) float f32x4;

// ---------------------------------------------------------------------------
// K0: split in_proj weight [512][128] into bf16 hi/lo planes.
// ---------------------------------------------------------------------------
__global__ __launch_bounds__(256) void k_prep_w(
    const float* __restrict__ w, unsigned short* __restrict__ hi, unsigned short* __restrict__ lo)
{
  int i = blockIdx.x*256 + threadIdx.x;      // 65536
  float v = w[i];
  unsigned short h = f2bf(v);
  hi[i] = h;
  lo[i] = f2bf(v - bf2f(h));
}

// ---------------------------------------------------------------------------
// K1a: LN1 -> xn bf16 hi/lo planes [MTOT][128]. Reads x [B,128,L] coalesced.
// ---------------------------------------------------------------------------
__global__ __launch_bounds__(256) void k_ln(
    const float* __restrict__ x, const float* __restrict__ ln1w, const float* __restrict__ ln1b,
    unsigned short* __restrict__ xnh, unsigned short* __restrict__ xnl)
{
  __shared__ float a_s[DM][65];
  __shared__ float mS[64], rS[64];
  const int tid = threadIdx.x;
  const int m0 = blockIdx.x * 64;
  const int b = m0 >> 13, l0 = m0 & (LSEQ-1);
  const float* xb = x + b*DM*LSEQ;
#pragma unroll
  for (int i = 0; i < 32; ++i) {
    int idx = tid + i*256;
    int d = idx >> 6, l = idx & 63;
    a_s[d][l] = xb[d*LSEQ + l0 + l];
  }
  __syncthreads();
  {
    int p = tid & 3, l = tid >> 2;  // 4 threads per row l
    float s = 0.f, q = 0.f;
#pragma unroll
    for (int jj = 0; jj < 32; ++jj) {
      float v = a_s[p + 4*jj][l];
      s += v; q += v*v;
    }
    s += __shfl_xor(s,1); s += __shfl_xor(s,2);
    q += __shfl_xor(q,1); q += __shfl_xor(q,2);
    float m = s*(1.f/DM);
    float var = q*(1.f/DM) - m*m;
    if (p == 0) { mS[l] = m; rS[l] = rsqrtf(var + 1e-5f); }
  }
  __syncthreads();
  // 64 rows x 128 cols = 8192 elements -> 32 iterations of 256 threads.
#pragma unroll
  for (int i = 0; i < 32; ++i) {
    int idx = tid + i*256;
    int l = idx >> 7, d = idx & 127;
    float v = (a_s[d][l] - mS[l])*rS[l]*ln1w[d] + ln1b[d];
    unsigned short h = f2bf(v);
    xnh[(m0+l)*DM + d] = h;
    xnl[(m0+l)*DM + d] = f2bf(v - bf2f(h));
  }
}

// ---------------------------------------------------------------------------
// K1b: in_proj GEMM via bf16 MFMA, 3-pass hi/lo split (fp32-grade accuracy).
// Tile 64x64, K=128 fully LDS-resident, XOR-swizzled 16B slots.
// ---------------------------------------------------------------------------
__global__ __launch_bounds__(256) void k_gemm_in(
    const unsigned short* __restrict__ xnh, const unsigned short* __restrict__ xnl,
    const unsigned short* __restrict__ wh,  const unsigned short* __restrict__ wl,
    float* __restrict__ xi, float* __restrict__ zz)
{
  __shared__ char lds[65536];                 // 4 planes x 16KB (64 rows x 128 bf16)
  const int tid = threadIdx.x;
  const int m0 = blockIdx.x * 64;
  const int n0 = blockIdx.y * 64;
  const unsigned short* srcs[4] = { xnh + m0*DM, xnl + m0*DM, wh + n0*DM, wl + n0*DM };
#pragma unroll
  for (int p = 0; p < 4; ++p) {
#pragma unroll
    for (int i = 0; i < 4; ++i) {
      int u = tid + i*256;                    // 16B unit within plane (0..1023)
      int row = u >> 4, c = u & 15;
      int dstu = p*1024 + row*16 + (c ^ (row & 7));
      *(uint4*)(lds + dstu*16) = *(const uint4*)(srcs[p] + row*DM + c*8);
    }
  }
  __syncthreads();
  const int wid = tid >> 6, lane = tid & 63;
  const int m0w = (wid & 1)*32, n0w = (wid >> 1)*32;
  const int lr = lane & 15, kg = lane >> 4;
  bf16x8 ah[2][4], al[2][4], bh[2][4], bl[2][4];
#pragma unroll
  for (int mi = 0; mi < 2; ++mi) {
    int row = m0w + mi*16 + lr;
#pragma unroll
    for (int kk = 0; kk < 4; ++kk) {
      int slot = (kk*4 + kg) ^ (row & 7);
      ah[mi][kk] = *(const bf16x8*)(lds + 0     + row*256 + slot*16);
      al[mi][kk] = *(const bf16x8*)(lds + 16384 + row*256 + slot*16);
    }
  }
#pragma unroll
  for (int nj = 0; nj < 2; ++nj) {
    int row = n0w + nj*16 + lr;
#pragma unroll
    for (int kk = 0; kk < 4; ++kk) {
      int slot = (kk*4 + kg) ^ (row & 7);
      bh[nj][kk] = *(const bf16x8*)(lds + 32768 + row*256 + slot*16);
      bl[nj][kk] = *(const bf16x8*)(lds + 49152 + row*256 + slot*16);
    }
  }
  f32x4 acc[2][2];
#pragma unroll
  for (int mi = 0; mi < 2; ++mi)
#pragma unroll
    for (int nj = 0; nj < 2; ++nj) acc[mi][nj] = 0.f;
#pragma unroll
  for (int kk = 0; kk < 4; ++kk)
#pragma unroll
    for (int mi = 0; mi < 2; ++mi)
#pragma unroll
      for (int nj = 0; nj < 2; ++nj)
        acc[mi][nj] = __builtin_amdgcn_mfma_f32_16x16x32_bf16(ah[mi][kk], bh[nj][kk], acc[mi][nj], 0,0,0);
#pragma unroll
  for (int kk = 0; kk < 4; ++kk)
#pragma unroll
    for (int mi = 0; mi < 2; ++mi)
#pragma unroll
      for (int nj = 0; nj < 2; ++nj)
        acc[mi][nj] = __builtin_amdgcn_mfma_f32_16x16x32_bf16(ah[mi][kk], bl[nj][kk], acc[mi][nj], 0,0,0);
#pragma unroll
  for (int kk = 0; kk < 4; ++kk)
#pragma unroll
    for (int mi = 0; mi < 2; ++mi)
#pragma unroll
      for (int nj = 0; nj < 2; ++nj)
        acc[mi][nj] = __builtin_amdgcn_mfma_f32_16x16x32_bf16(al[mi][kk], bh[nj][kk], acc[mi][nj], 0,0,0);
  // C/D: col = lane&15 (n), row = (lane>>4)*4 + r (m)
  float* base = (n0 < 256) ? xi : zz;
  const int ncol0 = (n0 < 256) ? n0 : n0 - 256;
#pragma unroll
  for (int mi = 0; mi < 2; ++mi)
#pragma unroll
    for (int nj = 0; nj < 2; ++nj) {
      int n_g = ncol0 + n0w + nj*16 + lr;
#pragma unroll
      for (int r = 0; r < 4; ++r) {
        int m_g = m0 + m0w + mi*16 + kg*4 + r;
        base[m_g*DI + n_g] = acc[mi][nj][r];
      }
    }
}

// ---------------------------------------------------------------------------
// K2: causal conv4 + SiLU (on the fly) + x_proj GEMM -> dt_r[8], B[16], C[16].
// ---------------------------------------------------------------------------
__global__ __launch_bounds__(256) void k_conv_xproj(
  const float* __restrict__ xi,
  const float* __restrict__ cwf, const float* __restrict__ cbf,
  const float* __restrict__ cwb, const float* __restrict__ cbb,
  const float* __restrict__ xwf, const float* __restrict__ xwb,
  float* __restrict__ dtr, float* __restrict__ Bm, float* __restrict__ Cm)
{
  __shared__ float xcs[64][257];
  const int tid = threadIdx.x, bid = blockIdx.x;
  const int lt = bid & (LSEQ/64 - 1);
  const int b  = (bid >> 7) & 3;
  const int dir = bid >> 9;
  const int l0 = lt*64;
  const float* cw  = dir ? cwb : cwf;
  const float* cbp = dir ? cbb : cbf;
  const float* xw  = dir ? xwb : xwf;
  const int d = tid;
  const float w0 = cw[d*4+0], w1 = cw[d*4+1], w2 = cw[d*4+2], w3 = cw[d*4+3];
  const float bias = cbp[d];
  const int g0 = dir ? (LSEQ-1-l0) : l0;
  const int stp = dir ? -DI : DI;
  const float* xp = xi + (b*LSEQ)*DI + d + g0*DI;
  float h3 = 0.f, h2 = 0.f, h1 = 0.f;
  if (l0 >= 3) { h3 = xp[-3*stp]; h2 = xp[-2*stp]; h1 = xp[-1*stp]; }
  float r0 = xp[0], r1 = xp[stp], r2 = xp[2*stp], r3 = xp[3*stp];
  for (int j = 0; j < 64; j += 4) {
    float v0 = r0, v1 = r1, v2 = r2, v3 = r3;
    if (j + 4 < 64) {
      const float* q = xp + (j+4)*stp;
      r0 = q[0]; r1 = q[stp]; r2 = q[2*stp]; r3 = q[3*stp];
    }
    float a;
    a = bias + w0*h3 + w1*h2 + w2*h1 + w3*v0; xcs[j+0][d] = fsilu(a);
    a = bias + w0*h2 + w1*h1 + w2*v0 + w3*v1; xcs[j+1][d] = fsilu(a);
    a = bias + w0*h1 + w1*v0 + w2*v1 + w3*v2; xcs[j+2][d] = fsilu(a);
    a = bias + w0*v0 + w1*v1 + w2*v2 + w3*v3; xcs[j+3][d] = fsilu(a);
    h3 = v1; h2 = v2; h1 = v3;
  }
  __syncthreads();
  const int wv = __builtin_amdgcn_readfirstlane(tid >> 6);
  const int lane = tid & 63;
  const int t0 = wv*10;
  float acc[10] = {};
  for (int kc = 0; kc < DI; kc += 32) {
    float xcr[32];
#pragma unroll
    for (int kk = 0; kk < 32; ++kk) xcr[kk] = xcs[lane][kc+kk];
#pragma unroll
    for (int j = 0; j < 10; ++j) {
      const float* wr = xw + (t0+j)*DI + kc;
#pragma unroll
      for (int kk = 0; kk < 32; ++kk) acc[j] = fmaf(xcr[kk], wr[kk], acc[j]);
    }
  }
  const int base = (dir*NB + b)*LSEQ + l0 + lane;
#pragma unroll
  for (int j = 0; j < 10; ++j) {
    int t = t0 + j;
    if (t < 8)       dtr[base*RK + t] = acc[j];
    else if (t < 24) Bm[base*NS + t - 8] = acc[j];
    else             Cm[base*NS + t - 24] = acc[j];
  }
}

// ---------------------------------------------------------------------------
// K3: chunk-local scan (from h=0): produces h_local per chunk + sum(dt).
// exp power-chain when A[d][n] = (n+1)*A[d][0] (runtime-verified, fallback kept).
// ---------------------------------------------------------------------------
__global__ __launch_bounds__(256) void k_scan_local(
  const float* __restrict__ xi, const float* __restrict__ dtr, const float* __restrict__ Bm,
  const float* __restrict__ cwf, const float* __restrict__ cbf,
  const float* __restrict__ cwb, const float* __restrict__ cbb,
  const float* __restrict__ dtwf, const float* __restrict__ dtbf,
  const float* __restrict__ dtwb, const float* __restrict__ dtbb,
  const float* __restrict__ alogf, const float* __restrict__ alogb,
  float* __restrict__ hloc, float* __restrict__ sumdt)
{
  __shared__ float Bc[LC][NS];
  __shared__ float dts[LC][RK];
  const int tid = threadIdx.x, bid = blockIdx.x;
  const int c = bid & (NCH-1), b = (bid>>7)&3, dir = bid>>9;
  const int db = dir*NB + b;
  const int l0 = c*LC;
  for (int i = tid; i < LC*NS; i += 256) (&Bc[0][0])[i]  = Bm[(db*LSEQ + l0)*NS + i];
  for (int i = tid; i < LC*RK; i += 256) (&dts[0][0])[i] = dtr[(db*LSEQ + l0)*RK + i];
  const float* cw  = dir ? cwb : cwf;
  const float* cbp = dir ? cbb : cbf;
  const float* dtw = dir ? dtwb : dtwf;
  const float* dtbp= dir ? dtbb : dtbf;
  const float* alog= dir ? alogb : alogf;
  const int d = tid;
  const float w0 = cw[d*4+0], w1 = cw[d*4+1], w2 = cw[d*4+2], w3 = cw[d*4+3];
  const float cbias = cbp[d];
  float dw[RK];
#pragma unroll
  for (int r = 0; r < RK; ++r) dw[r] = dtw[d*RK+r];
  const float dtbv = dtbp[d];
  float A2[NS];
#pragma unroll
  for (int n = 0; n < NS; ++n) A2[n] = -fexpn(alog[d*NS+n]) * LOG2E;
  const float a20 = A2[0];
  bool pw = true;
#pragma unroll
  for (int n = 1; n < NS; ++n) pw = pw && (fabsf(A2[n] - (n+1)*a20) <= 1e-3f*fabsf(A2[n]));
  float h[NS];
#pragma unroll
  for (int n = 0; n < NS; ++n) h[n] = 0.f;
  const int g0 = dir ? (LSEQ-1-l0) : l0;
  const int stp = dir ? -DI : DI;
  const float* xp = xi + (b*LSEQ)*DI + d + g0*DI;
  float h3=0.f, h2=0.f, h1=0.f;
  if (l0 >= 3) { h3 = xp[-3*stp]; h2 = xp[-2*stp]; h1 = xp[-1*stp]; }
  float r0 = xp[0], r1 = xp[stp], r2 = xp[2*stp], r3 = xp[3*stp];
  __syncthreads();
  float sac = 0.f;
  for (int j = 0; j < LC; j += 4) {
    float v0=r0, v1=r1, v2=r2, v3=r3;
    if (j + 4 < LC) { const float* q = xp + (j+4)*stp; r0=q[0]; r1=q[stp]; r2=q[2*stp]; r3=q[3*stp]; }
#pragma unroll
    for (int u = 0; u < 4; ++u) {
      float v = (u==0)?v0:(u==1)?v1:(u==2)?v2:v3;
      float a = cbias + w0*h3 + w1*h2 + w2*h1 + w3*v;
      float xc = fsilu(a);
      float dd8[RK];
      *(float4*)(dd8+0) = *(const float4*)&dts[j+u][0];
      *(float4*)(dd8+4) = *(const float4*)&dts[j+u][4];
      float sd = dtbv;
#pragma unroll
      for (int r = 0; r < RK; ++r) sd = fmaf(dw[r], dd8[r], sd);
      float dt = fsoftplus(sd);
      sac += dt;
      float dx = dt*xc;
      float bb[NS];
      *(float4*)(bb+0)  = *(const float4*)&Bc[j+u][0];
      *(float4*)(bb+4)  = *(const float4*)&Bc[j+u][4];
      *(float4*)(bb+8)  = *(const float4*)&Bc[j+u][8];
      *(float4*)(bb+12) = *(const float4*)&Bc[j+u][12];
      float earr[NS];
      if (pw) {
        float e1 = fexp2(a20*dt);
        float e = e1; earr[0] = e;
#pragma unroll
        for (int n = 1; n < NS; ++n) { e *= e1; earr[n] = e; }
      } else {
#pragma unroll
        for (int n = 0; n < NS; ++n) earr[n] = fexp2(A2[n]*dt);
      }
#pragma unroll
      for (int n = 0; n < NS; ++n) h[n] = fmaf(h[n], earr[n], dx*bb[n]);
      h3 = h2; h2 = h1; h1 = v;
    }
  }
  const int hb = ((db*NCH + c)*DI + d)*NS;
#pragma unroll
  for (int n = 0; n < NS; ++n) hloc[hb+n] = h[n];
  sumdt[(db*NCH + c)*DI + d] = sac;
}

// ---------------------------------------------------------------------------
// K4: sequential prefix over chunks, 16-deep double-buffered prefetch.
// ---------------------------------------------------------------------------
__global__ __launch_bounds__(64) void k_prefix(
  const float* __restrict__ hloc, const float* __restrict__ sumdt,
  const float* __restrict__ alogf, const float* __restrict__ alogb,
  float* __restrict__ hin)
{
  const int gid = blockIdx.x*64 + threadIdx.x;   // 32768
  const int n = gid & 15;
  const int d = (gid >> 4) & 255;
  const int db = gid >> 12;
  const float* alog = (db >= NB) ? alogb : alogf;
  const float a2 = -fexpn(alog[d*NS+n]) * LOG2E;
  const int HS = DI*NS;                          // per-chunk stride (floats)
  const float* hp = hloc + (size_t)db*NCH*HS + d*NS + n;
  const float* sp = sumdt + (size_t)db*NCH*DI + d;
  float* op = hin + (size_t)db*NCH*HS + d*NS + n;
  float hr = 0.f;
  float bl[16], bs[16];
#pragma unroll
  for (int j = 0; j < 16; ++j) { bl[j] = hp[j*HS]; bs[j] = sp[j*DI]; }
  for (int blk = 0; blk < 8; ++blk) {
    float nl[16], nsv[16];
    if (blk < 7) {
#pragma unroll
      for (int j = 0; j < 16; ++j) { nl[j] = hp[(blk*16+16+j)*HS]; nsv[j] = sp[(blk*16+16+j)*DI]; }
    }
#pragma unroll
    for (int j = 0; j < 16; ++j) {
      op[(blk*16+j)*HS] = hr;
      hr = fmaf(fexp2(a2*bs[j]), hr, bl[j]);
    }
    if (blk < 7) {
#pragma unroll
      for (int j = 0; j < 16; ++j) { bl[j] = nl[j]; bs[j] = nsv[j]; }
    }
  }
}

// ---------------------------------------------------------------------------
// K5: rescan from h_in producing y, + D-skip, * SiLU(z).
// ---------------------------------------------------------------------------
__global__ __launch_bounds__(256) void k_scan_out(
  const float* __restrict__ xi, const float* __restrict__ zb,
  const float* __restrict__ dtr, const float* __restrict__ Bm, const float* __restrict__ Cm,
  const float* __restrict__ hin,
  const float* __restrict__ cwf, const float* __restrict__ cbf,
  const float* __restrict__ cwb, const float* __restrict__ cbb,
  const float* __restrict__ dtwf, const float* __restrict__ dtbf,
  const float* __restrict__ dtwb, const float* __restrict__ dtbb,
  const float* __restrict__ alogf, const float* __restrict__ alogb,
  const float* __restrict__ Dskf, const float* __restrict__ Dskb,
  float* __restrict__ s2)
{
  __shared__ float Bc[LC][NS];
  __shared__ float Cc[LC][NS];
  __shared__ float dts[LC][RK];
  const int tid = threadIdx.x, bid = blockIdx.x;
  const int c = bid & (NCH-1), b = (bid>>7)&3, dir = bid>>9;
  const int db = dir*NB + b;
  const int l0 = c*LC;
  for (int i = tid; i < LC*NS; i += 256) (&Bc[0][0])[i]  = Bm[(db*LSEQ + l0)*NS + i];
  for (int i = tid; i < LC*NS; i += 256) (&Cc[0][0])[i]  = Cm[(db*LSEQ + l0)*NS + i];
  for (int i = tid; i < LC*RK; i += 256) (&dts[0][0])[i] = dtr[(db*LSEQ + l0)*RK + i];
  const float* cw  = dir ? cwb : cwf;
  const float* cbp = dir ? cbb : cbf;
  const float* dtw = dir ? dtwb : dtwf;
  const float* dtbp= dir ? dtbb : dtbf;
  const float* alog= dir ? alogb : alogf;
  const int d = tid;
  const float w0 = cw[d*4+0], w1 = cw[d*4+1], w2 = cw[d*4+2], w3 = cw[d*4+3];
  const float cbias = cbp[d];
  const float Dd = (dir ? Dskb : Dskf)[d];
  float dw[RK];
#pragma unroll
  for (int r = 0; r < RK; ++r) dw[r] = dtw[d*RK+r];
  const float dtbv = dtbp[d];
  float A2[NS];
#pragma unroll
  for (int n = 0; n < NS; ++n) A2[n] = -fexpn(alog[d*NS+n]) * LOG2E;
  const float a20 = A2[0];
  bool pw = true;
#pragma unroll
  for (int n = 1; n < NS; ++n) pw = pw && (fabsf(A2[n] - (n+1)*a20) <= 1e-3f*fabsf(A2[n]));
  const int hb = ((db*NCH + c)*DI + d)*NS;
  float h[NS];
#pragma unroll
  for (int n = 0; n < NS; ++n) h[n] = hin[hb+n];
  const int g0 = dir ? (LSEQ-1-l0) : l0;
  const int stp = dir ? -DI : DI;
  const float* xp = xi + (b*LSEQ)*DI + d + g0*DI;
  const float* zp = zb + (b*LSEQ)*DI + d + g0*DI;
  float* sp = s2 + (db*LSEQ + l0)*DI + d;
  float h3=0.f, h2=0.f, h1=0.f;
  if (l0 >= 3) { h3 = xp[-3*stp]; h2 = xp[-2*stp]; h1 = xp[-1*stp]; }
  float r0 = xp[0], r1 = xp[stp], r2 = xp[2*stp], r3 = xp[3*stp];
  float z0 = zp[0], z1 = zp[stp], z2 = zp[2*stp], z3 = zp[3*stp];
  __syncthreads();
  for (int j = 0; j < LC; j += 4) {
    float v0=r0, v1=r1, v2=r2, v3=r3;
    float y0=z0, y1=z1, y2=z2, y3=z3;
    if (j + 4 < LC) {
      const float* q = xp + (j+4)*stp; r0=q[0]; r1=q[stp]; r2=q[2*stp]; r3=q[3*stp];
      const float* qz = zp + (j+4)*stp; z0=qz[0]; z1=qz[stp]; z2=qz[2*stp]; z3=qz[3*stp];
    }
#pragma unroll
    for (int u = 0; u < 4; ++u) {
      float v  = (u==0)?v0:(u==1)?v1:(u==2)?v2:v3;
      float zv = (u==0)?y0:(u==1)?y1:(u==2)?y2:y3;
      float a = cbias + w0*h3 + w1*h2 + w2*h1 + w3*v;
      float xc = fsilu(a);
      float dd8[RK];
      *(float4*)(dd8+0) = *(const float4*)&dts[j+u][0];
      *(float4*)(dd8+4) = *(const float4*)&dts[j+u][4];
      float sd = dtbv;
#pragma unroll
      for (int r = 0; r < RK; ++r) sd = fmaf(dw[r], dd8[r], sd);
      float dt = fsoftplus(sd);
      float dx = dt*xc;
      float bb[NS], ccv[NS];
      *(float4*)(bb+0)  = *(const float4*)&Bc[j+u][0];
      *(float4*)(bb+4)  = *(const float4*)&Bc[j+u][4];
      *(float4*)(bb+8)  = *(const float4*)&Bc[j+u][8];
      *(float4*)(bb+12) = *(const float4*)&Bc[j+u][12];
      *(float4*)(ccv+0)  = *(const float4*)&Cc[j+u][0];
      *(float4*)(ccv+4)  = *(const float4*)&Cc[j+u][4];
      *(float4*)(ccv+8)  = *(const float4*)&Cc[j+u][8];
      *(float4*)(ccv+12) = *(const float4*)&Cc[j+u][12];
      float earr[NS];
      if (pw) {
        float e1 = fexp2(a20*dt);
        float e = e1; earr[0] = e;
#pragma unroll
        for (int n = 1; n < NS; ++n) { e *= e1; earr[n] = e; }
      } else {
#pragma unroll
        for (int n = 0; n < NS; ++n) earr[n] = fexp2(A2[n]*dt);
      }
      float yv = 0.f;
#pragma unroll
      for (int n = 0; n < NS; ++n) {
        h[n] = fmaf(h[n], earr[n], dx*bb[n]);
        yv = fmaf(h[n], ccv[n], yv);
      }
      yv = fmaf(xc, Dd, yv);
      sp[(j+u)*DI] = yv * fsilu(zv);
      h3 = h2; h2 = h1; h1 = v;
    }
  }
}

// ---------------------------------------------------------------------------
// K6: s = sF + rev(sB); out_proj GEMM (K=256); + residual x; LN2; transposed
// store to [B,128,L]. Block: 64 rows x 128 cols, 512 threads, 4x4 per thread.
// ---------------------------------------------------------------------------
__global__ __launch_bounds__(512) void k_out(
  const float* __restrict__ s2, const float* __restrict__ wop,
  const float* __restrict__ x, const float* __restrict__ ln2w, const float* __restrict__ ln2b,
  float* __restrict__ out)
{
  __shared__ float smem[64*65 + DM*65];
  float (*s_s)[65] = (float(*)[65])smem;
  float (*w_s)[65] = (float(*)[65])(smem + 64*65);
  const int tid = threadIdx.x;
  const int m0 = blockIdx.x*64;
  const int b = m0 >> 13, l0 = m0 & (LSEQ-1);
  const int tx = tid & 31, ty = tid >> 5;
  const float* sF = s2 + (0*NB + b)*LSEQ*DI;
  const float* sB = s2 + (NB + b)*LSEQ*DI;
  float acc[4][4] = {};
  for (int kc = 0; kc < DI; kc += 64) {
#pragma unroll
    for (int i = 0; i < 8; ++i) {
      int idx = tid + i*512;
      int r = idx >> 6, kk = idx & 63;
      int l = l0 + r;
      s_s[r][kk] = sF[l*DI + kc + kk] + sB[(LSEQ-1-l)*DI + kc + kk];
    }
#pragma unroll
    for (int i = 0; i < 16; ++i) {
      int idx = tid + i*512;
      int nn = idx >> 6, kk = idx & 63;
      w_s[nn][kk] = wop[nn*DI + kc + kk];
    }
    __syncthreads();
    for (int kk = 0; kk < 64; ++kk) {
      float av[4], bv[4];
#pragma unroll
      for (int ii = 0; ii < 4; ++ii) av[ii] = s_s[ty*4+ii][kk];
#pragma unroll
      for (int jj = 0; jj < 4; ++jj) bv[jj] = w_s[tx*4+jj][kk];
#pragma unroll
      for (int ii = 0; ii < 4; ++ii)
#pragma unroll
        for (int jj = 0; jj < 4; ++jj) acc[ii][jj] = fmaf(av[ii], bv[jj], acc[ii][jj]);
    }
    __syncthreads();
  }
  const float* xb = x + b*DM*LSEQ + l0;
  float lw[4], lb[4];
#pragma unroll
  for (int jj = 0; jj < 4; ++jj) { lw[jj] = ln2w[tx*4+jj]; lb[jj] = ln2b[tx*4+jj]; }
#pragma unroll
  for (int ii = 0; ii < 4; ++ii)
#pragma unroll
    for (int jj = 0; jj < 4; ++jj)
      acc[ii][jj] += xb[(tx*4+jj)*LSEQ + ty*4 + ii];
  float rm[4], rr[4];
#pragma unroll
  for (int ii = 0; ii < 4; ++ii) {
    float s = acc[ii][0]+acc[ii][1]+acc[ii][2]+acc[ii][3];
    float q = acc[ii][0]*acc[ii][0]+acc[ii][1]*acc[ii][1]+acc[ii][2]*acc[ii][2]+acc[ii][3]*acc[ii][3];
#pragma unroll
    for (int mk = 1; mk <= 16; mk <<= 1) { s += __shfl_xor(s, mk); q += __shfl_xor(q, mk); }
    float m = s*(1.f/DM);
    float var = q*(1.f/DM) - m*m;
    rm[ii] = m; rr[ii] = rsqrtf(var + 1e-5f);
  }
  float (*res)[132] = (float(*)[132])smem;
#pragma unroll
  for (int ii = 0; ii < 4; ++ii) {
    float4 v;
    v.x = (acc[ii][0]-rm[ii])*rr[ii]*lw[0] + lb[0];
    v.y = (acc[ii][1]-rm[ii])*rr[ii]*lw[1] + lb[1];
    v.z = (acc[ii][2]-rm[ii])*rr[ii]*lw[2] + lb[2];
    v.w = (acc[ii][3]-rm[ii])*rr[ii]*lw[3] + lb[3];
    *(float4*)&res[ty*4+ii][tx*4] = v;
  }
  __syncthreads();
  float* ob = out + b*DM*LSEQ + l0;
#pragma unroll
  for (int i = 0; i < 16; ++i) {
    int idx = tid + i*512;
    int col = idx >> 6, l = idx & 63;
    ob[col*LSEQ + l] = res[l][col];
  }
}

// ---------------------------------------------------------------------------
extern "C" void kernel_launch(void* const* d_in, const int* in_sizes, int n_in,
                              void* d_out, int out_size, void* d_ws, size_t ws_size,
                              hipStream_t stream)
{
  (void)in_sizes; (void)n_in; (void)out_size; (void)ws_size;
  const float* x     = (const float*)d_in[0];
  const float* ln1w  = (const float*)d_in[1];
  const float* ln1b  = (const float*)d_in[2];
  const float* ln2w  = (const float*)d_in[3];
  const float* ln2b  = (const float*)d_in[4];
  const float* wip   = (const float*)d_in[5];
  const float* wop   = (const float*)d_in[6];
  const float* cwf   = (const float*)d_in[7];
  const float* cbf   = (const float*)d_in[8];
  const float* xwf   = (const float*)d_in[9];
  const float* dtwf  = (const float*)d_in[10];
  const float* dtbf  = (const float*)d_in[11];
  const float* alogf = (const float*)d_in[12];
  const float* Dskf  = (const float*)d_in[13];
  const float* cwb   = (const float*)d_in[14];
  const float* cbb   = (const float*)d_in[15];
  const float* xwb   = (const float*)d_in[16];
  const float* dtwb  = (const float*)d_in[17];
  const float* dtbb  = (const float*)d_in[18];
  const float* alogb = (const float*)d_in[19];
  const float* Dskb  = (const float*)d_in[20];

  // workspace layout (floats)
  float* ws    = (float*)d_ws;
  float* xi    = ws;                    //  8,388,608
  float* zz    = xi   + 8388608;        //  8,388,608
  float* dtr   = zz   + 8388608;        //    524,288
  float* Bm    = dtr  + 524288;         //  1,048,576
  float* Cm    = Bm   + 1048576;        //  1,048,576
  float* s2    = Cm   + 1048576;        // 16,777,216
  float* hloc  = s2   + 16777216;       //  4,194,304
  float* hin   = hloc + 4194304;        //  4,194,304
  float* sumdt = hin  + 4194304;        //    262,144
  float* out   = (float*)d_out;
  // xn/w bf16 planes alias the s2 region (dead until k_scan_out runs).
  // NOTE: every aliased byte is rewritten every call (k_ln covers all 64 rows
  // per tile; k_prep_w covers all 65536 weights) -> replay-deterministic.
  unsigned short* xnh = (unsigned short*)s2;                 // 4,194,304 ush
  unsigned short* xnl = (unsigned short*)(s2 + 2097152);     // 4,194,304 ush
  unsigned short* whp = (unsigned short*)(s2 + 4194304);     //    65,536 ush
  unsigned short* wlp = (unsigned short*)(s2 + 4227072);     //    65,536 ush

  k_prep_w<<<256, 256, 0, stream>>>(wip, whp, wlp);
  k_ln<<<512, 256, 0, stream>>>(x, ln1w, ln1b, xnh, xnl);
  k_gemm_in<<<dim3(512,8), 256, 0, stream>>>(xnh, xnl, whp, wlp, xi, zz);
  k_conv_xproj<<<1024, 256, 0, stream>>>(xi, cwf,cbf,cwb,cbb, xwf,xwb, dtr, Bm, Cm);
  k_scan_local<<<1024, 256, 0, stream>>>(xi, dtr, Bm, cwf,cbf,cwb,cbb,
                                         dtwf,dtbf,dtwb,dtbb, alogf, alogb, hloc, sumdt);
  k_prefix<<<512, 64, 0, stream>>>(hloc, sumdt, alogf, alogb, hin);
  k_scan_out<<<1024, 256, 0, stream>>>(xi, zz, dtr, Bm, Cm, hin, cwf,cbf,cwb,cbb,
                                       dtwf,dtbf,dtwb,dtbb, alogf,alogb, Dskf, Dskb, s2);
  k_out<<<512, 512, 0, stream>>>(s2, wop, x, ln2w, ln2b, out);
}

// Round 4
// 232.151 us; speedup vs baseline: 1.6483x; 1.2825x over previous
//
#include <hip/hip_runtime.h>

// MambaLayer bidirectional selective-scan, fp32 (bf16/bf16-split MFMA GEMMs).
// Shapes: B=4, L=8192 (32*16*16), d_model=128, d_inner=256, d_state=16, dt_rank=8.
#define NB   4
#define LSEQ 8192
#define DM   128
#define DI   256
#define NS   16
#define RK   8
#define NCH  256          // chunks over L
#define LC   32           // L / NCH
#define MTOT (NB*LSEQ)    // 32768 rows
#define LOG2E 1.44269504088896340736f
#define LN2f  0.69314718055994530942f

#if __has_builtin(__builtin_amdgcn_exp2f)
__device__ __forceinline__ float fexp2(float x){ return __builtin_amdgcn_exp2f(x); }
#else
__device__ __forceinline__ float fexp2(float x){ return exp2f(x); }
#endif
#if __has_builtin(__builtin_amdgcn_logf)
__device__ __forceinline__ float flog2(float x){ return __builtin_amdgcn_logf(x); }
#else
__device__ __forceinline__ float flog2(float x){ return log2f(x); }
#endif
#if __has_builtin(__builtin_amdgcn_rcpf)
__device__ __forceinline__ float frcp(float x){ return __builtin_amdgcn_rcpf(x); }
#else
__device__ __forceinline__ float frcp(float x){ return 1.f/x; }
#endif
__device__ __forceinline__ float fexpn(float x){ return fexp2(x*LOG2E); }
__device__ __forceinline__ float fsilu(float x){ return x*frcp(1.f + fexpn(-x)); }
__device__ __forceinline__ float fsoftplus(float x){
  return fmaxf(x,0.f) + flog2(1.f + fexpn(-fabsf(x)))*LN2f;
}

__device__ __forceinline__ unsigned short f2bf(float v){
  unsigned int u = __float_as_uint(v);
  return (unsigned short)((u + 0x7FFFu + ((u >> 16) & 1u)) >> 16);
}
__device__ __forceinline__ float bf2f(unsigned short h){
  return __uint_as_float(((unsigned int)h) << 16);
}

typedef __attribute__((ext_vector_type(8))) short bf16x8;
typedef __attribute__((ext_vector_type(4))) float f32x4;

// ---------------------------------------------------------------------------
// K0: split in_proj weight [512][128] into bf16 hi/lo planes; convert x_proj
// weights [2][40][256] into padded bf16 [2][48][256] (rows 40..47 zeroed).
// ---------------------------------------------------------------------------
__global__ __launch_bounds__(256) void k_prep_w(
    const float* __restrict__ w, unsigned short* __restrict__ hi, unsigned short* __restrict__ lo,
    const float* __restrict__ xwf, const float* __restrict__ xwb, unsigned short* __restrict__ xwbf)
{
  int i = blockIdx.x*256 + threadIdx.x;      // 0..90111
  if (i < 65536) {
    float v = w[i];
    unsigned short h = f2bf(v);
    hi[i] = h;
    lo[i] = f2bf(v - bf2f(h));
  } else {
    int j = i - 65536;                       // 0..24575
    int dirw = j / 12288;                    // 48*256 per dir
    int rem = j - dirw*12288;
    int row = rem >> 8, k = rem & 255;
    const float* src = dirw ? xwb : xwf;
    xwbf[j] = (row < 40) ? f2bf(src[row*256 + k]) : (unsigned short)0;
  }
}

// ---------------------------------------------------------------------------
// K1a: LN1 -> xn bf16 hi/lo planes [MTOT][128]. Reads x [B,128,L] coalesced.
// ---------------------------------------------------------------------------
__global__ __launch_bounds__(256) void k_ln(
    const float* __restrict__ x, const float* __restrict__ ln1w, const float* __restrict__ ln1b,
    unsigned short* __restrict__ xnh, unsigned short* __restrict__ xnl)
{
  __shared__ float a_s[DM][65];
  __shared__ float mS[64], rS[64];
  const int tid = threadIdx.x;
  const int m0 = blockIdx.x * 64;
  const int b = m0 >> 13, l0 = m0 & (LSEQ-1);
  const float* xb = x + b*DM*LSEQ;
#pragma unroll
  for (int i = 0; i < 32; ++i) {
    int idx = tid + i*256;
    int d = idx >> 6, l = idx & 63;
    a_s[d][l] = xb[d*LSEQ + l0 + l];
  }
  __syncthreads();
  {
    int p = tid & 3, l = tid >> 2;  // 4 threads per row l
    float s = 0.f, q = 0.f;
#pragma unroll
    for (int jj = 0; jj < 32; ++jj) {
      float v = a_s[p + 4*jj][l];
      s += v; q += v*v;
    }
    s += __shfl_xor(s,1); s += __shfl_xor(s,2);
    q += __shfl_xor(q,1); q += __shfl_xor(q,2);
    float m = s*(1.f/DM);
    float var = q*(1.f/DM) - m*m;
    if (p == 0) { mS[l] = m; rS[l] = rsqrtf(var + 1e-5f); }
  }
  __syncthreads();
  // 64 rows x 128 cols = 8192 elements -> 32 iterations of 256 threads.
#pragma unroll
  for (int i = 0; i < 32; ++i) {
    int idx = tid + i*256;
    int l = idx >> 7, d = idx & 127;
    float v = (a_s[d][l] - mS[l])*rS[l]*ln1w[d] + ln1b[d];
    unsigned short h = f2bf(v);
    xnh[(m0+l)*DM + d] = h;
    xnl[(m0+l)*DM + d] = f2bf(v - bf2f(h));
  }
}

// ---------------------------------------------------------------------------
// K1b: in_proj GEMM via bf16 MFMA, 3-pass hi/lo split (fp32-grade accuracy).
// Tile 64x64, K=128 fully LDS-resident, XOR-swizzled 16B slots.
// ---------------------------------------------------------------------------
__global__ __launch_bounds__(256) void k_gemm_in(
    const unsigned short* __restrict__ xnh, const unsigned short* __restrict__ xnl,
    const unsigned short* __restrict__ wh,  const unsigned short* __restrict__ wl,
    float* __restrict__ xi, float* __restrict__ zz)
{
  __shared__ char lds[65536];                 // 4 planes x 16KB (64 rows x 128 bf16)
  const int tid = threadIdx.x;
  const int m0 = blockIdx.x * 64;
  const int n0 = blockIdx.y * 64;
  const unsigned short* srcs[4] = { xnh + m0*DM, xnl + m0*DM, wh + n0*DM, wl + n0*DM };
#pragma unroll
  for (int p = 0; p < 4; ++p) {
#pragma unroll
    for (int i = 0; i < 4; ++i) {
      int u = tid + i*256;                    // 16B unit within plane (0..1023)
      int row = u >> 4, c = u & 15;
      int dstu = p*1024 + row*16 + (c ^ (row & 7));
      *(uint4*)(lds + dstu*16) = *(const uint4*)(srcs[p] + row*DM + c*8);
    }
  }
  __syncthreads();
  const int wid = tid >> 6, lane = tid & 63;
  const int m0w = (wid & 1)*32, n0w = (wid >> 1)*32;
  const int lr = lane & 15, kg = lane >> 4;
  bf16x8 ah[2][4], al[2][4], bh[2][4], bl[2][4];
#pragma unroll
  for (int mi = 0; mi < 2; ++mi) {
    int row = m0w + mi*16 + lr;
#pragma unroll
    for (int kk = 0; kk < 4; ++kk) {
      int slot = (kk*4 + kg) ^ (row & 7);
      ah[mi][kk] = *(const bf16x8*)(lds + 0     + row*256 + slot*16);
      al[mi][kk] = *(const bf16x8*)(lds + 16384 + row*256 + slot*16);
    }
  }
#pragma unroll
  for (int nj = 0; nj < 2; ++nj) {
    int row = n0w + nj*16 + lr;
#pragma unroll
    for (int kk = 0; kk < 4; ++kk) {
      int slot = (kk*4 + kg) ^ (row & 7);
      bh[nj][kk] = *(const bf16x8*)(lds + 32768 + row*256 + slot*16);
      bl[nj][kk] = *(const bf16x8*)(lds + 49152 + row*256 + slot*16);
    }
  }
  f32x4 acc[2][2];
#pragma unroll
  for (int mi = 0; mi < 2; ++mi)
#pragma unroll
    for (int nj = 0; nj < 2; ++nj) acc[mi][nj] = 0.f;
#pragma unroll
  for (int kk = 0; kk < 4; ++kk)
#pragma unroll
    for (int mi = 0; mi < 2; ++mi)
#pragma unroll
      for (int nj = 0; nj < 2; ++nj)
        acc[mi][nj] = __builtin_amdgcn_mfma_f32_16x16x32_bf16(ah[mi][kk], bh[nj][kk], acc[mi][nj], 0,0,0);
#pragma unroll
  for (int kk = 0; kk < 4; ++kk)
#pragma unroll
    for (int mi = 0; mi < 2; ++mi)
#pragma unroll
      for (int nj = 0; nj < 2; ++nj)
        acc[mi][nj] = __builtin_amdgcn_mfma_f32_16x16x32_bf16(ah[mi][kk], bl[nj][kk], acc[mi][nj], 0,0,0);
#pragma unroll
  for (int kk = 0; kk < 4; ++kk)
#pragma unroll
    for (int mi = 0; mi < 2; ++mi)
#pragma unroll
      for (int nj = 0; nj < 2; ++nj)
        acc[mi][nj] = __builtin_amdgcn_mfma_f32_16x16x32_bf16(al[mi][kk], bh[nj][kk], acc[mi][nj], 0,0,0);
  // C/D: col = lane&15 (n), row = (lane>>4)*4 + r (m)
  float* base = (n0 < 256) ? xi : zz;
  const int ncol0 = (n0 < 256) ? n0 : n0 - 256;
#pragma unroll
  for (int mi = 0; mi < 2; ++mi)
#pragma unroll
    for (int nj = 0; nj < 2; ++nj) {
      int n_g = ncol0 + n0w + nj*16 + lr;
#pragma unroll
      for (int r = 0; r < 4; ++r) {
        int m_g = m0 + m0w + mi*16 + kg*4 + r;
        base[m_g*DI + n_g] = acc[mi][nj][r];
      }
    }
}

// ---------------------------------------------------------------------------
// K2: causal conv4 + SiLU -> bf16 A-plane in LDS; x_proj GEMM via MFMA
// against preconverted bf16 weights (48x256, rows>=40 zero).
// Output: dt_r[8], B[16], C[16] per row.
// ---------------------------------------------------------------------------
__global__ __launch_bounds__(256) void k_conv_xproj(
  const float* __restrict__ xi,
  const float* __restrict__ cwf, const float* __restrict__ cbf,
  const float* __restrict__ cwb, const float* __restrict__ cbb,
  const unsigned short* __restrict__ xwbf,   // [2][48][256] bf16
  float* __restrict__ dtr, float* __restrict__ Bm, float* __restrict__ Cm)
{
  __shared__ char lds[57344];   // A: 64 rows x 512B @0; W: 48 rows x 512B @32768
  const int tid = threadIdx.x, bid = blockIdx.x;
  const int lt = bid & (LSEQ/64 - 1);
  const int b  = (bid >> 7) & 3;
  const int dir = bid >> 9;
  const int l0 = lt*64;
  const int db = dir*NB + b;
  // ---- stage x_proj weights (swizzled slots) ----
  const unsigned short* xwp = xwbf + dir*48*256;
#pragma unroll
  for (int i = 0; i < 6; ++i) {
    int u = tid + i*256;                     // 0..1535 slots
    int row = u >> 5, s = u & 31;
    *(uint4*)(lds + 32768 + row*512 + ((s ^ (row & 7))<<4)) =
        *(const uint4*)(xwp + row*256 + s*8);
  }
  // ---- conv + SiLU into bf16 A-plane ----
  const float* cw  = dir ? cwb : cwf;
  const float* cbp = dir ? cbb : cbf;
  const int d = tid;
  const float w0 = cw[d*4+0], w1 = cw[d*4+1], w2 = cw[d*4+2], w3 = cw[d*4+3];
  const float bias = cbp[d];
  const int g0 = dir ? (LSEQ-1-l0) : l0;
  const int stp = dir ? -DI : DI;
  const float* xp = xi + (b*LSEQ)*DI + d + g0*DI;
  float h3 = 0.f, h2 = 0.f, h1 = 0.f;
  if (l0 >= 3) { h3 = xp[-3*stp]; h2 = xp[-2*stp]; h1 = xp[-1*stp]; }
  float r0 = xp[0], r1 = xp[stp], r2 = xp[2*stp], r3 = xp[3*stp];
  const int sbase = (((d>>3))<<4) + ((d&7)<<1);  // slot*16 + byte, pre-XOR
  for (int j = 0; j < 64; j += 4) {
    float v0 = r0, v1 = r1, v2 = r2, v3 = r3;
    if (j + 4 < 64) {
      const float* q = xp + (j+4)*stp;
      r0 = q[0]; r1 = q[stp]; r2 = q[2*stp]; r3 = q[3*stp];
    }
    float a;
#pragma unroll
    for (int u = 0; u < 4; ++u) {
      float vv = (u==0)?v0:(u==1)?v1:(u==2)?v2:v3;
      a = bias + w0*h3 + w1*h2 + w2*h1 + w3*vv;
      int row = j + u;
      *(unsigned short*)(lds + row*512 + ((((d>>3) ^ (row&7))<<4) + ((d&7)<<1))) = f2bf(fsilu(a));
      h3 = h2; h2 = h1; h1 = vv;
    }
  }
  __syncthreads();
  // ---- MFMA: [64 rows] x [48 cols], K=256 ----
  const int wid = tid >> 6, lane = tid & 63;
  const int lr = lane & 15, kg = lane >> 4;
  const int arow = wid*16 + lr;
  f32x4 acc[3];
#pragma unroll
  for (int j = 0; j < 3; ++j) acc[j] = 0.f;
#pragma unroll
  for (int t = 0; t < 8; ++t) {
    bf16x8 af = *(const bf16x8*)(lds + arow*512 + (((t*4+kg) ^ (arow&7))<<4));
#pragma unroll
    for (int j = 0; j < 3; ++j) {
      int wrow = j*16 + lr;
      bf16x8 bfr = *(const bf16x8*)(lds + 32768 + wrow*512 + (((t*4+kg) ^ (wrow&7))<<4));
      acc[j] = __builtin_amdgcn_mfma_f32_16x16x32_bf16(af, bfr, acc[j], 0,0,0);
    }
  }
  // C/D: col = lane&15, row = kg*4 + r
  const int base_l = (db*LSEQ + l0) + wid*16 + kg*4;
#pragma unroll
  for (int j = 0; j < 3; ++j) {
    int col = j*16 + lr;
#pragma unroll
    for (int r = 0; r < 4; ++r) {
      int gl = base_l + r;
      float v = acc[j][r];
      if (col < 8)       dtr[gl*RK + col] = v;
      else if (col < 24) Bm[gl*NS + col - 8] = v;
      else if (col < 40) Cm[gl*NS + col - 24] = v;
    }
  }
}

// ---------------------------------------------------------------------------
// K3: chunk-local scan (from h=0): produces h_local per chunk + sum(dt).
// exp power-chain when A[d][n] = (n+1)*A[d][0] (runtime-verified, fallback kept).
// ---------------------------------------------------------------------------
__global__ __launch_bounds__(256) void k_scan_local(
  const float* __restrict__ xi, const float* __restrict__ dtr, const float* __restrict__ Bm,
  const float* __restrict__ cwf, const float* __restrict__ cbf,
  const float* __restrict__ cwb, const float* __restrict__ cbb,
  const float* __restrict__ dtwf, const float* __restrict__ dtbf,
  const float* __restrict__ dtwb, const float* __restrict__ dtbb,
  const float* __restrict__ alogf, const float* __restrict__ alogb,
  float* __restrict__ hloc, float* __restrict__ sumdt)
{
  __shared__ float Bc[LC][NS];
  __shared__ float dts[LC][RK];
  const int tid = threadIdx.x, bid = blockIdx.x;
  const int c = bid & (NCH-1), b = (bid>>8)&3, dir = bid>>10;
  const int db = dir*NB + b;
  const int l0 = c*LC;
  for (int i = tid; i < LC*NS; i += 256) (&Bc[0][0])[i]  = Bm[(db*LSEQ + l0)*NS + i];
  for (int i = tid; i < LC*RK; i += 256) (&dts[0][0])[i] = dtr[(db*LSEQ + l0)*RK + i];
  const float* cw  = dir ? cwb : cwf;
  const float* cbp = dir ? cbb : cbf;
  const float* dtw = dir ? dtwb : dtwf;
  const float* dtbp= dir ? dtbb : dtbf;
  const float* alog= dir ? alogb : alogf;
  const int d = tid;
  const float w0 = cw[d*4+0], w1 = cw[d*4+1], w2 = cw[d*4+2], w3 = cw[d*4+3];
  const float cbias = cbp[d];
  float dw[RK];
#pragma unroll
  for (int r = 0; r < RK; ++r) dw[r] = dtw[d*RK+r];
  const float dtbv = dtbp[d];
  float A2[NS];
#pragma unroll
  for (int n = 0; n < NS; ++n) A2[n] = -fexpn(alog[d*NS+n]) * LOG2E;
  const float a20 = A2[0];
  bool pw = true;
#pragma unroll
  for (int n = 1; n < NS; ++n) pw = pw && (fabsf(A2[n] - (n+1)*a20) <= 1e-3f*fabsf(A2[n]));
  float h[NS];
#pragma unroll
  for (int n = 0; n < NS; ++n) h[n] = 0.f;
  const int g0 = dir ? (LSEQ-1-l0) : l0;
  const int stp = dir ? -DI : DI;
  const float* xp = xi + (b*LSEQ)*DI + d + g0*DI;
  float h3=0.f, h2=0.f, h1=0.f;
  if (l0 >= 3) { h3 = xp[-3*stp]; h2 = xp[-2*stp]; h1 = xp[-1*stp]; }
  float r0 = xp[0], r1 = xp[stp], r2 = xp[2*stp], r3 = xp[3*stp];
  __syncthreads();
  float sac = 0.f;
  for (int j = 0; j < LC; j += 4) {
    float v0=r0, v1=r1, v2=r2, v3=r3;
    if (j + 4 < LC) { const float* q = xp + (j+4)*stp; r0=q[0]; r1=q[stp]; r2=q[2*stp]; r3=q[3*stp]; }
#pragma unroll
    for (int u = 0; u < 4; ++u) {
      float v = (u==0)?v0:(u==1)?v1:(u==2)?v2:v3;
      float a = cbias + w0*h3 + w1*h2 + w2*h1 + w3*v;
      float xc = fsilu(a);
      float dd8[RK];
      *(float4*)(dd8+0) = *(const float4*)&dts[j+u][0];
      *(float4*)(dd8+4) = *(const float4*)&dts[j+u][4];
      float sd = dtbv;
#pragma unroll
      for (int r = 0; r < RK; ++r) sd = fmaf(dw[r], dd8[r], sd);
      float dt = fsoftplus(sd);
      sac += dt;
      float dx = dt*xc;
      float bb[NS];
      *(float4*)(bb+0)  = *(const float4*)&Bc[j+u][0];
      *(float4*)(bb+4)  = *(const float4*)&Bc[j+u][4];
      *(float4*)(bb+8)  = *(const float4*)&Bc[j+u][8];
      *(float4*)(bb+12) = *(const float4*)&Bc[j+u][12];
      float earr[NS];
      if (pw) {
        float e1 = fexp2(a20*dt);
        float e = e1; earr[0] = e;
#pragma unroll
        for (int n = 1; n < NS; ++n) { e *= e1; earr[n] = e; }
      } else {
#pragma unroll
        for (int n = 0; n < NS; ++n) earr[n] = fexp2(A2[n]*dt);
      }
#pragma unroll
      for (int n = 0; n < NS; ++n) h[n] = fmaf(h[n], earr[n], dx*bb[n]);
      h3 = h2; h2 = h1; h1 = v;
    }
  }
  const int hb = ((db*NCH + c)*DI + d)*NS;
#pragma unroll
  for (int n = 0; n < NS; ++n) hloc[hb+n] = h[n];
  sumdt[(db*NCH + c)*DI + d] = sac;
}

// ---------------------------------------------------------------------------
// K4: sequential prefix over chunks, 16-deep batched prefetch, IN-PLACE:
// hloc[c] is overwritten with h_in[c] (state entering chunk c). Safe because
// chunk c's value is buffered (and chunk c+1..c+16 prefetched) before the
// write to chunk c happens.
// ---------------------------------------------------------------------------
__global__ __launch_bounds__(64) void k_prefix(
  float* __restrict__ hloc, const float* __restrict__ sumdt,
  const float* __restrict__ alogf, const float* __restrict__ alogb)
{
  const int gid = blockIdx.x*64 + threadIdx.x;   // 32768
  const int n = gid & 15;
  const int d = (gid >> 4) & 255;
  const int db = gid >> 12;
  const float* alog = (db >= NB) ? alogb : alogf;
  const float a2 = -fexpn(alog[d*NS+n]) * LOG2E;
  const int HS = DI*NS;                          // per-chunk stride (floats)
  float* hp = hloc + (size_t)db*NCH*HS + d*NS + n;
  const float* sp = sumdt + (size_t)db*NCH*DI + d;
  float hr = 0.f;
  float bl[16], bs[16];
#pragma unroll
  for (int j = 0; j < 16; ++j) { bl[j] = hp[j*HS]; bs[j] = sp[j*DI]; }
  for (int blk = 0; blk < NCH/16; ++blk) {
    float nl[16], nsv[16];
    if (blk < NCH/16 - 1) {
#pragma unroll
      for (int j = 0; j < 16; ++j) { nl[j] = hp[(blk*16+16+j)*HS]; nsv[j] = sp[(blk*16+16+j)*DI]; }
    }
#pragma unroll
    for (int j = 0; j < 16; ++j) {
      float hl = bl[j];
      hp[(blk*16+j)*HS] = hr;
      hr = fmaf(fexp2(a2*bs[j]), hr, hl);
    }
    if (blk < NCH/16 - 1) {
#pragma unroll
      for (int j = 0; j < 16; ++j) { bl[j] = nl[j]; bs[j] = nsv[j]; }
    }
  }
}

// ---------------------------------------------------------------------------
// K5: rescan from h_in (=hloc after K4) producing y, + D-skip, * SiLU(z).
// ---------------------------------------------------------------------------
__global__ __launch_bounds__(256) void k_scan_out(
  const float* __restrict__ xi, const float* __restrict__ zb,
  const float* __restrict__ dtr, const float* __restrict__ Bm, const float* __restrict__ Cm,
  const float* __restrict__ hin,
  const float* __restrict__ cwf, const float* __restrict__ cbf,
  const float* __restrict__ cwb, const float* __restrict__ cbb,
  const float* __restrict__ dtwf, const float* __restrict__ dtbf,
  const float* __restrict__ dtwb, const float* __restrict__ dtbb,
  const float* __restrict__ alogf, const float* __restrict__ alogb,
  const float* __restrict__ Dskf, const float* __restrict__ Dskb,
  float* __restrict__ s2)
{
  __shared__ float Bc[LC][NS];
  __shared__ float Cc[LC][NS];
  __shared__ float dts[LC][RK];
  const int tid = threadIdx.x, bid = blockIdx.x;
  const int c = bid & (NCH-1), b = (bid>>8)&3, dir = bid>>10;
  const int db = dir*NB + b;
  const int l0 = c*LC;
  for (int i = tid; i < LC*NS; i += 256) (&Bc[0][0])[i]  = Bm[(db*LSEQ + l0)*NS + i];
  for (int i = tid; i < LC*NS; i += 256) (&Cc[0][0])[i]  = Cm[(db*LSEQ + l0)*NS + i];
  for (int i = tid; i < LC*RK; i += 256) (&dts[0][0])[i] = dtr[(db*LSEQ + l0)*RK + i];
  const float* cw  = dir ? cwb : cwf;
  const float* cbp = dir ? cbb : cbf;
  const float* dtw = dir ? dtwb : dtwf;
  const float* dtbp= dir ? dtbb : dtbf;
  const float* alog= dir ? alogb : alogf;
  const int d = tid;
  const float w0 = cw[d*4+0], w1 = cw[d*4+1], w2 = cw[d*4+2], w3 = cw[d*4+3];
  const float cbias = cbp[d];
  const float Dd = (dir ? Dskb : Dskf)[d];
  float dw[RK];
#pragma unroll
  for (int r = 0; r < RK; ++r) dw[r] = dtw[d*RK+r];
  const float dtbv = dtbp[d];
  float A2[NS];
#pragma unroll
  for (int n = 0; n < NS; ++n) A2[n] = -fexpn(alog[d*NS+n]) * LOG2E;
  const float a20 = A2[0];
  bool pw = true;
#pragma unroll
  for (int n = 1; n < NS; ++n) pw = pw && (fabsf(A2[n] - (n+1)*a20) <= 1e-3f*fabsf(A2[n]));
  const int hb = ((db*NCH + c)*DI + d)*NS;
  float h[NS];
#pragma unroll
  for (int n = 0; n < NS; ++n) h[n] = hin[hb+n];
  const int g0 = dir ? (LSEQ-1-l0) : l0;
  const int stp = dir ? -DI : DI;
  const float* xp = xi + (b*LSEQ)*DI + d + g0*DI;
  const float* zp = zb + (b*LSEQ)*DI + d + g0*DI;
  float* sp = s2 + (db*LSEQ + l0)*DI + d;
  float h3=0.f, h2=0.f, h1=0.f;
  if (l0 >= 3) { h3 = xp[-3*stp]; h2 = xp[-2*stp]; h1 = xp[-1*stp]; }
  float r0 = xp[0], r1 = xp[stp], r2 = xp[2*stp], r3 = xp[3*stp];
  float z0 = zp[0], z1 = zp[stp], z2 = zp[2*stp], z3 = zp[3*stp];
  __syncthreads();
  for (int j = 0; j < LC; j += 4) {
    float v0=r0, v1=r1, v2=r2, v3=r3;
    float y0=z0, y1=z1, y2=z2, y3=z3;
    if (j + 4 < LC) {
      const float* q = xp + (j+4)*stp; r0=q[0]; r1=q[stp]; r2=q[2*stp]; r3=q[3*stp];
      const float* qz = zp + (j+4)*stp; z0=qz[0]; z1=qz[stp]; z2=qz[2*stp]; z3=qz[3*stp];
    }
#pragma unroll
    for (int u = 0; u < 4; ++u) {
      float v  = (u==0)?v0:(u==1)?v1:(u==2)?v2:v3;
      float zv = (u==0)?y0:(u==1)?y1:(u==2)?y2:y3;
      float a = cbias + w0*h3 + w1*h2 + w2*h1 + w3*v;
      float xc = fsilu(a);
      float dd8[RK];
      *(float4*)(dd8+0) = *(const float4*)&dts[j+u][0];
      *(float4*)(dd8+4) = *(const float4*)&dts[j+u][4];
      float sd = dtbv;
#pragma unroll
      for (int r = 0; r < RK; ++r) sd = fmaf(dw[r], dd8[r], sd);
      float dt = fsoftplus(sd);
      float dx = dt*xc;
      float bb[NS], ccv[NS];
      *(float4*)(bb+0)  = *(const float4*)&Bc[j+u][0];
      *(float4*)(bb+4)  = *(const float4*)&Bc[j+u][4];
      *(float4*)(bb+8)  = *(const float4*)&Bc[j+u][8];
      *(float4*)(bb+12) = *(const float4*)&Bc[j+u][12];
      *(float4*)(ccv+0)  = *(const float4*)&Cc[j+u][0];
      *(float4*)(ccv+4)  = *(const float4*)&Cc[j+u][4];
      *(float4*)(ccv+8)  = *(const float4*)&Cc[j+u][8];
      *(float4*)(ccv+12) = *(const float4*)&Cc[j+u][12];
      float earr[NS];
      if (pw) {
        float e1 = fexp2(a20*dt);
        float e = e1; earr[0] = e;
#pragma unroll
        for (int n = 1; n < NS; ++n) { e *= e1; earr[n] = e; }
      } else {
#pragma unroll
        for (int n = 0; n < NS; ++n) earr[n] = fexp2(A2[n]*dt);
      }
      float yv = 0.f;
#pragma unroll
      for (int n = 0; n < NS; ++n) {
        h[n] = fmaf(h[n], earr[n], dx*bb[n]);
        yv = fmaf(h[n], ccv[n], yv);
      }
      yv = fmaf(xc, Dd, yv);
      sp[(j+u)*DI] = yv * fsilu(zv);
      h3 = h2; h2 = h1; h1 = v;
    }
  }
}

// ---------------------------------------------------------------------------
// K6: s = sF + rev(sB); out_proj GEMM (K=256); + residual x; LN2; transposed
// store to [B,128,L]. Block: 64 rows x 128 cols, 512 threads, 4x4 per thread.
// ---------------------------------------------------------------------------
__global__ __launch_bounds__(512) void k_out(
  const float* __restrict__ s2, const float* __restrict__ wop,
  const float* __restrict__ x, const float* __restrict__ ln2w, const float* __restrict__ ln2b,
  float* __restrict__ out)
{
  __shared__ float smem[64*65 + DM*65];
  float (*s_s)[65] = (float(*)[65])smem;
  float (*w_s)[65] = (float(*)[65])(smem + 64*65);
  const int tid = threadIdx.x;
  const int m0 = blockIdx.x*64;
  const int b = m0 >> 13, l0 = m0 & (LSEQ-1);
  const int tx = tid & 31, ty = tid >> 5;
  const float* sF = s2 + (0*NB + b)*LSEQ*DI;
  const float* sB = s2 + (NB + b)*LSEQ*DI;
  float acc[4][4] = {};
  for (int kc = 0; kc < DI; kc += 64) {
#pragma unroll
    for (int i = 0; i < 8; ++i) {
      int idx = tid + i*512;
      int r = idx >> 6, kk = idx & 63;
      int l = l0 + r;
      s_s[r][kk] = sF[l*DI + kc + kk] + sB[(LSEQ-1-l)*DI + kc + kk];
    }
#pragma unroll
    for (int i = 0; i < 16; ++i) {
      int idx = tid + i*512;
      int nn = idx >> 6, kk = idx & 63;
      w_s[nn][kk] = wop[nn*DI + kc + kk];
    }
    __syncthreads();
    for (int kk = 0; kk < 64; ++kk) {
      float av[4], bv[4];
#pragma unroll
      for (int ii = 0; ii < 4; ++ii) av[ii] = s_s[ty*4+ii][kk];
#pragma unroll
      for (int jj = 0; jj < 4; ++jj) bv[jj] = w_s[tx*4+jj][kk];
#pragma unroll
      for (int ii = 0; ii < 4; ++ii)
#pragma unroll
        for (int jj = 0; jj < 4; ++jj) acc[ii][jj] = fmaf(av[ii], bv[jj], acc[ii][jj]);
    }
    __syncthreads();
  }
  const float* xb = x + b*DM*LSEQ + l0;
  float lw[4], lb[4];
#pragma unroll
  for (int jj = 0; jj < 4; ++jj) { lw[jj] = ln2w[tx*4+jj]; lb[jj] = ln2b[tx*4+jj]; }
#pragma unroll
  for (int ii = 0; ii < 4; ++ii)
#pragma unroll
    for (int jj = 0; jj < 4; ++jj)
      acc[ii][jj] += xb[(tx*4+jj)*LSEQ + ty*4 + ii];
  float rm[4], rr[4];
#pragma unroll
  for (int ii = 0; ii < 4; ++ii) {
    float s = acc[ii][0]+acc[ii][1]+acc[ii][2]+acc[ii][3];
    float q = acc[ii][0]*acc[ii][0]+acc[ii][1]*acc[ii][1]+acc[ii][2]*acc[ii][2]+acc[ii][3]*acc[ii][3];
#pragma unroll
    for (int mk = 1; mk <= 16; mk <<= 1) { s += __shfl_xor(s, mk); q += __shfl_xor(q, mk); }
    float m = s*(1.f/DM);
    float var = q*(1.f/DM) - m*m;
    rm[ii] = m; rr[ii] = rsqrtf(var + 1e-5f);
  }
  float (*res)[132] = (float(*)[132])smem;
#pragma unroll
  for (int ii = 0; ii < 4; ++ii) {
    float4 v;
    v.x = (acc[ii][0]-rm[ii])*rr[ii]*lw[0] + lb[0];
    v.y = (acc[ii][1]-rm[ii])*rr[ii]*lw[1] + lb[1];
    v.z = (acc[ii][2]-rm[ii])*rr[ii]*lw[2] + lb[2];
    v.w = (acc[ii][3]-rm[ii])*rr[ii]*lw[3] + lb[3];
    *(float4*)&res[ty*4+ii][tx*4] = v;
  }
  __syncthreads();
  float* ob = out + b*DM*LSEQ + l0;
#pragma unroll
  for (int i = 0; i < 16; ++i) {
    int idx = tid + i*512;
    int col = idx >> 6, l = idx & 63;
    ob[col*LSEQ + l] = res[l][col];
  }
}

// ---------------------------------------------------------------------------
extern "C" void kernel_launch(void* const* d_in, const int* in_sizes, int n_in,
                              void* d_out, int out_size, void* d_ws, size_t ws_size,
                              hipStream_t stream)
{
  (void)in_sizes; (void)n_in; (void)out_size; (void)ws_size;
  const float* x     = (const float*)d_in[0];
  const float* ln1w  = (const float*)d_in[1];
  const float* ln1b  = (const float*)d_in[2];
  const float* ln2w  = (const float*)d_in[3];
  const float* ln2b  = (const float*)d_in[4];
  const float* wip   = (const float*)d_in[5];
  const float* wop   = (const float*)d_in[6];
  const float* cwf   = (const float*)d_in[7];
  const float* cbf   = (const float*)d_in[8];
  const float* xwf   = (const float*)d_in[9];
  const float* dtwf  = (const float*)d_in[10];
  const float* dtbf  = (const float*)d_in[11];
  const float* alogf = (const float*)d_in[12];
  const float* Dskf  = (const float*)d_in[13];
  const float* cwb   = (const float*)d_in[14];
  const float* cbb   = (const float*)d_in[15];
  const float* xwb   = (const float*)d_in[16];
  const float* dtwb  = (const float*)d_in[17];
  const float* dtbb  = (const float*)d_in[18];
  const float* alogb = (const float*)d_in[19];
  const float* Dskb  = (const float*)d_in[20];

  // workspace layout (floats)
  float* ws    = (float*)d_ws;
  float* xi    = ws;                    //  8,388,608
  float* zz    = xi   + 8388608;        //  8,388,608
  float* dtr   = zz   + 8388608;        //    524,288
  float* Bm    = dtr  + 524288;         //  1,048,576
  float* Cm    = Bm   + 1048576;        //  1,048,576
  float* s2    = Cm   + 1048576;        // 16,777,216
  float* hloc  = s2   + 16777216;       //  8,388,608 (doubles as h_in after K4)
  float* sumdt = hloc + 8388608;        //    524,288
  float* xwbfF = sumdt + 524288;        //     12,288 (24,576 bf16)
  float* out   = (float*)d_out;
  // xn/w bf16 planes alias the s2 region (dead until k_scan_out runs).
  // Every aliased byte is rewritten every call -> replay-deterministic.
  unsigned short* xnh = (unsigned short*)s2;                 // 4,194,304 ush
  unsigned short* xnl = (unsigned short*)(s2 + 2097152);     // 4,194,304 ush
  unsigned short* whp = (unsigned short*)(s2 + 4194304);     //    65,536 ush
  unsigned short* wlp = (unsigned short*)(s2 + 4227072);     //    65,536 ush
  unsigned short* xwbf = (unsigned short*)xwbfF;             //    24,576 ush

  k_prep_w<<<352, 256, 0, stream>>>(wip, whp, wlp, xwf, xwb, xwbf);
  k_ln<<<512, 256, 0, stream>>>(x, ln1w, ln1b, xnh, xnl);
  k_gemm_in<<<dim3(512,8), 256, 0, stream>>>(xnh, xnl, whp, wlp, xi, zz);
  k_conv_xproj<<<1024, 256, 0, stream>>>(xi, cwf,cbf,cwb,cbb, xwbf, dtr, Bm, Cm);
  k_scan_local<<<2048, 256, 0, stream>>>(xi, dtr, Bm, cwf,cbf,cwb,cbb,
                                         dtwf,dtbf,dtwb,dtbb, alogf, alogb, hloc, sumdt);
  k_prefix<<<512, 64, 0, stream>>>(hloc, sumdt, alogf, alogb);
  k_scan_out<<<2048, 256, 0, stream>>>(xi, zz, dtr, Bm, Cm, hloc, cwf,cbf,cwb,cbb,
                                       dtwf,dtbf,dtwb,dtbb, alogf,alogb, Dskf, Dskb, s2);
  k_out<<<512, 512, 0, stream>>>(s2, wop, x, ln2w, ln2b, out);
}

// Round 5
// 186.889 us; speedup vs baseline: 2.0475x; 1.2422x over previous
//
#include <hip/hip_runtime.h>

// MambaLayer bidirectional selective-scan, fp32 (bf16/bf16-split MFMA GEMMs).
// Shapes: B=4, L=8192 (32*16*16), d_model=128, d_inner=256, d_state=16, dt_rank=8.
#define NB   4
#define LSEQ 8192
#define DM   128
#define DI   256
#define NS   16
#define RK   8
#define NCH  256          // chunks over L
#define LC   32           // L / NCH
#define MTOT (NB*LSEQ)    // 32768 rows
#define LOG2E 1.44269504088896340736f
#define LN2f  0.69314718055994530942f

#if __has_builtin(__builtin_amdgcn_exp2f)
__device__ __forceinline__ float fexp2(float x){ return __builtin_amdgcn_exp2f(x); }
#else
__device__ __forceinline__ float fexp2(float x){ return exp2f(x); }
#endif
#if __has_builtin(__builtin_amdgcn_logf)
__device__ __forceinline__ float flog2(float x){ return __builtin_amdgcn_logf(x); }
#else
__device__ __forceinline__ float flog2(float x){ return log2f(x); }
#endif
#if __has_builtin(__builtin_amdgcn_rcpf)
__device__ __forceinline__ float frcp(float x){ return __builtin_amdgcn_rcpf(x); }
#else
__device__ __forceinline__ float frcp(float x){ return 1.f/x; }
#endif
__device__ __forceinline__ float fexpn(float x){ return fexp2(x*LOG2E); }
__device__ __forceinline__ float fsilu(float x){ return x*frcp(1.f + fexpn(-x)); }
__device__ __forceinline__ float fsoftplus(float x){
  return fmaxf(x,0.f) + flog2(1.f + fexpn(-fabsf(x)))*LN2f;
}

__device__ __forceinline__ unsigned short f2bf(float v){
  unsigned int u = __float_as_uint(v);
  return (unsigned short)((u + 0x7FFFu + ((u >> 16) & 1u)) >> 16);
}
__device__ __forceinline__ float bf2f(unsigned short h){
  return __uint_as_float(((unsigned int)h) << 16);
}

typedef __attribute__((ext_vector_type(8))) short bf16x8;
typedef __attribute__((ext_vector_type(4))) float f32x4;

// ---------------------------------------------------------------------------
// K0: split in_proj weight into bf16 hi/lo; x_proj weights -> padded bf16
// [2][48][256]; out_proj weight [128][256] -> bf16.
// ---------------------------------------------------------------------------
__global__ __launch_bounds__(256) void k_prep_w(
    const float* __restrict__ w, unsigned short* __restrict__ hi, unsigned short* __restrict__ lo,
    const float* __restrict__ xwf, const float* __restrict__ xwb, unsigned short* __restrict__ xwbf,
    const float* __restrict__ wop, unsigned short* __restrict__ wopbf)
{
  int i = blockIdx.x*256 + threadIdx.x;      // 0..122879
  if (i < 65536) {
    float v = w[i];
    unsigned short h = f2bf(v);
    hi[i] = h;
    lo[i] = f2bf(v - bf2f(h));
  } else if (i < 90112) {
    int j = i - 65536;                       // 0..24575
    int dirw = j / 12288;                    // 48*256 per dir
    int rem = j - dirw*12288;
    int row = rem >> 8, k = rem & 255;
    const float* src = dirw ? xwb : xwf;
    xwbf[j] = (row < 40) ? f2bf(src[row*256 + k]) : (unsigned short)0;
  } else {
    int j = i - 90112;                       // 0..32767
    wopbf[j] = f2bf(wop[j]);
  }
}

// ---------------------------------------------------------------------------
// K1a: LN1 -> xn bf16 hi/lo planes [MTOT][128]. Reads x [B,128,L] coalesced.
// ---------------------------------------------------------------------------
__global__ __launch_bounds__(256) void k_ln(
    const float* __restrict__ x, const float* __restrict__ ln1w, const float* __restrict__ ln1b,
    unsigned short* __restrict__ xnh, unsigned short* __restrict__ xnl)
{
  __shared__ float a_s[DM][65];
  __shared__ float mS[64], rS[64];
  const int tid = threadIdx.x;
  const int m0 = blockIdx.x * 64;
  const int b = m0 >> 13, l0 = m0 & (LSEQ-1);
  const float* xb = x + b*DM*LSEQ;
#pragma unroll
  for (int i = 0; i < 32; ++i) {
    int idx = tid + i*256;
    int d = idx >> 6, l = idx & 63;
    a_s[d][l] = xb[d*LSEQ + l0 + l];
  }
  __syncthreads();
  {
    int p = tid & 3, l = tid >> 2;  // 4 threads per row l
    float s = 0.f, q = 0.f;
#pragma unroll
    for (int jj = 0; jj < 32; ++jj) {
      float v = a_s[p + 4*jj][l];
      s += v; q += v*v;
    }
    s += __shfl_xor(s,1); s += __shfl_xor(s,2);
    q += __shfl_xor(q,1); q += __shfl_xor(q,2);
    float m = s*(1.f/DM);
    float var = q*(1.f/DM) - m*m;
    if (p == 0) { mS[l] = m; rS[l] = rsqrtf(var + 1e-5f); }
  }
  __syncthreads();
#pragma unroll
  for (int i = 0; i < 32; ++i) {
    int idx = tid + i*256;
    int l = idx >> 7, d = idx & 127;
    float v = (a_s[d][l] - mS[l])*rS[l]*ln1w[d] + ln1b[d];
    unsigned short h = f2bf(v);
    xnh[(m0+l)*DM + d] = h;
    xnl[(m0+l)*DM + d] = f2bf(v - bf2f(h));
  }
}

// ---------------------------------------------------------------------------
// K1b: in_proj GEMM via bf16 MFMA, 3-pass hi/lo split (fp32-grade accuracy).
// Tile 64x64, K=128 fully LDS-resident, XOR-swizzled 16B slots.
// ---------------------------------------------------------------------------
__global__ __launch_bounds__(256) void k_gemm_in(
    const unsigned short* __restrict__ xnh, const unsigned short* __restrict__ xnl,
    const unsigned short* __restrict__ wh,  const unsigned short* __restrict__ wl,
    float* __restrict__ xi, float* __restrict__ zz)
{
  __shared__ char lds[65536];                 // 4 planes x 16KB (64 rows x 128 bf16)
  const int tid = threadIdx.x;
  const int m0 = blockIdx.x * 64;
  const int n0 = blockIdx.y * 64;
  const unsigned short* srcs[4] = { xnh + m0*DM, xnl + m0*DM, wh + n0*DM, wl + n0*DM };
#pragma unroll
  for (int p = 0; p < 4; ++p) {
#pragma unroll
    for (int i = 0; i < 4; ++i) {
      int u = tid + i*256;                    // 16B unit within plane (0..1023)
      int row = u >> 4, c = u & 15;
      int dstu = p*1024 + row*16 + (c ^ (row & 7));
      *(uint4*)(lds + dstu*16) = *(const uint4*)(srcs[p] + row*DM + c*8);
    }
  }
  __syncthreads();
  const int wid = tid >> 6, lane = tid & 63;
  const int m0w = (wid & 1)*32, n0w = (wid >> 1)*32;
  const int lr = lane & 15, kg = lane >> 4;
  bf16x8 ah[2][4], al[2][4], bh[2][4], bl[2][4];
#pragma unroll
  for (int mi = 0; mi < 2; ++mi) {
    int row = m0w + mi*16 + lr;
#pragma unroll
    for (int kk = 0; kk < 4; ++kk) {
      int slot = (kk*4 + kg) ^ (row & 7);
      ah[mi][kk] = *(const bf16x8*)(lds + 0     + row*256 + slot*16);
      al[mi][kk] = *(const bf16x8*)(lds + 16384 + row*256 + slot*16);
    }
  }
#pragma unroll
  for (int nj = 0; nj < 2; ++nj) {
    int row = n0w + nj*16 + lr;
#pragma unroll
    for (int kk = 0; kk < 4; ++kk) {
      int slot = (kk*4 + kg) ^ (row & 7);
      bh[nj][kk] = *(const bf16x8*)(lds + 32768 + row*256 + slot*16);
      bl[nj][kk] = *(const bf16x8*)(lds + 49152 + row*256 + slot*16);
    }
  }
  f32x4 acc[2][2];
#pragma unroll
  for (int mi = 0; mi < 2; ++mi)
#pragma unroll
    for (int nj = 0; nj < 2; ++nj) acc[mi][nj] = 0.f;
#pragma unroll
  for (int kk = 0; kk < 4; ++kk)
#pragma unroll
    for (int mi = 0; mi < 2; ++mi)
#pragma unroll
      for (int nj = 0; nj < 2; ++nj)
        acc[mi][nj] = __builtin_amdgcn_mfma_f32_16x16x32_bf16(ah[mi][kk], bh[nj][kk], acc[mi][nj], 0,0,0);
#pragma unroll
  for (int kk = 0; kk < 4; ++kk)
#pragma unroll
    for (int mi = 0; mi < 2; ++mi)
#pragma unroll
      for (int nj = 0; nj < 2; ++nj)
        acc[mi][nj] = __builtin_amdgcn_mfma_f32_16x16x32_bf16(ah[mi][kk], bl[nj][kk], acc[mi][nj], 0,0,0);
#pragma unroll
  for (int kk = 0; kk < 4; ++kk)
#pragma unroll
    for (int mi = 0; mi < 2; ++mi)
#pragma unroll
      for (int nj = 0; nj < 2; ++nj)
        acc[mi][nj] = __builtin_amdgcn_mfma_f32_16x16x32_bf16(al[mi][kk], bh[nj][kk], acc[mi][nj], 0,0,0);
  // C/D: col = lane&15 (n), row = (lane>>4)*4 + r (m)
  float* base = (n0 < 256) ? xi : zz;
  const int ncol0 = (n0 < 256) ? n0 : n0 - 256;
#pragma unroll
  for (int mi = 0; mi < 2; ++mi)
#pragma unroll
    for (int nj = 0; nj < 2; ++nj) {
      int n_g = ncol0 + n0w + nj*16 + lr;
#pragma unroll
      for (int r = 0; r < 4; ++r) {
        int m_g = m0 + m0w + mi*16 + kg*4 + r;
        base[m_g*DI + n_g] = acc[mi][nj][r];
      }
    }
}

// ---------------------------------------------------------------------------
// K2: causal conv4 + SiLU -> bf16 A-plane in LDS; x_proj GEMM via MFMA
// against preconverted bf16 weights (48x256, rows>=40 zero).
// ---------------------------------------------------------------------------
__global__ __launch_bounds__(256) void k_conv_xproj(
  const float* __restrict__ xi,
  const float* __restrict__ cwf, const float* __restrict__ cbf,
  const float* __restrict__ cwb, const float* __restrict__ cbb,
  const unsigned short* __restrict__ xwbf,   // [2][48][256] bf16
  float* __restrict__ dtr, float* __restrict__ Bm, float* __restrict__ Cm)
{
  __shared__ char lds[57344];   // A: 64 rows x 512B @0; W: 48 rows x 512B @32768
  const int tid = threadIdx.x, bid = blockIdx.x;
  const int lt = bid & (LSEQ/64 - 1);
  const int b  = (bid >> 7) & 3;
  const int dir = bid >> 9;
  const int l0 = lt*64;
  const int db = dir*NB + b;
  const unsigned short* xwp = xwbf + dir*48*256;
#pragma unroll
  for (int i = 0; i < 6; ++i) {
    int u = tid + i*256;                     // 0..1535 slots
    int row = u >> 5, s = u & 31;
    *(uint4*)(lds + 32768 + row*512 + ((s ^ (row & 7))<<4)) =
        *(const uint4*)(xwp + row*256 + s*8);
  }
  const float* cw  = dir ? cwb : cwf;
  const float* cbp = dir ? cbb : cbf;
  const int d = tid;
  const float w0 = cw[d*4+0], w1 = cw[d*4+1], w2 = cw[d*4+2], w3 = cw[d*4+3];
  const float bias = cbp[d];
  const int g0 = dir ? (LSEQ-1-l0) : l0;
  const int stp = dir ? -DI : DI;
  const float* xp = xi + (b*LSEQ)*DI + d + g0*DI;
  float h3 = 0.f, h2 = 0.f, h1 = 0.f;
  if (l0 >= 3) { h3 = xp[-3*stp]; h2 = xp[-2*stp]; h1 = xp[-1*stp]; }
  float r0 = xp[0], r1 = xp[stp], r2 = xp[2*stp], r3 = xp[3*stp];
  for (int j = 0; j < 64; j += 4) {
    float v0 = r0, v1 = r1, v2 = r2, v3 = r3;
    if (j + 4 < 64) {
      const float* q = xp + (j+4)*stp;
      r0 = q[0]; r1 = q[stp]; r2 = q[2*stp]; r3 = q[3*stp];
    }
    float a;
#pragma unroll
    for (int u = 0; u < 4; ++u) {
      float vv = (u==0)?v0:(u==1)?v1:(u==2)?v2:v3;
      a = bias + w0*h3 + w1*h2 + w2*h1 + w3*vv;
      int row = j + u;
      *(unsigned short*)(lds + row*512 + ((((d>>3) ^ (row&7))<<4) + ((d&7)<<1))) = f2bf(fsilu(a));
      h3 = h2; h2 = h1; h1 = vv;
    }
  }
  __syncthreads();
  const int wid = tid >> 6, lane = tid & 63;
  const int lr = lane & 15, kg = lane >> 4;
  const int arow = wid*16 + lr;
  f32x4 acc[3];
#pragma unroll
  for (int j = 0; j < 3; ++j) acc[j] = 0.f;
#pragma unroll
  for (int t = 0; t < 8; ++t) {
    bf16x8 af = *(const bf16x8*)(lds + arow*512 + (((t*4+kg) ^ (arow&7))<<4));
#pragma unroll
    for (int j = 0; j < 3; ++j) {
      int wrow = j*16 + lr;
      bf16x8 bfr = *(const bf16x8*)(lds + 32768 + wrow*512 + (((t*4+kg) ^ (wrow&7))<<4));
      acc[j] = __builtin_amdgcn_mfma_f32_16x16x32_bf16(af, bfr, acc[j], 0,0,0);
    }
  }
  const int base_l = (db*LSEQ + l0) + wid*16 + kg*4;
#pragma unroll
  for (int j = 0; j < 3; ++j) {
    int col = j*16 + lr;
#pragma unroll
    for (int r = 0; r < 4; ++r) {
      int gl = base_l + r;
      float v = acc[j][r];
      if (col < 8)       dtr[gl*RK + col] = v;
      else if (col < 24) Bm[gl*NS + col - 8] = v;
      else if (col < 40) Cm[gl*NS + col - 24] = v;
    }
  }
}

// ---------------------------------------------------------------------------
// K3: chunk-local scan (from h=0): produces h_local per chunk + sum(dt).
// ---------------------------------------------------------------------------
__global__ __launch_bounds__(256) void k_scan_local(
  const float* __restrict__ xi, const float* __restrict__ dtr, const float* __restrict__ Bm,
  const float* __restrict__ cwf, const float* __restrict__ cbf,
  const float* __restrict__ cwb, const float* __restrict__ cbb,
  const float* __restrict__ dtwf, const float* __restrict__ dtbf,
  const float* __restrict__ dtwb, const float* __restrict__ dtbb,
  const float* __restrict__ alogf, const float* __restrict__ alogb,
  float* __restrict__ hloc, float* __restrict__ sumdt)
{
  __shared__ float Bc[LC][NS];
  __shared__ float dts[LC][RK];
  const int tid = threadIdx.x, bid = blockIdx.x;
  const int c = bid & (NCH-1), b = (bid>>8)&3, dir = bid>>10;
  const int db = dir*NB + b;
  const int l0 = c*LC;
  for (int i = tid; i < LC*NS; i += 256) (&Bc[0][0])[i]  = Bm[(db*LSEQ + l0)*NS + i];
  for (int i = tid; i < LC*RK; i += 256) (&dts[0][0])[i] = dtr[(db*LSEQ + l0)*RK + i];
  const float* cw  = dir ? cwb : cwf;
  const float* cbp = dir ? cbb : cbf;
  const float* dtw = dir ? dtwb : dtwf;
  const float* dtbp= dir ? dtbb : dtbf;
  const float* alog= dir ? alogb : alogf;
  const int d = tid;
  const float w0 = cw[d*4+0], w1 = cw[d*4+1], w2 = cw[d*4+2], w3 = cw[d*4+3];
  const float cbias = cbp[d];
  float dw[RK];
#pragma unroll
  for (int r = 0; r < RK; ++r) dw[r] = dtw[d*RK+r];
  const float dtbv = dtbp[d];
  float A2[NS];
#pragma unroll
  for (int n = 0; n < NS; ++n) A2[n] = -fexpn(alog[d*NS+n]) * LOG2E;
  const float a20 = A2[0];
  bool pw = true;
#pragma unroll
  for (int n = 1; n < NS; ++n) pw = pw && (fabsf(A2[n] - (n+1)*a20) <= 1e-3f*fabsf(A2[n]));
  float h[NS];
#pragma unroll
  for (int n = 0; n < NS; ++n) h[n] = 0.f;
  const int g0 = dir ? (LSEQ-1-l0) : l0;
  const int stp = dir ? -DI : DI;
  const float* xp = xi + (b*LSEQ)*DI + d + g0*DI;
  float h3=0.f, h2=0.f, h1=0.f;
  if (l0 >= 3) { h3 = xp[-3*stp]; h2 = xp[-2*stp]; h1 = xp[-1*stp]; }
  float r0 = xp[0], r1 = xp[stp], r2 = xp[2*stp], r3 = xp[3*stp];
  __syncthreads();
  float sac = 0.f;
  for (int j = 0; j < LC; j += 4) {
    float v0=r0, v1=r1, v2=r2, v3=r3;
    if (j + 4 < LC) { const float* q = xp + (j+4)*stp; r0=q[0]; r1=q[stp]; r2=q[2*stp]; r3=q[3*stp]; }
#pragma unroll
    for (int u = 0; u < 4; ++u) {
      float v = (u==0)?v0:(u==1)?v1:(u==2)?v2:v3;
      float a = cbias + w0*h3 + w1*h2 + w2*h1 + w3*v;
      float xc = fsilu(a);
      float dd8[RK];
      *(float4*)(dd8+0) = *(const float4*)&dts[j+u][0];
      *(float4*)(dd8+4) = *(const float4*)&dts[j+u][4];
      float sd = dtbv;
#pragma unroll
      for (int r = 0; r < RK; ++r) sd = fmaf(dw[r], dd8[r], sd);
      float dt = fsoftplus(sd);
      sac += dt;
      float dx = dt*xc;
      float bb[NS];
      *(float4*)(bb+0)  = *(const float4*)&Bc[j+u][0];
      *(float4*)(bb+4)  = *(const float4*)&Bc[j+u][4];
      *(float4*)(bb+8)  = *(const float4*)&Bc[j+u][8];
      *(float4*)(bb+12) = *(const float4*)&Bc[j+u][12];
      float earr[NS];
      if (pw) {
        float e1 = fexp2(a20*dt);
        float e = e1; earr[0] = e;
#pragma unroll
        for (int n = 1; n < NS; ++n) { e *= e1; earr[n] = e; }
      } else {
#pragma unroll
        for (int n = 0; n < NS; ++n) earr[n] = fexp2(A2[n]*dt);
      }
#pragma unroll
      for (int n = 0; n < NS; ++n) h[n] = fmaf(h[n], earr[n], dx*bb[n]);
      h3 = h2; h2 = h1; h1 = v;
    }
  }
  const int hb = ((db*NCH + c)*DI + d)*NS;
#pragma unroll
  for (int n = 0; n < NS; ++n) hloc[hb+n] = h[n];
  sumdt[(db*NCH + c)*DI + d] = sac;
}

// ---------------------------------------------------------------------------
// K4: sequential prefix over chunks, 16-deep batched prefetch, IN-PLACE.
// ---------------------------------------------------------------------------
__global__ __launch_bounds__(64) void k_prefix(
  float* __restrict__ hloc, const float* __restrict__ sumdt,
  const float* __restrict__ alogf, const float* __restrict__ alogb)
{
  const int gid = blockIdx.x*64 + threadIdx.x;   // 32768
  const int n = gid & 15;
  const int d = (gid >> 4) & 255;
  const int db = gid >> 12;
  const float* alog = (db >= NB) ? alogb : alogf;
  const float a2 = -fexpn(alog[d*NS+n]) * LOG2E;
  const int HS = DI*NS;
  float* hp = hloc + (size_t)db*NCH*HS + d*NS + n;
  const float* sp = sumdt + (size_t)db*NCH*DI + d;
  float hr = 0.f;
  float bl[16], bs[16];
#pragma unroll
  for (int j = 0; j < 16; ++j) { bl[j] = hp[j*HS]; bs[j] = sp[j*DI]; }
  for (int blk = 0; blk < NCH/16; ++blk) {
    float nl[16], nsv[16];
    if (blk < NCH/16 - 1) {
#pragma unroll
      for (int j = 0; j < 16; ++j) { nl[j] = hp[(blk*16+16+j)*HS]; nsv[j] = sp[(blk*16+16+j)*DI]; }
    }
#pragma unroll
    for (int j = 0; j < 16; ++j) {
      float hl = bl[j];
      hp[(blk*16+j)*HS] = hr;
      hr = fmaf(fexp2(a2*bs[j]), hr, hl);
    }
    if (blk < NCH/16 - 1) {
#pragma unroll
      for (int j = 0; j < 16; ++j) { bl[j] = nl[j]; bs[j] = nsv[j]; }
    }
  }
}

// ---------------------------------------------------------------------------
// K5: rescan from h_in (=hloc after K4) producing y, + D-skip, * SiLU(z).
// Writes s as bf16 (halved write traffic; feeds MFMA k_out).
// ---------------------------------------------------------------------------
__global__ __launch_bounds__(256) void k_scan_out(
  const float* __restrict__ xi, const float* __restrict__ zb,
  const float* __restrict__ dtr, const float* __restrict__ Bm, const float* __restrict__ Cm,
  const float* __restrict__ hin,
  const float* __restrict__ cwf, const float* __restrict__ cbf,
  const float* __restrict__ cwb, const float* __restrict__ cbb,
  const float* __restrict__ dtwf, const float* __restrict__ dtbf,
  const float* __restrict__ dtwb, const float* __restrict__ dtbb,
  const float* __restrict__ alogf, const float* __restrict__ alogb,
  const float* __restrict__ Dskf, const float* __restrict__ Dskb,
  unsigned short* __restrict__ s2bf)
{
  __shared__ float Bc[LC][NS];
  __shared__ float Cc[LC][NS];
  __shared__ float dts[LC][RK];
  const int tid = threadIdx.x, bid = blockIdx.x;
  const int c = bid & (NCH-1), b = (bid>>8)&3, dir = bid>>10;
  const int db = dir*NB + b;
  const int l0 = c*LC;
  for (int i = tid; i < LC*NS; i += 256) (&Bc[0][0])[i]  = Bm[(db*LSEQ + l0)*NS + i];
  for (int i = tid; i < LC*NS; i += 256) (&Cc[0][0])[i]  = Cm[(db*LSEQ + l0)*NS + i];
  for (int i = tid; i < LC*RK; i += 256) (&dts[0][0])[i] = dtr[(db*LSEQ + l0)*RK + i];
  const float* cw  = dir ? cwb : cwf;
  const float* cbp = dir ? cbb : cbf;
  const float* dtw = dir ? dtwb : dtwf;
  const float* dtbp= dir ? dtbb : dtbf;
  const float* alog= dir ? alogb : alogf;
  const int d = tid;
  const float w0 = cw[d*4+0], w1 = cw[d*4+1], w2 = cw[d*4+2], w3 = cw[d*4+3];
  const float cbias = cbp[d];
  const float Dd = (dir ? Dskb : Dskf)[d];
  float dw[RK];
#pragma unroll
  for (int r = 0; r < RK; ++r) dw[r] = dtw[d*RK+r];
  const float dtbv = dtbp[d];
  float A2[NS];
#pragma unroll
  for (int n = 0; n < NS; ++n) A2[n] = -fexpn(alog[d*NS+n]) * LOG2E;
  const float a20 = A2[0];
  bool pw = true;
#pragma unroll
  for (int n = 1; n < NS; ++n) pw = pw && (fabsf(A2[n] - (n+1)*a20) <= 1e-3f*fabsf(A2[n]));
  const int hb = ((db*NCH + c)*DI + d)*NS;
  float h[NS];
#pragma unroll
  for (int n = 0; n < NS; ++n) h[n] = hin[hb+n];
  const int g0 = dir ? (LSEQ-1-l0) : l0;
  const int stp = dir ? -DI : DI;
  const float* xp = xi + (b*LSEQ)*DI + d + g0*DI;
  const float* zp = zb + (b*LSEQ)*DI + d + g0*DI;
  unsigned short* sp = s2bf + (size_t)(db*LSEQ + l0)*DI + d;
  float h3=0.f, h2=0.f, h1=0.f;
  if (l0 >= 3) { h3 = xp[-3*stp]; h2 = xp[-2*stp]; h1 = xp[-1*stp]; }
  float r0 = xp[0], r1 = xp[stp], r2 = xp[2*stp], r3 = xp[3*stp];
  float z0 = zp[0], z1 = zp[stp], z2 = zp[2*stp], z3 = zp[3*stp];
  __syncthreads();
  for (int j = 0; j < LC; j += 4) {
    float v0=r0, v1=r1, v2=r2, v3=r3;
    float y0=z0, y1=z1, y2=z2, y3=z3;
    if (j + 4 < LC) {
      const float* q = xp + (j+4)*stp; r0=q[0]; r1=q[stp]; r2=q[2*stp]; r3=q[3*stp];
      const float* qz = zp + (j+4)*stp; z0=qz[0]; z1=qz[stp]; z2=qz[2*stp]; z3=qz[3*stp];
    }
#pragma unroll
    for (int u = 0; u < 4; ++u) {
      float v  = (u==0)?v0:(u==1)?v1:(u==2)?v2:v3;
      float zv = (u==0)?y0:(u==1)?y1:(u==2)?y2:y3;
      float a = cbias + w0*h3 + w1*h2 + w2*h1 + w3*v;
      float xc = fsilu(a);
      float dd8[RK];
      *(float4*)(dd8+0) = *(const float4*)&dts[j+u][0];
      *(float4*)(dd8+4) = *(const float4*)&dts[j+u][4];
      float sd = dtbv;
#pragma unroll
      for (int r = 0; r < RK; ++r) sd = fmaf(dw[r], dd8[r], sd);
      float dt = fsoftplus(sd);
      float dx = dt*xc;
      float bb[NS], ccv[NS];
      *(float4*)(bb+0)  = *(const float4*)&Bc[j+u][0];
      *(float4*)(bb+4)  = *(const float4*)&Bc[j+u][4];
      *(float4*)(bb+8)  = *(const float4*)&Bc[j+u][8];
      *(float4*)(bb+12) = *(const float4*)&Bc[j+u][12];
      *(float4*)(ccv+0)  = *(const float4*)&Cc[j+u][0];
      *(float4*)(ccv+4)  = *(const float4*)&Cc[j+u][4];
      *(float4*)(ccv+8)  = *(const float4*)&Cc[j+u][8];
      *(float4*)(ccv+12) = *(const float4*)&Cc[j+u][12];
      float earr[NS];
      if (pw) {
        float e1 = fexp2(a20*dt);
        float e = e1; earr[0] = e;
#pragma unroll
        for (int n = 1; n < NS; ++n) { e *= e1; earr[n] = e; }
      } else {
#pragma unroll
        for (int n = 0; n < NS; ++n) earr[n] = fexp2(A2[n]*dt);
      }
      float yv = 0.f;
#pragma unroll
      for (int n = 0; n < NS; ++n) {
        h[n] = fmaf(h[n], earr[n], dx*bb[n]);
        yv = fmaf(h[n], ccv[n], yv);
      }
      yv = fmaf(xc, Dd, yv);
      sp[(j+u)*DI] = f2bf(yv * fsilu(zv));
      h3 = h2; h2 = h1; h1 = v;
    }
  }
}

// ---------------------------------------------------------------------------
// K6 v2: MFMA out_proj. (sF + rev(sB)) @ W^T == [sF | rev(sB)] @ [W;W]^T.
// A-tile 64 rows x 512 K bf16 in swizzled LDS; W frags in registers from
// global bf16 (L2-resident). Epilogue: +residual, LN2, transposed store.
// ---------------------------------------------------------------------------
__global__ __launch_bounds__(512) void k_out(
  const unsigned short* __restrict__ s2bf,  // [2][NB][LSEQ][DI] bf16
  const unsigned short* __restrict__ wopbf, // [DM][DI] bf16
  const float* __restrict__ x, const float* __restrict__ ln2w, const float* __restrict__ ln2b,
  float* __restrict__ out)
{
  __shared__ char lds[65536];   // A: 64 rows x 1024B (64 slots of 16B), swizzled
  const int tid = threadIdx.x;
  const int m0 = blockIdx.x*64;
  const int b = m0 >> 13, l0 = m0 & (LSEQ-1);
  const unsigned short* sF = s2bf + (size_t)b*LSEQ*DI;
  const unsigned short* sB = s2bf + (size_t)(NB + b)*LSEQ*DI;
  // stage A: 64 rows x 64 slots (sF -> slots 0..31, rev(sB) -> slots 32..63)
#pragma unroll
  for (int i = 0; i < 8; ++i) {
    int u = tid + i*512;
    int row = u >> 6, c = u & 63;
    int l = l0 + row;
    const unsigned short* src = (c < 32) ? (sF + (size_t)l*DI + c*8)
                                         : (sB + (size_t)(LSEQ-1-l)*DI + (c-32)*8);
    *(uint4*)(lds + row*1024 + ((c ^ (row & 7))<<4)) = *(const uint4*)src;
  }
  // W frags while staging lands: wave (wr,wc); cols n = wc*32 + nt*16 + lr
  const int wid = tid >> 6;
  const int wr = wid >> 2, wc = wid & 3;
  const int lane = tid & 63, lr = lane & 15, kg = lane >> 4;
  bf16x8 wf[2][8];
#pragma unroll
  for (int nt = 0; nt < 2; ++nt) {
    int n = wc*32 + nt*16 + lr;
#pragma unroll
    for (int kt = 0; kt < 8; ++kt)
      wf[nt][kt] = *(const bf16x8*)(wopbf + n*DI + kt*32 + kg*8);
  }
  __syncthreads();
  f32x4 acc[2][2];
#pragma unroll
  for (int mt = 0; mt < 2; ++mt)
#pragma unroll
    for (int nt = 0; nt < 2; ++nt) acc[mt][nt] = 0.f;
#pragma unroll
  for (int kt2 = 0; kt2 < 16; ++kt2) {
#pragma unroll
    for (int mt = 0; mt < 2; ++mt) {
      int row = wr*32 + mt*16 + lr;
      int slot = (kt2*4 + kg) ^ (row & 7);
      bf16x8 af = *(const bf16x8*)(lds + row*1024 + (slot<<4));
#pragma unroll
      for (int nt = 0; nt < 2; ++nt)
        acc[mt][nt] = __builtin_amdgcn_mfma_f32_16x16x32_bf16(af, wf[nt][kt2 & 7], acc[mt][nt], 0,0,0);
    }
  }
  __syncthreads();   // all A reads done; reuse LDS as res[64][133] + mS/rS
  float* smem = (float*)lds;
  const int RP = 133;
  float* mS = smem + 64*RP;      // 64 floats
  float* rS = mS + 64;           // 64 floats
  const float* xb = x + b*DM*LSEQ + l0;
  // acc + residual -> res[m][n]  (C/D: n = ..+lr, m = ..+kg*4+r)
#pragma unroll
  for (int mt = 0; mt < 2; ++mt) {
    int mbase = wr*32 + mt*16 + kg*4;
#pragma unroll
    for (int nt = 0; nt < 2; ++nt) {
      int n = wc*32 + nt*16 + lr;
      float4 rx = *(const float4*)&xb[n*LSEQ + mbase];
      smem[(mbase+0)*RP + n] = acc[mt][nt][0] + rx.x;
      smem[(mbase+1)*RP + n] = acc[mt][nt][1] + rx.y;
      smem[(mbase+2)*RP + n] = acc[mt][nt][2] + rx.z;
      smem[(mbase+3)*RP + n] = acc[mt][nt][3] + rx.w;
    }
  }
  __syncthreads();
  // LN2 stats: 8 threads per row
  {
    int row = tid >> 3, p = tid & 7;
    float s = 0.f, q = 0.f;
#pragma unroll
    for (int jj = 0; jj < 16; ++jj) {
      float v = smem[row*RP + p*16 + jj];
      s += v; q += v*v;
    }
    s += __shfl_xor(s,1); s += __shfl_xor(s,2); s += __shfl_xor(s,4);
    q += __shfl_xor(q,1); q += __shfl_xor(q,2); q += __shfl_xor(q,4);
    if (p == 0) {
      float m = s*(1.f/DM);
      float var = q*(1.f/DM) - m*m;
      mS[row] = m; rS[row] = rsqrtf(var + 1e-5f);
    }
  }
  __syncthreads();
  // normalized transposed store: out[b][col][l0+l]
  float* ob = out + b*DM*LSEQ + l0;
#pragma unroll
  for (int i = 0; i < 16; ++i) {
    int idx = tid + i*512;
    int col = idx >> 6, l = idx & 63;
    float v = (smem[l*RP + col] - mS[l])*rS[l]*ln2w[col] + ln2b[col];
    ob[col*LSEQ + l] = v;
  }
}

// ---------------------------------------------------------------------------
extern "C" void kernel_launch(void* const* d_in, const int* in_sizes, int n_in,
                              void* d_out, int out_size, void* d_ws, size_t ws_size,
                              hipStream_t stream)
{
  (void)in_sizes; (void)n_in; (void)out_size; (void)ws_size;
  const float* x     = (const float*)d_in[0];
  const float* ln1w  = (const float*)d_in[1];
  const float* ln1b  = (const float*)d_in[2];
  const float* ln2w  = (const float*)d_in[3];
  const float* ln2b  = (const float*)d_in[4];
  const float* wip   = (const float*)d_in[5];
  const float* wop   = (const float*)d_in[6];
  const float* cwf   = (const float*)d_in[7];
  const float* cbf   = (const float*)d_in[8];
  const float* xwf   = (const float*)d_in[9];
  const float* dtwf  = (const float*)d_in[10];
  const float* dtbf  = (const float*)d_in[11];
  const float* alogf = (const float*)d_in[12];
  const float* Dskf  = (const float*)d_in[13];
  const float* cwb   = (const float*)d_in[14];
  const float* cbb   = (const float*)d_in[15];
  const float* xwb   = (const float*)d_in[16];
  const float* dtwb  = (const float*)d_in[17];
  const float* dtbb  = (const float*)d_in[18];
  const float* alogb = (const float*)d_in[19];
  const float* Dskb  = (const float*)d_in[20];

  // workspace layout (floats)
  float* ws    = (float*)d_ws;
  float* xi    = ws;                    //  8,388,608
  float* zz    = xi   + 8388608;        //  8,388,608
  float* dtr   = zz   + 8388608;        //    524,288
  float* Bm    = dtr  + 524288;         //  1,048,576
  float* Cm    = Bm   + 1048576;        //  1,048,576
  float* s2    = Cm   + 1048576;        // 16,777,216 (region; bf16 s uses half)
  float* hloc  = s2   + 16777216;       //  8,388,608 (doubles as h_in after K4)
  float* sumdt = hloc + 8388608;        //    524,288
  float* xwbfF = sumdt + 524288;        //     12,288 floats (24,576 bf16)
  float* wopbfF= xwbfF + 12288;         //     16,384 floats (32,768 bf16)
  float* out   = (float*)d_out;
  // bf16 planes alias the s2 region (dead until k_scan_out runs).
  // Every aliased byte is rewritten every call -> replay-deterministic.
  unsigned short* xnh = (unsigned short*)s2;                 // 4,194,304 ush
  unsigned short* xnl = (unsigned short*)(s2 + 2097152);     // 4,194,304 ush
  unsigned short* whp = (unsigned short*)(s2 + 4194304);     //    65,536 ush
  unsigned short* wlp = (unsigned short*)(s2 + 4227072);     //    65,536 ush
  unsigned short* s2bf = (unsigned short*)s2;                // 16,777,216 ush (after K5)
  unsigned short* xwbf = (unsigned short*)xwbfF;
  unsigned short* wopbf = (unsigned short*)wopbfF;

  k_prep_w<<<480, 256, 0, stream>>>(wip, whp, wlp, xwf, xwb, xwbf, wop, wopbf);
  k_ln<<<512, 256, 0, stream>>>(x, ln1w, ln1b, xnh, xnl);
  k_gemm_in<<<dim3(512,8), 256, 0, stream>>>(xnh, xnl, whp, wlp, xi, zz);
  k_conv_xproj<<<1024, 256, 0, stream>>>(xi, cwf,cbf,cwb,cbb, xwbf, dtr, Bm, Cm);
  k_scan_local<<<2048, 256, 0, stream>>>(xi, dtr, Bm, cwf,cbf,cwb,cbb,
                                         dtwf,dtbf,dtwb,dtbb, alogf, alogb, hloc, sumdt);
  k_prefix<<<512, 64, 0, stream>>>(hloc, sumdt, alogf, alogb);
  k_scan_out<<<2048, 256, 0, stream>>>(xi, zz, dtr, Bm, Cm, hloc, cwf,cbf,cwb,cbb,
                                       dtwf,dtbf,dtwb,dtbb, alogf,alogb, Dskf, Dskb, s2bf);
  k_out<<<512, 512, 0, stream>>>(s2bf, wopbf, x, ln2w, ln2b, out);
}

// Round 7
// 184.219 us; speedup vs baseline: 2.0772x; 1.0145x over previous
//
#include <hip/hip_runtime.h>

// MambaLayer bidirectional selective-scan (bf16 MFMA GEMMs, packed xc/dt scan).
// Shapes: B=4, L=8192, d_model=128, d_inner=256, d_state=16, dt_rank=8.
#define NB   4
#define LSEQ 8192
#define DM   128
#define DI   256
#define NS   16
#define RK   8
#define NCH  256          // chunks over L
#define LC   32           // L / NCH
#define MTOT (NB*LSEQ)
#define LOG2E 1.44269504088896340736f
#define LN2f  0.69314718055994530942f

#if __has_builtin(__builtin_amdgcn_exp2f)
__device__ __forceinline__ float fexp2(float x){ return __builtin_amdgcn_exp2f(x); }
#else
__device__ __forceinline__ float fexp2(float x){ return exp2f(x); }
#endif
#if __has_builtin(__builtin_amdgcn_logf)
__device__ __forceinline__ float flog2(float x){ return __builtin_amdgcn_logf(x); }
#else
__device__ __forceinline__ float flog2(float x){ return log2f(x); }
#endif
#if __has_builtin(__builtin_amdgcn_rcpf)
__device__ __forceinline__ float frcp(float x){ return __builtin_amdgcn_rcpf(x); }
#else
__device__ __forceinline__ float frcp(float x){ return 1.f/x; }
#endif
__device__ __forceinline__ float fexpn(float x){ return fexp2(x*LOG2E); }
__device__ __forceinline__ float fsilu(float x){ return x*frcp(1.f + fexpn(-x)); }
__device__ __forceinline__ float fsoftplus(float x){
  return fmaxf(x,0.f) + flog2(1.f + fexpn(-fabsf(x)))*LN2f;
}

__device__ __forceinline__ unsigned short f2bf(float v){
  unsigned int u = __float_as_uint(v);
  return (unsigned short)((u + 0x7FFFu + ((u >> 16) & 1u)) >> 16);
}
__device__ __forceinline__ float bf2f(unsigned short h){
  return __uint_as_float(((unsigned int)h) << 16);
}

typedef __attribute__((ext_vector_type(8))) short bf16x8;
typedef __attribute__((ext_vector_type(4))) float f32x4;

// ---------------------------------------------------------------------------
// K0: weights -> bf16: in_proj [512][128]; x_proj padded [2][48][256];
// out_proj [128][256].
// ---------------------------------------------------------------------------
__global__ __launch_bounds__(256) void k_prep_w(
    const float* __restrict__ wip, unsigned short* __restrict__ wipbf,
    const float* __restrict__ xwf, const float* __restrict__ xwb, unsigned short* __restrict__ xwbf,
    const float* __restrict__ wop, unsigned short* __restrict__ wopbf)
{
  int i = blockIdx.x*256 + threadIdx.x;      // 0..122879
  if (i < 65536) {
    wipbf[i] = f2bf(wip[i]);
  } else if (i < 90112) {
    int j = i - 65536;                       // 0..24575
    int dirw = j / 12288;
    int rem = j - dirw*12288;
    int row = rem >> 8, k = rem & 255;
    const float* src = dirw ? xwb : xwf;
    xwbf[j] = (row < 40) ? f2bf(src[row*256 + k]) : (unsigned short)0;
  } else {
    int j = i - 90112;                       // 0..32767
    wopbf[j] = f2bf(wop[j]);
  }
}

// ---------------------------------------------------------------------------
// K1a: LN1 -> xn bf16 [MTOT][128]. Reads x [B,128,L] coalesced.
// ---------------------------------------------------------------------------
__global__ __launch_bounds__(256) void k_ln(
    const float* __restrict__ x, const float* __restrict__ ln1w, const float* __restrict__ ln1b,
    unsigned short* __restrict__ xnbf)
{
  __shared__ float a_s[DM][65];
  __shared__ float mS[64], rS[64];
  const int tid = threadIdx.x;
  const int m0 = blockIdx.x * 64;
  const int b = m0 >> 13, l0 = m0 & (LSEQ-1);
  const float* xb = x + b*DM*LSEQ;
#pragma unroll
  for (int i = 0; i < 32; ++i) {
    int idx = tid + i*256;
    int d = idx >> 6, l = idx & 63;
    a_s[d][l] = xb[d*LSEQ + l0 + l];
  }
  __syncthreads();
  {
    int p = tid & 3, l = tid >> 2;
    float s = 0.f, q = 0.f;
#pragma unroll
    for (int jj = 0; jj < 32; ++jj) {
      float v = a_s[p + 4*jj][l];
      s += v; q += v*v;
    }
    s += __shfl_xor(s,1); s += __shfl_xor(s,2);
    q += __shfl_xor(q,1); q += __shfl_xor(q,2);
    float m = s*(1.f/DM);
    float var = q*(1.f/DM) - m*m;
    if (p == 0) { mS[l] = m; rS[l] = rsqrtf(var + 1e-5f); }
  }
  __syncthreads();
#pragma unroll
  for (int i = 0; i < 32; ++i) {
    int idx = tid + i*256;
    int l = idx >> 7, d = idx & 127;
    float v = (a_s[d][l] - mS[l])*rS[l]*ln1w[d] + ln1b[d];
    xnbf[(m0+l)*DM + d] = f2bf(v);
  }
}

// ---------------------------------------------------------------------------
// K1b: in_proj GEMM via bf16 MFMA (single plane). Tile 64x64, K=128.
// n0<256 -> xi (fp32); n0>=256 -> zzb (bf16).
// ---------------------------------------------------------------------------
__global__ __launch_bounds__(256) void k_gemm_in(
    const unsigned short* __restrict__ xnbf, const unsigned short* __restrict__ wipbf,
    float* __restrict__ xi, unsigned short* __restrict__ zzb)
{
  __shared__ char lds[32768];                 // 2 planes x 16KB (64 rows x 128 bf16)
  const int tid = threadIdx.x;
  const int m0 = blockIdx.x * 64;
  const int n0 = blockIdx.y * 64;
  const unsigned short* srcs[2] = { xnbf + m0*DM, wipbf + n0*DM };
#pragma unroll
  for (int p = 0; p < 2; ++p) {
#pragma unroll
    for (int i = 0; i < 4; ++i) {
      int u = tid + i*256;                    // 16B unit within plane
      int row = u >> 4, c = u & 15;
      int dstu = p*1024 + row*16 + (c ^ (row & 7));
      *(uint4*)(lds + dstu*16) = *(const uint4*)(srcs[p] + row*DM + c*8);
    }
  }
  __syncthreads();
  const int wid = tid >> 6, lane = tid & 63;
  const int m0w = (wid & 1)*32, n0w = (wid >> 1)*32;
  const int lr = lane & 15, kg = lane >> 4;
  bf16x8 af[2][4], bfv[2][4];
#pragma unroll
  for (int mi = 0; mi < 2; ++mi) {
    int row = m0w + mi*16 + lr;
#pragma unroll
    for (int kk = 0; kk < 4; ++kk) {
      int slot = (kk*4 + kg) ^ (row & 7);
      af[mi][kk] = *(const bf16x8*)(lds + row*256 + slot*16);
    }
  }
#pragma unroll
  for (int nj = 0; nj < 2; ++nj) {
    int row = n0w + nj*16 + lr;
#pragma unroll
    for (int kk = 0; kk < 4; ++kk) {
      int slot = (kk*4 + kg) ^ (row & 7);
      bfv[nj][kk] = *(const bf16x8*)(lds + 16384 + row*256 + slot*16);
    }
  }
  f32x4 acc[2][2];
#pragma unroll
  for (int mi = 0; mi < 2; ++mi)
#pragma unroll
    for (int nj = 0; nj < 2; ++nj) acc[mi][nj] = 0.f;
#pragma unroll
  for (int kk = 0; kk < 4; ++kk)
#pragma unroll
    for (int mi = 0; mi < 2; ++mi)
#pragma unroll
      for (int nj = 0; nj < 2; ++nj)
        acc[mi][nj] = __builtin_amdgcn_mfma_f32_16x16x32_bf16(af[mi][kk], bfv[nj][kk], acc[mi][nj], 0,0,0);
  // C/D: col = lane&15 (n), row = (lane>>4)*4 + r (m)
  if (n0 < 256) {
#pragma unroll
    for (int mi = 0; mi < 2; ++mi)
#pragma unroll
      for (int nj = 0; nj < 2; ++nj) {
        int n_g = n0 + n0w + nj*16 + lr;
#pragma unroll
        for (int r = 0; r < 4; ++r) {
          int m_g = m0 + m0w + mi*16 + kg*4 + r;
          xi[(size_t)m_g*DI + n_g] = acc[mi][nj][r];
        }
      }
  } else {
#pragma unroll
    for (int mi = 0; mi < 2; ++mi)
#pragma unroll
      for (int nj = 0; nj < 2; ++nj) {
        int n_g = (n0 - 256) + n0w + nj*16 + lr;
#pragma unroll
        for (int r = 0; r < 4; ++r) {
          int m_g = m0 + m0w + mi*16 + kg*4 + r;
          zzb[(size_t)m_g*DI + n_g] = f2bf(acc[mi][nj][r]);
        }
      }
  }
}

// ---------------------------------------------------------------------------
// K2: conv4+SiLU -> xc (phase1, also to LDS A-plane); x_proj MFMA (phase2,
// dt_r -> LDS, B/C -> global); dt = softplus(dt_r@dtw+b) (phase3).
// xc and dt stored PACKED: one uint per (l,d): lo = xc bf16, hi = dt bf16.
// ---------------------------------------------------------------------------
__global__ __launch_bounds__(256) void k_conv_xproj(
  const float* __restrict__ xi,
  const float* __restrict__ cwf, const float* __restrict__ cbf,
  const float* __restrict__ cwb, const float* __restrict__ cbb,
  const unsigned short* __restrict__ xwbf,   // [2][48][256] bf16
  const float* __restrict__ dtwf, const float* __restrict__ dtbf,
  const float* __restrict__ dtwb, const float* __restrict__ dtbb,
  float* __restrict__ Bm, float* __restrict__ Cm,
  unsigned int* __restrict__ xdt)
{
  __shared__ char lds[57344];   // A: 64x512B @0; W: 48x512B @32768
  __shared__ float dtr_s[64][8];
  const int tid = threadIdx.x, bid = blockIdx.x;
  const int lt = bid & (LSEQ/64 - 1);
  const int b  = (bid >> 7) & 3;
  const int dir = bid >> 9;
  const int l0 = lt*64;
  const int db = dir*NB + b;
  const unsigned short* xwp = xwbf + dir*48*256;
#pragma unroll
  for (int i = 0; i < 6; ++i) {
    int u = tid + i*256;
    int row = u >> 5, s = u & 31;
    *(uint4*)(lds + 32768 + row*512 + ((s ^ (row & 7))<<4)) =
        *(const uint4*)(xwp + row*256 + s*8);
  }
  const float* cw  = dir ? cwb : cwf;
  const float* cbp = dir ? cbb : cbf;
  const int d = tid;
  const float w0 = cw[d*4+0], w1 = cw[d*4+1], w2 = cw[d*4+2], w3 = cw[d*4+3];
  const float bias = cbp[d];
  const int g0 = dir ? (LSEQ-1-l0) : l0;
  const int stp = dir ? -DI : DI;
  const float* xp = xi + (size_t)(b*LSEQ)*DI + d + (size_t)g0*DI;
  unsigned short* xdt_us = (unsigned short*)xdt;
  const size_t obase = ((size_t)(db*LSEQ + l0))*DI + d;
  float h3 = 0.f, h2 = 0.f, h1 = 0.f;
  if (l0 >= 3) { h3 = xp[-3*stp]; h2 = xp[-2*stp]; h1 = xp[-1*stp]; }
  float r0 = xp[0], r1 = xp[stp], r2 = xp[2*stp], r3 = xp[3*stp];
  for (int j = 0; j < 64; j += 4) {
    float v0 = r0, v1 = r1, v2 = r2, v3 = r3;
    if (j + 4 < 64) {
      const float* q = xp + (j+4)*stp;
      r0 = q[0]; r1 = q[stp]; r2 = q[2*stp]; r3 = q[3*stp];
    }
#pragma unroll
    for (int u = 0; u < 4; ++u) {
      float vv = (u==0)?v0:(u==1)?v1:(u==2)?v2:v3;
      float a = bias + w0*h3 + w1*h2 + w2*h1 + w3*vv;
      int row = j + u;
      unsigned short xcb = f2bf(fsilu(a));
      *(unsigned short*)(lds + row*512 + ((((d>>3) ^ (row&7))<<4) + ((d&7)<<1))) = xcb;
      xdt_us[(obase + (size_t)row*DI)*2] = xcb;
      h3 = h2; h2 = h1; h1 = vv;
    }
  }
  __syncthreads();
  // ---- phase 2: MFMA [64 rows] x [48 cols], K=256 ----
  const int wid = tid >> 6, lane = tid & 63;
  const int lr = lane & 15, kg = lane >> 4;
  const int arow = wid*16 + lr;
  f32x4 acc[3];
#pragma unroll
  for (int j = 0; j < 3; ++j) acc[j] = 0.f;
#pragma unroll
  for (int t = 0; t < 8; ++t) {
    bf16x8 afv = *(const bf16x8*)(lds + arow*512 + (((t*4+kg) ^ (arow&7))<<4));
#pragma unroll
    for (int j = 0; j < 3; ++j) {
      int wrow = j*16 + lr;
      bf16x8 bfr = *(const bf16x8*)(lds + 32768 + wrow*512 + (((t*4+kg) ^ (wrow&7))<<4));
      acc[j] = __builtin_amdgcn_mfma_f32_16x16x32_bf16(afv, bfr, acc[j], 0,0,0);
    }
  }
  const int base_l = (db*LSEQ + l0) + wid*16 + kg*4;
  const int rloc = wid*16 + kg*4;
#pragma unroll
  for (int j = 0; j < 3; ++j) {
    int col = j*16 + lr;
#pragma unroll
    for (int r = 0; r < 4; ++r) {
      float v = acc[j][r];
      if (col < 8)       dtr_s[rloc + r][col] = v;
      else if (col < 24) Bm[(size_t)(base_l + r)*NS + col - 8] = v;
      else if (col < 40) Cm[(size_t)(base_l + r)*NS + col - 24] = v;
    }
  }
  __syncthreads();
  // ---- phase 3: dt = softplus(dtr @ dtw[d] + b[d]) ----
  const float* dtw = dir ? dtwb : dtwf;
  const float* dtbp= dir ? dtbb : dtbf;
  float dwv[8];
  *(float4*)(dwv+0) = *(const float4*)&dtw[d*RK];
  *(float4*)(dwv+4) = *(const float4*)&dtw[d*RK+4];
  const float dtbv = dtbp[d];
  for (int row = 0; row < 64; ++row) {
    float sd = dtbv;
#pragma unroll
    for (int r = 0; r < RK; ++r) sd = fmaf(dtr_s[row][r], dwv[r], sd);
    xdt_us[(obase + (size_t)row*DI)*2 + 1] = f2bf(fsoftplus(sd));
  }
}

// ---------------------------------------------------------------------------
// K3: chunk-local scan from h=0 -> h_local (bf16) + sum(dt).
// Streams packed xc/dt; exp power-chain (runtime-verified, fallback kept).
// ---------------------------------------------------------------------------
__global__ __launch_bounds__(256) void k_scan_local(
  const unsigned int* __restrict__ xdt, const float* __restrict__ Bm,
  const float* __restrict__ alogf, const float* __restrict__ alogb,
  unsigned short* __restrict__ hloc, float* __restrict__ sumdt)
{
  __shared__ float Bc[LC][NS];
  const int tid = threadIdx.x, bid = blockIdx.x;
  const int c = bid & (NCH-1), b = (bid>>8)&3, dir = bid>>10;
  const int db = dir*NB + b;
  const int l0 = c*LC;
  for (int i = tid; i < LC*NS; i += 256) (&Bc[0][0])[i] = Bm[(size_t)(db*LSEQ + l0)*NS + i];
  const float* alog = dir ? alogb : alogf;
  const int d = tid;
  float A2[NS];
#pragma unroll
  for (int n = 0; n < NS; ++n) A2[n] = -fexpn(alog[d*NS+n]) * LOG2E;
  const float a20 = A2[0];
  bool pw = true;
#pragma unroll
  for (int n = 1; n < NS; ++n) pw = pw && (fabsf(A2[n] - (n+1)*a20) <= 1e-3f*fabsf(A2[n]));
  float h[NS];
#pragma unroll
  for (int n = 0; n < NS; ++n) h[n] = 0.f;
  const unsigned int* xp = xdt + (size_t)(db*LSEQ + l0)*DI + d;
  unsigned int u0 = xp[0], u1 = xp[DI], u2 = xp[2*DI], u3 = xp[3*DI];
  __syncthreads();
  float sac = 0.f;
  for (int j = 0; j < LC; j += 4) {
    unsigned int w0=u0, w1=u1, w2=u2, w3=u3;
    if (j + 4 < LC) {
      const unsigned int* q = xp + (size_t)(j+4)*DI;
      u0=q[0]; u1=q[DI]; u2=q[2*DI]; u3=q[3*DI];
    }
#pragma unroll
    for (int u = 0; u < 4; ++u) {
      unsigned int uu = (u==0)?w0:(u==1)?w1:(u==2)?w2:w3;
      float xc = __uint_as_float(uu << 16);
      float dt = __uint_as_float(uu & 0xffff0000u);
      sac += dt;
      float dx = dt*xc;
      float bb[NS];
      *(float4*)(bb+0)  = *(const float4*)&Bc[j+u][0];
      *(float4*)(bb+4)  = *(const float4*)&Bc[j+u][4];
      *(float4*)(bb+8)  = *(const float4*)&Bc[j+u][8];
      *(float4*)(bb+12) = *(const float4*)&Bc[j+u][12];
      float earr[NS];
      if (pw) {
        float e1 = fexp2(a20*dt);
        float e = e1; earr[0] = e;
#pragma unroll
        for (int n = 1; n < NS; ++n) { e *= e1; earr[n] = e; }
      } else {
#pragma unroll
        for (int n = 0; n < NS; ++n) earr[n] = fexp2(A2[n]*dt);
      }
#pragma unroll
      for (int n = 0; n < NS; ++n) h[n] = fmaf(h[n], earr[n], dx*bb[n]);
    }
  }
  // pack h -> bf16, 32B store
  unsigned int hp8[8];
#pragma unroll
  for (int k = 0; k < 8; ++k)
    hp8[k] = (unsigned int)f2bf(h[2*k]) | ((unsigned int)f2bf(h[2*k+1]) << 16);
  unsigned short* dst = hloc + ((size_t)(db*NCH + c)*DI + d)*NS;
  *(uint4*)(dst)   = *(uint4*)(hp8);
  *(uint4*)(dst+8) = *(uint4*)(hp8+4);
  sumdt[(size_t)(db*NCH + c)*DI + d] = sac;
}

// ---------------------------------------------------------------------------
// K4: sequential prefix over chunks (bf16 h, fp32 carry), 16-deep prefetch,
// IN-PLACE: hloc[c] becomes h_in[c].
// ---------------------------------------------------------------------------
__global__ __launch_bounds__(64) void k_prefix(
  unsigned short* __restrict__ hloc, const float* __restrict__ sumdt,
  const float* __restrict__ alogf, const float* __restrict__ alogb)
{
  const int gid = blockIdx.x*64 + threadIdx.x;   // 32768
  const int n = gid & 15;
  const int d = (gid >> 4) & 255;
  const int db = gid >> 12;
  const float* alog = (db >= NB) ? alogb : alogf;
  const float a2 = -fexpn(alog[d*NS+n]) * LOG2E;
  const int HS = DI*NS;                          // per-chunk stride (ushorts)
  unsigned short* hp = hloc + (size_t)db*NCH*HS + d*NS + n;
  const float* sp = sumdt + (size_t)db*NCH*DI + d;
  float hr = 0.f;
  float bl[16], bs[16];
#pragma unroll
  for (int j = 0; j < 16; ++j) { bl[j] = bf2f(hp[(size_t)j*HS]); bs[j] = sp[(size_t)j*DI]; }
  for (int blk = 0; blk < NCH/16; ++blk) {
    float nl[16], nsv[16];
    if (blk < NCH/16 - 1) {
#pragma unroll
      for (int j = 0; j < 16; ++j) {
        nl[j]  = bf2f(hp[(size_t)(blk*16+16+j)*HS]);
        nsv[j] = sp[(size_t)(blk*16+16+j)*DI];
      }
    }
#pragma unroll
    for (int j = 0; j < 16; ++j) {
      float hl = bl[j];
      hp[(size_t)(blk*16+j)*HS] = f2bf(hr);
      hr = fmaf(fexp2(a2*bs[j]), hr, hl);
    }
    if (blk < NCH/16 - 1) {
#pragma unroll
      for (int j = 0; j < 16; ++j) { bl[j] = nl[j]; bs[j] = nsv[j]; }
    }
  }
}

// ---------------------------------------------------------------------------
// K5: rescan from h_in producing y, + D-skip, * SiLU(z) -> s (bf16).
// Streams packed xc/dt and bf16 z.
// ---------------------------------------------------------------------------
__global__ __launch_bounds__(256) void k_scan_out(
  const unsigned int* __restrict__ xdt, const unsigned short* __restrict__ zzb,
  const float* __restrict__ Bm, const float* __restrict__ Cm,
  const unsigned short* __restrict__ hinb,
  const float* __restrict__ alogf, const float* __restrict__ alogb,
  const float* __restrict__ Dskf, const float* __restrict__ Dskb,
  unsigned short* __restrict__ s2bf)
{
  __shared__ float Bc[LC][NS];
  __shared__ float Cc[LC][NS];
  const int tid = threadIdx.x, bid = blockIdx.x;
  const int c = bid & (NCH-1), b = (bid>>8)&3, dir = bid>>10;
  const int db = dir*NB + b;
  const int l0 = c*LC;
  for (int i = tid; i < LC*NS; i += 256) (&Bc[0][0])[i] = Bm[(size_t)(db*LSEQ + l0)*NS + i];
  for (int i = tid; i < LC*NS; i += 256) (&Cc[0][0])[i] = Cm[(size_t)(db*LSEQ + l0)*NS + i];
  const float* alog = dir ? alogb : alogf;
  const int d = tid;
  const float Dd = (dir ? Dskb : Dskf)[d];
  float A2[NS];
#pragma unroll
  for (int n = 0; n < NS; ++n) A2[n] = -fexpn(alog[d*NS+n]) * LOG2E;
  const float a20 = A2[0];
  bool pw = true;
#pragma unroll
  for (int n = 1; n < NS; ++n) pw = pw && (fabsf(A2[n] - (n+1)*a20) <= 1e-3f*fabsf(A2[n]));
  // h_in (bf16 -> fp32)
  float h[NS];
  {
    const unsigned short* hb = hinb + ((size_t)(db*NCH + c)*DI + d)*NS;
    uint4 p0 = *(const uint4*)(hb);
    uint4 p1 = *(const uint4*)(hb+8);
    unsigned int w[8] = {p0.x,p0.y,p0.z,p0.w,p1.x,p1.y,p1.z,p1.w};
#pragma unroll
    for (int k = 0; k < 8; ++k) {
      h[2*k]   = __uint_as_float(w[k] << 16);
      h[2*k+1] = __uint_as_float(w[k] & 0xffff0000u);
    }
  }
  const int g0 = dir ? (LSEQ-1-l0) : l0;
  const int stp = dir ? -DI : DI;
  const unsigned int* xp = xdt + (size_t)(db*LSEQ + l0)*DI + d;
  const unsigned short* zp = zzb + (size_t)(b*LSEQ + g0)*DI + d;
  unsigned short* sp = s2bf + (size_t)(db*LSEQ + l0)*DI + d;
  unsigned int u0 = xp[0], u1 = xp[DI], u2 = xp[2*DI], u3 = xp[3*DI];
  unsigned short z0 = zp[0], z1 = zp[stp], z2 = zp[2*stp], z3 = zp[3*stp];
  __syncthreads();
  for (int j = 0; j < LC; j += 4) {
    unsigned int w0=u0, w1=u1, w2=u2, w3=u3;
    unsigned short y0=z0, y1=z1, y2=z2, y3=z3;
    if (j + 4 < LC) {
      const unsigned int* q = xp + (size_t)(j+4)*DI;
      u0=q[0]; u1=q[DI]; u2=q[2*DI]; u3=q[3*DI];
      const unsigned short* qz = zp + (j+4)*stp;
      z0=qz[0]; z1=qz[stp]; z2=qz[2*stp]; z3=qz[3*stp];
    }
#pragma unroll
    for (int u = 0; u < 4; ++u) {
      unsigned int uu = (u==0)?w0:(u==1)?w1:(u==2)?w2:w3;
      unsigned short zu = (u==0)?y0:(u==1)?y1:(u==2)?y2:y3;
      float xc = __uint_as_float(uu << 16);
      float dt = __uint_as_float(uu & 0xffff0000u);
      float dx = dt*xc;
      float bb[NS], ccv[NS];
      *(float4*)(bb+0)  = *(const float4*)&Bc[j+u][0];
      *(float4*)(bb+4)  = *(const float4*)&Bc[j+u][4];
      *(float4*)(bb+8)  = *(const float4*)&Bc[j+u][8];
      *(float4*)(bb+12) = *(const float4*)&Bc[j+u][12];
      *(float4*)(ccv+0)  = *(const float4*)&Cc[j+u][0];
      *(float4*)(ccv+4)  = *(const float4*)&Cc[j+u][4];
      *(float4*)(ccv+8)  = *(const float4*)&Cc[j+u][8];
      *(float4*)(ccv+12) = *(const float4*)&Cc[j+u][12];
      float earr[NS];
      if (pw) {
        float e1 = fexp2(a20*dt);
        float e = e1; earr[0] = e;
#pragma unroll
        for (int n = 1; n < NS; ++n) { e *= e1; earr[n] = e; }
      } else {
#pragma unroll
        for (int n = 0; n < NS; ++n) earr[n] = fexp2(A2[n]*dt);
      }
      float yv = 0.f;
#pragma unroll
      for (int n = 0; n < NS; ++n) {
        h[n] = fmaf(h[n], earr[n], dx*bb[n]);
        yv = fmaf(h[n], ccv[n], yv);
      }
      yv = fmaf(xc, Dd, yv);
      float zv = bf2f(zu);
      sp[(size_t)(j+u)*DI] = f2bf(yv * fsilu(zv));
    }
  }
}

// ---------------------------------------------------------------------------
// K6: MFMA out_proj. (sF + rev(sB)) @ W^T == [sF | rev(sB)] @ [W;W]^T.
// Epilogue: +residual, LN2, transposed store.
// ---------------------------------------------------------------------------
__global__ __launch_bounds__(512) void k_out(
  const unsigned short* __restrict__ s2bf,  // [2][NB][LSEQ][DI] bf16
  const unsigned short* __restrict__ wopbf, // [DM][DI] bf16
  const float* __restrict__ x, const float* __restrict__ ln2w, const float* __restrict__ ln2b,
  float* __restrict__ out)
{
  __shared__ char lds[65536];
  const int tid = threadIdx.x;
  const int m0 = blockIdx.x*64;
  const int b = m0 >> 13, l0 = m0 & (LSEQ-1);
  const unsigned short* sF = s2bf + (size_t)b*LSEQ*DI;
  const unsigned short* sB = s2bf + (size_t)(NB + b)*LSEQ*DI;
#pragma unroll
  for (int i = 0; i < 8; ++i) {
    int u = tid + i*512;
    int row = u >> 6, c = u & 63;
    int l = l0 + row;
    const unsigned short* src = (c < 32) ? (sF + (size_t)l*DI + c*8)
                                         : (sB + (size_t)(LSEQ-1-l)*DI + (c-32)*8);
    *(uint4*)(lds + row*1024 + ((c ^ (row & 7))<<4)) = *(const uint4*)src;
  }
  const int wid = tid >> 6;
  const int wr = wid >> 2, wc = wid & 3;
  const int lane = tid & 63, lr = lane & 15, kg = lane >> 4;
  bf16x8 wf[2][8];
#pragma unroll
  for (int nt = 0; nt < 2; ++nt) {
    int n = wc*32 + nt*16 + lr;
#pragma unroll
    for (int kt = 0; kt < 8; ++kt)
      wf[nt][kt] = *(const bf16x8*)(wopbf + n*DI + kt*32 + kg*8);
  }
  __syncthreads();
  f32x4 acc[2][2];
#pragma unroll
  for (int mt = 0; mt < 2; ++mt)
#pragma unroll
    for (int nt = 0; nt < 2; ++nt) acc[mt][nt] = 0.f;
#pragma unroll
  for (int kt2 = 0; kt2 < 16; ++kt2) {
#pragma unroll
    for (int mt = 0; mt < 2; ++mt) {
      int row = wr*32 + mt*16 + lr;
      int slot = (kt2*4 + kg) ^ (row & 7);
      bf16x8 af = *(const bf16x8*)(lds + row*1024 + (slot<<4));
#pragma unroll
      for (int nt = 0; nt < 2; ++nt)
        acc[mt][nt] = __builtin_amdgcn_mfma_f32_16x16x32_bf16(af, wf[nt][kt2 & 7], acc[mt][nt], 0,0,0);
    }
  }
  __syncthreads();
  float* smem = (float*)lds;
  const int RP = 133;
  float* mS = smem + 64*RP;
  float* rS = mS + 64;
  const float* xb = x + b*DM*LSEQ + l0;
#pragma unroll
  for (int mt = 0; mt < 2; ++mt) {
    int mbase = wr*32 + mt*16 + kg*4;
#pragma unroll
    for (int nt = 0; nt < 2; ++nt) {
      int n = wc*32 + nt*16 + lr;
      float4 rx = *(const float4*)&xb[n*LSEQ + mbase];
      smem[(mbase+0)*RP + n] = acc[mt][nt][0] + rx.x;
      smem[(mbase+1)*RP + n] = acc[mt][nt][1] + rx.y;
      smem[(mbase+2)*RP + n] = acc[mt][nt][2] + rx.z;
      smem[(mbase+3)*RP + n] = acc[mt][nt][3] + rx.w;
    }
  }
  __syncthreads();
  {
    int row = tid >> 3, p = tid & 7;
    float s = 0.f, q = 0.f;
#pragma unroll
    for (int jj = 0; jj < 16; ++jj) {
      float v = smem[row*RP + p*16 + jj];
      s += v; q += v*v;
    }
    s += __shfl_xor(s,1); s += __shfl_xor(s,2); s += __shfl_xor(s,4);
    q += __shfl_xor(q,1); q += __shfl_xor(q,2); q += __shfl_xor(q,4);
    if (p == 0) {
      float m = s*(1.f/DM);
      float var = q*(1.f/DM) - m*m;
      mS[row] = m; rS[row] = rsqrtf(var + 1e-5f);
    }
  }
  __syncthreads();
  float* ob = out + b*DM*LSEQ + l0;
#pragma unroll
  for (int i = 0; i < 16; ++i) {
    int idx = tid + i*512;
    int col = idx >> 6, l = idx & 63;
    float v = (smem[l*RP + col] - mS[l])*rS[l]*ln2w[col] + ln2b[col];
    ob[col*LSEQ + l] = v;
  }
}

// ---------------------------------------------------------------------------
extern "C" void kernel_launch(void* const* d_in, const int* in_sizes, int n_in,
                              void* d_out, int out_size, void* d_ws, size_t ws_size,
                              hipStream_t stream)
{
  (void)in_sizes; (void)n_in; (void)out_size; (void)ws_size;
  const float* x     = (const float*)d_in[0];
  const float* ln1w  = (const float*)d_in[1];
  const float* ln1b  = (const float*)d_in[2];
  const float* ln2w  = (const float*)d_in[3];
  const float* ln2b  = (const float*)d_in[4];
  const float* wip   = (const float*)d_in[5];
  const float* wop   = (const float*)d_in[6];
  const float* cwf   = (const float*)d_in[7];
  const float* cbf   = (const float*)d_in[8];
  const float* xwf   = (const float*)d_in[9];
  const float* dtwf  = (const float*)d_in[10];
  const float* dtbf  = (const float*)d_in[11];
  const float* alogf = (const float*)d_in[12];
  const float* Dskf  = (const float*)d_in[13];
  const float* cwb   = (const float*)d_in[14];
  const float* cbb   = (const float*)d_in[15];
  const float* xwb   = (const float*)d_in[16];
  const float* dtwb  = (const float*)d_in[17];
  const float* dtbb  = (const float*)d_in[18];
  const float* alogb = (const float*)d_in[19];
  const float* Dskb  = (const float*)d_in[20];

  // workspace layout (float units)
  // zzb spans MTOT*DI bf16 = 8,388,608 ushort = 4,194,304 float-units (FIXED:
  // round 6 reserved only half of this, overflowing into Bm/Cm -> NaN).
  float* ws    = (float*)d_ws;
  float* xi    = ws;                    //  8,388,608
  float* zzbF  = xi    + 8388608;       //  4,194,304 (zzb: 8.4M ushort)
  float* Bm    = zzbF  + 4194304;       //  1,048,576
  float* Cm    = Bm    + 1048576;       //  1,048,576
  float* s2F   = Cm    + 1048576;       //  8,388,608 (s2bf: 16.8M ushort)
  float* xdtF  = s2F   + 8388608;       // 16,777,216 (packed uint xc|dt)
  float* hlocF = xdtF  + 16777216;      //  4,194,304 (bf16: 8.4M ushort)
  float* sumdt = hlocF + 4194304;       //    524,288
  float* xwbfF = sumdt + 524288;        //     12,288 (24,576 bf16)
  float* wopbfF= xwbfF + 12288;         //     16,384 (32,768 bf16)
  float* out   = (float*)d_out;
  // aliases in s2F region (fully rewritten by k_scan_out each call):
  unsigned short* xnbf  = (unsigned short*)s2F;             // 4,194,304 ush
  unsigned short* wipbf = (unsigned short*)(s2F + 2097152); //    65,536 ush
  unsigned short* s2bf  = (unsigned short*)s2F;
  unsigned short* zzb   = (unsigned short*)zzbF;
  unsigned int*   xdt   = (unsigned int*)xdtF;
  unsigned short* hloc  = (unsigned short*)hlocF;
  unsigned short* xwbf  = (unsigned short*)xwbfF;
  unsigned short* wopbf = (unsigned short*)wopbfF;

  k_prep_w<<<480, 256, 0, stream>>>(wip, wipbf, xwf, xwb, xwbf, wop, wopbf);
  k_ln<<<512, 256, 0, stream>>>(x, ln1w, ln1b, xnbf);
  k_gemm_in<<<dim3(512,8), 256, 0, stream>>>(xnbf, wipbf, xi, zzb);
  k_conv_xproj<<<1024, 256, 0, stream>>>(xi, cwf,cbf,cwb,cbb, xwbf,
                                         dtwf,dtbf,dtwb,dtbb, Bm, Cm, xdt);
  k_scan_local<<<2048, 256, 0, stream>>>(xdt, Bm, alogf, alogb, hloc, sumdt);
  k_prefix<<<512, 64, 0, stream>>>(hloc, sumdt, alogf, alogb);
  k_scan_out<<<2048, 256, 0, stream>>>(xdt, zzb, Bm, Cm, hloc,
                                       alogf, alogb, Dskf, Dskb, s2bf);
  k_out<<<512, 512, 0, stream>>>(s2bf, wopbf, x, ln2w, ln2b, out);
}

// Round 8
// 167.168 us; speedup vs baseline: 2.2891x; 1.1020x over previous
//
#include <hip/hip_runtime.h>

// MambaLayer bidirectional selective-scan (bf16 MFMA GEMMs, packed xc/dt scan).
// Shapes: B=4, L=8192, d_model=128, d_inner=256, d_state=16, dt_rank=8.
#define NB   4
#define LSEQ 8192
#define DM   128
#define DI   256
#define NS   16
#define RK   8
#define NCH  256          // chunks over L
#define LC   32           // L / NCH
#define MTOT (NB*LSEQ)
#define LOG2E 1.44269504088896340736f
#define LN2f  0.69314718055994530942f

#if __has_builtin(__builtin_amdgcn_exp2f)
__device__ __forceinline__ float fexp2(float x){ return __builtin_amdgcn_exp2f(x); }
#else
__device__ __forceinline__ float fexp2(float x){ return exp2f(x); }
#endif
#if __has_builtin(__builtin_amdgcn_logf)
__device__ __forceinline__ float flog2(float x){ return __builtin_amdgcn_logf(x); }
#else
__device__ __forceinline__ float flog2(float x){ return log2f(x); }
#endif
#if __has_builtin(__builtin_amdgcn_rcpf)
__device__ __forceinline__ float frcp(float x){ return __builtin_amdgcn_rcpf(x); }
#else
__device__ __forceinline__ float frcp(float x){ return 1.f/x; }
#endif
__device__ __forceinline__ float fexpn(float x){ return fexp2(x*LOG2E); }
__device__ __forceinline__ float fsilu(float x){ return x*frcp(1.f + fexpn(-x)); }
__device__ __forceinline__ float fsoftplus(float x){
  return fmaxf(x,0.f) + flog2(1.f + fexpn(-fabsf(x)))*LN2f;
}

__device__ __forceinline__ unsigned short f2bf(float v){
  unsigned int u = __float_as_uint(v);
  return (unsigned short)((u + 0x7FFFu + ((u >> 16) & 1u)) >> 16);
}
__device__ __forceinline__ float bf2f(unsigned short h){
  return __uint_as_float(((unsigned int)h) << 16);
}

typedef __attribute__((ext_vector_type(8))) short bf16x8;
typedef __attribute__((ext_vector_type(4))) float f32x4;

// ---------------------------------------------------------------------------
// K0: weights -> bf16: in_proj [512][128]; x_proj padded [2][48][256];
// out_proj [128][256].
// ---------------------------------------------------------------------------
__global__ __launch_bounds__(256) void k_prep_w(
    const float* __restrict__ wip, unsigned short* __restrict__ wipbf,
    const float* __restrict__ xwf, const float* __restrict__ xwb, unsigned short* __restrict__ xwbf,
    const float* __restrict__ wop, unsigned short* __restrict__ wopbf)
{
  int i = blockIdx.x*256 + threadIdx.x;      // 0..122879
  if (i < 65536) {
    wipbf[i] = f2bf(wip[i]);
  } else if (i < 90112) {
    int j = i - 65536;                       // 0..24575
    int dirw = j / 12288;
    int rem = j - dirw*12288;
    int row = rem >> 8, k = rem & 255;
    const float* src = dirw ? xwb : xwf;
    xwbf[j] = (row < 40) ? f2bf(src[row*256 + k]) : (unsigned short)0;
  } else {
    int j = i - 90112;                       // 0..32767
    wopbf[j] = f2bf(wop[j]);
  }
}

// ---------------------------------------------------------------------------
// K1a: LN1 -> xn bf16 [MTOT][128]. Reads x [B,128,L] coalesced.
// ---------------------------------------------------------------------------
__global__ __launch_bounds__(256) void k_ln(
    const float* __restrict__ x, const float* __restrict__ ln1w, const float* __restrict__ ln1b,
    unsigned short* __restrict__ xnbf)
{
  __shared__ float a_s[DM][65];
  __shared__ float mS[64], rS[64];
  const int tid = threadIdx.x;
  const int m0 = blockIdx.x * 64;
  const int b = m0 >> 13, l0 = m0 & (LSEQ-1);
  const float* xb = x + b*DM*LSEQ;
#pragma unroll
  for (int i = 0; i < 32; ++i) {
    int idx = tid + i*256;
    int d = idx >> 6, l = idx & 63;
    a_s[d][l] = xb[d*LSEQ + l0 + l];
  }
  __syncthreads();
  {
    int p = tid & 3, l = tid >> 2;
    float s = 0.f, q = 0.f;
#pragma unroll
    for (int jj = 0; jj < 32; ++jj) {
      float v = a_s[p + 4*jj][l];
      s += v; q += v*v;
    }
    s += __shfl_xor(s,1); s += __shfl_xor(s,2);
    q += __shfl_xor(q,1); q += __shfl_xor(q,2);
    float m = s*(1.f/DM);
    float var = q*(1.f/DM) - m*m;
    if (p == 0) { mS[l] = m; rS[l] = rsqrtf(var + 1e-5f); }
  }
  __syncthreads();
#pragma unroll
  for (int i = 0; i < 32; ++i) {
    int idx = tid + i*256;
    int l = idx >> 7, d = idx & 127;
    float v = (a_s[d][l] - mS[l])*rS[l]*ln1w[d] + ln1b[d];
    xnbf[(m0+l)*DM + d] = f2bf(v);
  }
}

// ---------------------------------------------------------------------------
// K1b: in_proj GEMM via bf16 MFMA (single plane). Tile 64x64, K=128.
// Both halves stored bf16: n0<256 -> xib; n0>=256 -> zzb.
// ---------------------------------------------------------------------------
__global__ __launch_bounds__(256) void k_gemm_in(
    const unsigned short* __restrict__ xnbf, const unsigned short* __restrict__ wipbf,
    unsigned short* __restrict__ xib, unsigned short* __restrict__ zzb)
{
  __shared__ char lds[32768];                 // 2 planes x 16KB (64 rows x 128 bf16)
  const int tid = threadIdx.x;
  const int m0 = blockIdx.x * 64;
  const int n0 = blockIdx.y * 64;
  const unsigned short* srcs[2] = { xnbf + m0*DM, wipbf + n0*DM };
#pragma unroll
  for (int p = 0; p < 2; ++p) {
#pragma unroll
    for (int i = 0; i < 4; ++i) {
      int u = tid + i*256;                    // 16B unit within plane
      int row = u >> 4, c = u & 15;
      int dstu = p*1024 + row*16 + (c ^ (row & 7));
      *(uint4*)(lds + dstu*16) = *(const uint4*)(srcs[p] + row*DM + c*8);
    }
  }
  __syncthreads();
  const int wid = tid >> 6, lane = tid & 63;
  const int m0w = (wid & 1)*32, n0w = (wid >> 1)*32;
  const int lr = lane & 15, kg = lane >> 4;
  bf16x8 af[2][4], bfv[2][4];
#pragma unroll
  for (int mi = 0; mi < 2; ++mi) {
    int row = m0w + mi*16 + lr;
#pragma unroll
    for (int kk = 0; kk < 4; ++kk) {
      int slot = (kk*4 + kg) ^ (row & 7);
      af[mi][kk] = *(const bf16x8*)(lds + row*256 + slot*16);
    }
  }
#pragma unroll
  for (int nj = 0; nj < 2; ++nj) {
    int row = n0w + nj*16 + lr;
#pragma unroll
    for (int kk = 0; kk < 4; ++kk) {
      int slot = (kk*4 + kg) ^ (row & 7);
      bfv[nj][kk] = *(const bf16x8*)(lds + 16384 + row*256 + slot*16);
    }
  }
  f32x4 acc[2][2];
#pragma unroll
  for (int mi = 0; mi < 2; ++mi)
#pragma unroll
    for (int nj = 0; nj < 2; ++nj) acc[mi][nj] = 0.f;
#pragma unroll
  for (int kk = 0; kk < 4; ++kk)
#pragma unroll
    for (int mi = 0; mi < 2; ++mi)
#pragma unroll
      for (int nj = 0; nj < 2; ++nj)
        acc[mi][nj] = __builtin_amdgcn_mfma_f32_16x16x32_bf16(af[mi][kk], bfv[nj][kk], acc[mi][nj], 0,0,0);
  // C/D: col = lane&15 (n), row = (lane>>4)*4 + r (m)
  unsigned short* base = (n0 < 256) ? xib : zzb;
  const int ncol0 = n0 & 255;
#pragma unroll
  for (int mi = 0; mi < 2; ++mi)
#pragma unroll
    for (int nj = 0; nj < 2; ++nj) {
      int n_g = ncol0 + n0w + nj*16 + lr;
#pragma unroll
      for (int r = 0; r < 4; ++r) {
        int m_g = m0 + m0w + mi*16 + kg*4 + r;
        base[(size_t)m_g*DI + n_g] = f2bf(acc[mi][nj][r]);
      }
    }
}

// ---------------------------------------------------------------------------
// K2: conv4+SiLU -> xc into LDS A-plane (phase1); x_proj MFMA (phase2,
// dt_r -> LDS, B/C -> global); phase3: dt = softplus(dt_r@dtw+b), read xc
// back from LDS, ONE packed 4B store per (l,d): lo = xc bf16, hi = dt bf16.
// (Round 7 wrote xc and dt as separate 2B stores -> 2x write amplification.)
// ---------------------------------------------------------------------------
__global__ __launch_bounds__(256) void k_conv_xproj(
  const unsigned short* __restrict__ xib,
  const float* __restrict__ cwf, const float* __restrict__ cbf,
  const float* __restrict__ cwb, const float* __restrict__ cbb,
  const unsigned short* __restrict__ xwbf,   // [2][48][256] bf16
  const float* __restrict__ dtwf, const float* __restrict__ dtbf,
  const float* __restrict__ dtwb, const float* __restrict__ dtbb,
  float* __restrict__ Bm, float* __restrict__ Cm,
  unsigned int* __restrict__ xdt)
{
  __shared__ char lds[57344];   // A: 64x512B @0; W: 48x512B @32768
  __shared__ float dtr_s[64][8];
  const int tid = threadIdx.x, bid = blockIdx.x;
  const int lt = bid & (LSEQ/64 - 1);
  const int b  = (bid >> 7) & 3;
  const int dir = bid >> 9;
  const int l0 = lt*64;
  const int db = dir*NB + b;
  const unsigned short* xwp = xwbf + dir*48*256;
#pragma unroll
  for (int i = 0; i < 6; ++i) {
    int u = tid + i*256;
    int row = u >> 5, s = u & 31;
    *(uint4*)(lds + 32768 + row*512 + ((s ^ (row & 7))<<4)) =
        *(const uint4*)(xwp + row*256 + s*8);
  }
  const float* cw  = dir ? cwb : cwf;
  const float* cbp = dir ? cbb : cbf;
  const int d = tid;
  const float w0 = cw[d*4+0], w1 = cw[d*4+1], w2 = cw[d*4+2], w3 = cw[d*4+3];
  const float bias = cbp[d];
  const int g0 = dir ? (LSEQ-1-l0) : l0;
  const int stp = dir ? -DI : DI;
  const unsigned short* xp = xib + (size_t)(b*LSEQ)*DI + d + (size_t)g0*DI;
  float h3 = 0.f, h2 = 0.f, h1 = 0.f;
  if (l0 >= 3) { h3 = bf2f(xp[-3*stp]); h2 = bf2f(xp[-2*stp]); h1 = bf2f(xp[-1*stp]); }
  float r0 = bf2f(xp[0]), r1 = bf2f(xp[stp]), r2 = bf2f(xp[2*stp]), r3 = bf2f(xp[3*stp]);
  for (int j = 0; j < 64; j += 4) {
    float v0 = r0, v1 = r1, v2 = r2, v3 = r3;
    if (j + 4 < 64) {
      const unsigned short* q = xp + (j+4)*stp;
      r0 = bf2f(q[0]); r1 = bf2f(q[stp]); r2 = bf2f(q[2*stp]); r3 = bf2f(q[3*stp]);
    }
#pragma unroll
    for (int u = 0; u < 4; ++u) {
      float vv = (u==0)?v0:(u==1)?v1:(u==2)?v2:v3;
      float a = bias + w0*h3 + w1*h2 + w2*h1 + w3*vv;
      int row = j + u;
      *(unsigned short*)(lds + row*512 + ((((d>>3) ^ (row&7))<<4) + ((d&7)<<1))) = f2bf(fsilu(a));
      h3 = h2; h2 = h1; h1 = vv;
    }
  }
  __syncthreads();
  // ---- phase 2: MFMA [64 rows] x [48 cols], K=256 ----
  const int wid = tid >> 6, lane = tid & 63;
  const int lr = lane & 15, kg = lane >> 4;
  const int arow = wid*16 + lr;
  f32x4 acc[3];
#pragma unroll
  for (int j = 0; j < 3; ++j) acc[j] = 0.f;
#pragma unroll
  for (int t = 0; t < 8; ++t) {
    bf16x8 afv = *(const bf16x8*)(lds + arow*512 + (((t*4+kg) ^ (arow&7))<<4));
#pragma unroll
    for (int j = 0; j < 3; ++j) {
      int wrow = j*16 + lr;
      bf16x8 bfr = *(const bf16x8*)(lds + 32768 + wrow*512 + (((t*4+kg) ^ (wrow&7))<<4));
      acc[j] = __builtin_amdgcn_mfma_f32_16x16x32_bf16(afv, bfr, acc[j], 0,0,0);
    }
  }
  const int base_l = (db*LSEQ + l0) + wid*16 + kg*4;
  const int rloc = wid*16 + kg*4;
#pragma unroll
  for (int j = 0; j < 3; ++j) {
    int col = j*16 + lr;
#pragma unroll
    for (int r = 0; r < 4; ++r) {
      float v = acc[j][r];
      if (col < 8)       dtr_s[rloc + r][col] = v;
      else if (col < 24) Bm[(size_t)(base_l + r)*NS + col - 8] = v;
      else if (col < 40) Cm[(size_t)(base_l + r)*NS + col - 24] = v;
    }
  }
  __syncthreads();
  // ---- phase 3: dt = softplus(dtr @ dtw[d] + b[d]); pack with xc (from LDS)
  // into ONE coalesced uint store per row.
  const float* dtw = dir ? dtwb : dtwf;
  const float* dtbp= dir ? dtbb : dtbf;
  float dwv[8];
  *(float4*)(dwv+0) = *(const float4*)&dtw[d*RK];
  *(float4*)(dwv+4) = *(const float4*)&dtw[d*RK+4];
  const float dtbv = dtbp[d];
  unsigned int* xdtp = xdt + (size_t)(db*LSEQ + l0)*DI + d;
  for (int row = 0; row < 64; ++row) {
    float sd = dtbv;
#pragma unroll
    for (int r = 0; r < RK; ++r) sd = fmaf(dtr_s[row][r], dwv[r], sd);
    unsigned short dtb = f2bf(fsoftplus(sd));
    unsigned short xcb = *(const unsigned short*)(lds + row*512 + ((((d>>3) ^ (row&7))<<4) + ((d&7)<<1)));
    xdtp[(size_t)row*DI] = (unsigned int)xcb | ((unsigned int)dtb << 16);
  }
}

// ---------------------------------------------------------------------------
// K3: chunk-local scan from h=0 -> h_local (bf16) + sum(dt).
// Streams packed xc/dt; exp power-chain (runtime-verified, fallback kept).
// ---------------------------------------------------------------------------
__global__ __launch_bounds__(256) void k_scan_local(
  const unsigned int* __restrict__ xdt, const float* __restrict__ Bm,
  const float* __restrict__ alogf, const float* __restrict__ alogb,
  unsigned short* __restrict__ hloc, float* __restrict__ sumdt)
{
  __shared__ float Bc[LC][NS];
  const int tid = threadIdx.x, bid = blockIdx.x;
  const int c = bid & (NCH-1), b = (bid>>8)&3, dir = bid>>10;
  const int db = dir*NB + b;
  const int l0 = c*LC;
  for (int i = tid; i < LC*NS; i += 256) (&Bc[0][0])[i] = Bm[(size_t)(db*LSEQ + l0)*NS + i];
  const float* alog = dir ? alogb : alogf;
  const int d = tid;
  float A2[NS];
#pragma unroll
  for (int n = 0; n < NS; ++n) A2[n] = -fexpn(alog[d*NS+n]) * LOG2E;
  const float a20 = A2[0];
  bool pw = true;
#pragma unroll
  for (int n = 1; n < NS; ++n) pw = pw && (fabsf(A2[n] - (n+1)*a20) <= 1e-3f*fabsf(A2[n]));
  float h[NS];
#pragma unroll
  for (int n = 0; n < NS; ++n) h[n] = 0.f;
  const unsigned int* xp = xdt + (size_t)(db*LSEQ + l0)*DI + d;
  unsigned int u0 = xp[0], u1 = xp[DI], u2 = xp[2*DI], u3 = xp[3*DI];
  __syncthreads();
  float sac = 0.f;
  for (int j = 0; j < LC; j += 4) {
    unsigned int w0=u0, w1=u1, w2=u2, w3=u3;
    if (j + 4 < LC) {
      const unsigned int* q = xp + (size_t)(j+4)*DI;
      u0=q[0]; u1=q[DI]; u2=q[2*DI]; u3=q[3*DI];
    }
#pragma unroll
    for (int u = 0; u < 4; ++u) {
      unsigned int uu = (u==0)?w0:(u==1)?w1:(u==2)?w2:w3;
      float xc = __uint_as_float(uu << 16);
      float dt = __uint_as_float(uu & 0xffff0000u);
      sac += dt;
      float dx = dt*xc;
      float bb[NS];
      *(float4*)(bb+0)  = *(const float4*)&Bc[j+u][0];
      *(float4*)(bb+4)  = *(const float4*)&Bc[j+u][4];
      *(float4*)(bb+8)  = *(const float4*)&Bc[j+u][8];
      *(float4*)(bb+12) = *(const float4*)&Bc[j+u][12];
      float earr[NS];
      if (pw) {
        float e1 = fexp2(a20*dt);
        float e = e1; earr[0] = e;
#pragma unroll
        for (int n = 1; n < NS; ++n) { e *= e1; earr[n] = e; }
      } else {
#pragma unroll
        for (int n = 0; n < NS; ++n) earr[n] = fexp2(A2[n]*dt);
      }
#pragma unroll
      for (int n = 0; n < NS; ++n) h[n] = fmaf(h[n], earr[n], dx*bb[n]);
    }
  }
  // pack h -> bf16, 32B store
  unsigned int hp8[8];
#pragma unroll
  for (int k = 0; k < 8; ++k)
    hp8[k] = (unsigned int)f2bf(h[2*k]) | ((unsigned int)f2bf(h[2*k+1]) << 16);
  unsigned short* dst = hloc + ((size_t)(db*NCH + c)*DI + d)*NS;
  *(uint4*)(dst)   = *(uint4*)(hp8);
  *(uint4*)(dst+8) = *(uint4*)(hp8+4);
  sumdt[(size_t)(db*NCH + c)*DI + d] = sac;
}

// ---------------------------------------------------------------------------
// K4: sequential prefix over chunks (bf16 h, fp32 carry), 16-deep prefetch,
// IN-PLACE: hloc[c] becomes h_in[c].
// ---------------------------------------------------------------------------
__global__ __launch_bounds__(64) void k_prefix(
  unsigned short* __restrict__ hloc, const float* __restrict__ sumdt,
  const float* __restrict__ alogf, const float* __restrict__ alogb)
{
  const int gid = blockIdx.x*64 + threadIdx.x;   // 32768
  const int n = gid & 15;
  const int d = (gid >> 4) & 255;
  const int db = gid >> 12;
  const float* alog = (db >= NB) ? alogb : alogf;
  const float a2 = -fexpn(alog[d*NS+n]) * LOG2E;
  const int HS = DI*NS;                          // per-chunk stride (ushorts)
  unsigned short* hp = hloc + (size_t)db*NCH*HS + d*NS + n;
  const float* sp = sumdt + (size_t)db*NCH*DI + d;
  float hr = 0.f;
  float bl[16], bs[16];
#pragma unroll
  for (int j = 0; j < 16; ++j) { bl[j] = bf2f(hp[(size_t)j*HS]); bs[j] = sp[(size_t)j*DI]; }
  for (int blk = 0; blk < NCH/16; ++blk) {
    float nl[16], nsv[16];
    if (blk < NCH/16 - 1) {
#pragma unroll
      for (int j = 0; j < 16; ++j) {
        nl[j]  = bf2f(hp[(size_t)(blk*16+16+j)*HS]);
        nsv[j] = sp[(size_t)(blk*16+16+j)*DI];
      }
    }
#pragma unroll
    for (int j = 0; j < 16; ++j) {
      float hl = bl[j];
      hp[(size_t)(blk*16+j)*HS] = f2bf(hr);
      hr = fmaf(fexp2(a2*bs[j]), hr, hl);
    }
    if (blk < NCH/16 - 1) {
#pragma unroll
      for (int j = 0; j < 16; ++j) { bl[j] = nl[j]; bs[j] = nsv[j]; }
    }
  }
}

// ---------------------------------------------------------------------------
// K5: rescan from h_in producing y, + D-skip, * SiLU(z) -> s (bf16).
// Streams packed xc/dt and bf16 z.
// ---------------------------------------------------------------------------
__global__ __launch_bounds__(256) void k_scan_out(
  const unsigned int* __restrict__ xdt, const unsigned short* __restrict__ zzb,
  const float* __restrict__ Bm, const float* __restrict__ Cm,
  const unsigned short* __restrict__ hinb,
  const float* __restrict__ alogf, const float* __restrict__ alogb,
  const float* __restrict__ Dskf, const float* __restrict__ Dskb,
  unsigned short* __restrict__ s2bf)
{
  __shared__ float Bc[LC][NS];
  __shared__ float Cc[LC][NS];
  const int tid = threadIdx.x, bid = blockIdx.x;
  const int c = bid & (NCH-1), b = (bid>>8)&3, dir = bid>>10;
  const int db = dir*NB + b;
  const int l0 = c*LC;
  for (int i = tid; i < LC*NS; i += 256) (&Bc[0][0])[i] = Bm[(size_t)(db*LSEQ + l0)*NS + i];
  for (int i = tid; i < LC*NS; i += 256) (&Cc[0][0])[i] = Cm[(size_t)(db*LSEQ + l0)*NS + i];
  const float* alog = dir ? alogb : alogf;
  const int d = tid;
  const float Dd = (dir ? Dskb : Dskf)[d];
  float A2[NS];
#pragma unroll
  for (int n = 0; n < NS; ++n) A2[n] = -fexpn(alog[d*NS+n]) * LOG2E;
  const float a20 = A2[0];
  bool pw = true;
#pragma unroll
  for (int n = 1; n < NS; ++n) pw = pw && (fabsf(A2[n] - (n+1)*a20) <= 1e-3f*fabsf(A2[n]));
  // h_in (bf16 -> fp32)
  float h[NS];
  {
    const unsigned short* hb = hinb + ((size_t)(db*NCH + c)*DI + d)*NS;
    uint4 p0 = *(const uint4*)(hb);
    uint4 p1 = *(const uint4*)(hb+8);
    unsigned int w[8] = {p0.x,p0.y,p0.z,p0.w,p1.x,p1.y,p1.z,p1.w};
#pragma unroll
    for (int k = 0; k < 8; ++k) {
      h[2*k]   = __uint_as_float(w[k] << 16);
      h[2*k+1] = __uint_as_float(w[k] & 0xffff0000u);
    }
  }
  const int g0 = dir ? (LSEQ-1-l0) : l0;
  const int stp = dir ? -DI : DI;
  const unsigned int* xp = xdt + (size_t)(db*LSEQ + l0)*DI + d;
  const unsigned short* zp = zzb + (size_t)(b*LSEQ + g0)*DI + d;
  unsigned short* sp = s2bf + (size_t)(db*LSEQ + l0)*DI + d;
  unsigned int u0 = xp[0], u1 = xp[DI], u2 = xp[2*DI], u3 = xp[3*DI];
  unsigned short z0 = zp[0], z1 = zp[stp], z2 = zp[2*stp], z3 = zp[3*stp];
  __syncthreads();
  for (int j = 0; j < LC; j += 4) {
    unsigned int w0=u0, w1=u1, w2=u2, w3=u3;
    unsigned short y0=z0, y1=z1, y2=z2, y3=z3;
    if (j + 4 < LC) {
      const unsigned int* q = xp + (size_t)(j+4)*DI;
      u0=q[0]; u1=q[DI]; u2=q[2*DI]; u3=q[3*DI];
      const unsigned short* qz = zp + (j+4)*stp;
      z0=qz[0]; z1=qz[stp]; z2=qz[2*stp]; z3=qz[3*stp];
    }
#pragma unroll
    for (int u = 0; u < 4; ++u) {
      unsigned int uu = (u==0)?w0:(u==1)?w1:(u==2)?w2:w3;
      unsigned short zu = (u==0)?y0:(u==1)?y1:(u==2)?y2:y3;
      float xc = __uint_as_float(uu << 16);
      float dt = __uint_as_float(uu & 0xffff0000u);
      float dx = dt*xc;
      float bb[NS], ccv[NS];
      *(float4*)(bb+0)  = *(const float4*)&Bc[j+u][0];
      *(float4*)(bb+4)  = *(const float4*)&Bc[j+u][4];
      *(float4*)(bb+8)  = *(const float4*)&Bc[j+u][8];
      *(float4*)(bb+12) = *(const float4*)&Bc[j+u][12];
      *(float4*)(ccv+0)  = *(const float4*)&Cc[j+u][0];
      *(float4*)(ccv+4)  = *(const float4*)&Cc[j+u][4];
      *(float4*)(ccv+8)  = *(const float4*)&Cc[j+u][8];
      *(float4*)(ccv+12) = *(const float4*)&Cc[j+u][12];
      float earr[NS];
      if (pw) {
        float e1 = fexp2(a20*dt);
        float e = e1; earr[0] = e;
#pragma unroll
        for (int n = 1; n < NS; ++n) { e *= e1; earr[n] = e; }
      } else {
#pragma unroll
        for (int n = 0; n < NS; ++n) earr[n] = fexp2(A2[n]*dt);
      }
      float yv = 0.f;
#pragma unroll
      for (int n = 0; n < NS; ++n) {
        h[n] = fmaf(h[n], earr[n], dx*bb[n]);
        yv = fmaf(h[n], ccv[n], yv);
      }
      yv = fmaf(xc, Dd, yv);
      float zv = bf2f(zu);
      sp[(size_t)(j+u)*DI] = f2bf(yv * fsilu(zv));
    }
  }
}

// ---------------------------------------------------------------------------
// K6: MFMA out_proj. (sF + rev(sB)) @ W^T == [sF | rev(sB)] @ [W;W]^T.
// Epilogue: +residual, LN2, transposed store.
// ---------------------------------------------------------------------------
__global__ __launch_bounds__(512) void k_out(
  const unsigned short* __restrict__ s2bf,  // [2][NB][LSEQ][DI] bf16
  const unsigned short* __restrict__ wopbf, // [DM][DI] bf16
  const float* __restrict__ x, const float* __restrict__ ln2w, const float* __restrict__ ln2b,
  float* __restrict__ out)
{
  __shared__ char lds[65536];
  const int tid = threadIdx.x;
  const int m0 = blockIdx.x*64;
  const int b = m0 >> 13, l0 = m0 & (LSEQ-1);
  const unsigned short* sF = s2bf + (size_t)b*LSEQ*DI;
  const unsigned short* sB = s2bf + (size_t)(NB + b)*LSEQ*DI;
#pragma unroll
  for (int i = 0; i < 8; ++i) {
    int u = tid + i*512;
    int row = u >> 6, c = u & 63;
    int l = l0 + row;
    const unsigned short* src = (c < 32) ? (sF + (size_t)l*DI + c*8)
                                         : (sB + (size_t)(LSEQ-1-l)*DI + (c-32)*8);
    *(uint4*)(lds + row*1024 + ((c ^ (row & 7))<<4)) = *(const uint4*)src;
  }
  const int wid = tid >> 6;
  const int wr = wid >> 2, wc = wid & 3;
  const int lane = tid & 63, lr = lane & 15, kg = lane >> 4;
  bf16x8 wf[2][8];
#pragma unroll
  for (int nt = 0; nt < 2; ++nt) {
    int n = wc*32 + nt*16 + lr;
#pragma unroll
    for (int kt = 0; kt < 8; ++kt)
      wf[nt][kt] = *(const bf16x8*)(wopbf + n*DI + kt*32 + kg*8);
  }
  __syncthreads();
  f32x4 acc[2][2];
#pragma unroll
  for (int mt = 0; mt < 2; ++mt)
#pragma unroll
    for (int nt = 0; nt < 2; ++nt) acc[mt][nt] = 0.f;
#pragma unroll
  for (int kt2 = 0; kt2 < 16; ++kt2) {
#pragma unroll
    for (int mt = 0; mt < 2; ++mt) {
      int row = wr*32 + mt*16 + lr;
      int slot = (kt2*4 + kg) ^ (row & 7);
      bf16x8 af = *(const bf16x8*)(lds + row*1024 + (slot<<4));
#pragma unroll
      for (int nt = 0; nt < 2; ++nt)
        acc[mt][nt] = __builtin_amdgcn_mfma_f32_16x16x32_bf16(af, wf[nt][kt2 & 7], acc[mt][nt], 0,0,0);
    }
  }
  __syncthreads();
  float* smem = (float*)lds;
  const int RP = 133;
  float* mS = smem + 64*RP;
  float* rS = mS + 64;
  const float* xb = x + b*DM*LSEQ + l0;
#pragma unroll
  for (int mt = 0; mt < 2; ++mt) {
    int mbase = wr*32 + mt*16 + kg*4;
#pragma unroll
    for (int nt = 0; nt < 2; ++nt) {
      int n = wc*32 + nt*16 + lr;
      float4 rx = *(const float4*)&xb[n*LSEQ + mbase];
      smem[(mbase+0)*RP + n] = acc[mt][nt][0] + rx.x;
      smem[(mbase+1)*RP + n] = acc[mt][nt][1] + rx.y;
      smem[(mbase+2)*RP + n] = acc[mt][nt][2] + rx.z;
      smem[(mbase+3)*RP + n] = acc[mt][nt][3] + rx.w;
    }
  }
  __syncthreads();
  {
    int row = tid >> 3, p = tid & 7;
    float s = 0.f, q = 0.f;
#pragma unroll
    for (int jj = 0; jj < 16; ++jj) {
      float v = smem[row*RP + p*16 + jj];
      s += v; q += v*v;
    }
    s += __shfl_xor(s,1); s += __shfl_xor(s,2); s += __shfl_xor(s,4);
    q += __shfl_xor(q,1); q += __shfl_xor(q,2); q += __shfl_xor(q,4);
    if (p == 0) {
      float m = s*(1.f/DM);
      float var = q*(1.f/DM) - m*m;
      mS[row] = m; rS[row] = rsqrtf(var + 1e-5f);
    }
  }
  __syncthreads();
  float* ob = out + b*DM*LSEQ + l0;
#pragma unroll
  for (int i = 0; i < 16; ++i) {
    int idx = tid + i*512;
    int col = idx >> 6, l = idx & 63;
    float v = (smem[l*RP + col] - mS[l])*rS[l]*ln2w[col] + ln2b[col];
    ob[col*LSEQ + l] = v;
  }
}

// ---------------------------------------------------------------------------
extern "C" void kernel_launch(void* const* d_in, const int* in_sizes, int n_in,
                              void* d_out, int out_size, void* d_ws, size_t ws_size,
                              hipStream_t stream)
{
  (void)in_sizes; (void)n_in; (void)out_size; (void)ws_size;
  const float* x     = (const float*)d_in[0];
  const float* ln1w  = (const float*)d_in[1];
  const float* ln1b  = (const float*)d_in[2];
  const float* ln2w  = (const float*)d_in[3];
  const float* ln2b  = (const float*)d_in[4];
  const float* wip   = (const float*)d_in[5];
  const float* wop   = (const float*)d_in[6];
  const float* cwf   = (const float*)d_in[7];
  const float* cbf   = (const float*)d_in[8];
  const float* xwf   = (const float*)d_in[9];
  const float* dtwf  = (const float*)d_in[10];
  const float* dtbf  = (const float*)d_in[11];
  const float* alogf = (const float*)d_in[12];
  const float* Dskf  = (const float*)d_in[13];
  const float* cwb   = (const float*)d_in[14];
  const float* cbb   = (const float*)d_in[15];
  const float* xwb   = (const float*)d_in[16];
  const float* dtwb  = (const float*)d_in[17];
  const float* dtbb  = (const float*)d_in[18];
  const float* alogb = (const float*)d_in[19];
  const float* Dskb  = (const float*)d_in[20];

  // workspace layout (float units)
  float* ws    = (float*)d_ws;
  float* xibF  = ws;                    //  4,194,304 (xib: 8.4M ushort)
  float* zzbF  = xibF  + 4194304;       //  4,194,304 (zzb: 8.4M ushort)
  float* Bm    = zzbF  + 4194304;       //  1,048,576
  float* Cm    = Bm    + 1048576;       //  1,048,576
  float* s2F   = Cm    + 1048576;       //  8,388,608 (s2bf: 16.8M ushort)
  float* xdtF  = s2F   + 8388608;       // 16,777,216 (packed uint xc|dt)
  float* hlocF = xdtF  + 16777216;      //  4,194,304 (bf16: 8.4M ushort)
  float* sumdt = hlocF + 4194304;       //    524,288
  float* xwbfF = sumdt + 524288;        //     12,288 (24,576 bf16)
  float* wopbfF= xwbfF + 12288;         //     16,384 (32,768 bf16)
  float* out   = (float*)d_out;
  // aliases in s2F region (fully rewritten by k_scan_out each call):
  unsigned short* xnbf  = (unsigned short*)s2F;             // 4,194,304 ush
  unsigned short* wipbf = (unsigned short*)(s2F + 2097152); //    65,536 ush
  unsigned short* s2bf  = (unsigned short*)s2F;
  unsigned short* xib   = (unsigned short*)xibF;
  unsigned short* zzb   = (unsigned short*)zzbF;
  unsigned int*   xdt   = (unsigned int*)xdtF;
  unsigned short* hloc  = (unsigned short*)hlocF;
  unsigned short* xwbf  = (unsigned short*)xwbfF;
  unsigned short* wopbf = (unsigned short*)wopbfF;

  k_prep_w<<<480, 256, 0, stream>>>(wip, wipbf, xwf, xwb, xwbf, wop, wopbf);
  k_ln<<<512, 256, 0, stream>>>(x, ln1w, ln1b, xnbf);
  k_gemm_in<<<dim3(512,8), 256, 0, stream>>>(xnbf, wipbf, xib, zzb);
  k_conv_xproj<<<1024, 256, 0, stream>>>(xib, cwf,cbf,cwb,cbb, xwbf,
                                         dtwf,dtbf,dtwb,dtbb, Bm, Cm, xdt);
  k_scan_local<<<2048, 256, 0, stream>>>(xdt, Bm, alogf, alogb, hloc, sumdt);
  k_prefix<<<512, 64, 0, stream>>>(hloc, sumdt, alogf, alogb);
  k_scan_out<<<2048, 256, 0, stream>>>(xdt, zzb, Bm, Cm, hloc,
                                       alogf, alogb, Dskf, Dskb, s2bf);
  k_out<<<512, 512, 0, stream>>>(s2bf, wopbf, x, ln2w, ln2b, out);
}

// Round 9
// 153.582 us; speedup vs baseline: 2.4916x; 1.0885x over previous
//
#include <hip/hip_runtime.h>

// MambaLayer bidirectional selective-scan (bf16 MFMA GEMMs, packed xc/dt scan,
// v_pk_fma_f32 packed-fp32 state math in the scans).
// Shapes: B=4, L=8192, d_model=128, d_inner=256, d_state=16, dt_rank=8.
#define NB   4
#define LSEQ 8192
#define DM   128
#define DI   256
#define NS   16
#define RK   8
#define NCH  256          // chunks over L
#define LC   32           // L / NCH
#define MTOT (NB*LSEQ)
#define LOG2E 1.44269504088896340736f
#define LN2f  0.69314718055994530942f

#if __has_builtin(__builtin_amdgcn_exp2f)
__device__ __forceinline__ float fexp2(float x){ return __builtin_amdgcn_exp2f(x); }
#else
__device__ __forceinline__ float fexp2(float x){ return exp2f(x); }
#endif
#if __has_builtin(__builtin_amdgcn_logf)
__device__ __forceinline__ float flog2(float x){ return __builtin_amdgcn_logf(x); }
#else
__device__ __forceinline__ float flog2(float x){ return log2f(x); }
#endif
#if __has_builtin(__builtin_amdgcn_rcpf)
__device__ __forceinline__ float frcp(float x){ return __builtin_amdgcn_rcpf(x); }
#else
__device__ __forceinline__ float frcp(float x){ return 1.f/x; }
#endif
__device__ __forceinline__ float fexpn(float x){ return fexp2(x*LOG2E); }
__device__ __forceinline__ float fsilu(float x){ return x*frcp(1.f + fexpn(-x)); }
__device__ __forceinline__ float fsoftplus(float x){
  return fmaxf(x,0.f) + flog2(1.f + fexpn(-fabsf(x)))*LN2f;
}

__device__ __forceinline__ unsigned short f2bf(float v){
  unsigned int u = __float_as_uint(v);
  return (unsigned short)((u + 0x7FFFu + ((u >> 16) & 1u)) >> 16);
}
__device__ __forceinline__ float bf2f(unsigned short h){
  return __uint_as_float(((unsigned int)h) << 16);
}

typedef __attribute__((ext_vector_type(8))) short bf16x8;
typedef __attribute__((ext_vector_type(4))) float f32x4;
typedef __attribute__((ext_vector_type(2))) float f32x2;

#if __has_builtin(__builtin_elementwise_fma)
__device__ __forceinline__ f32x2 pkfma(f32x2 a, f32x2 b, f32x2 c){ return __builtin_elementwise_fma(a,b,c); }
#else
__device__ __forceinline__ f32x2 pkfma(f32x2 a, f32x2 b, f32x2 c){ return a*b + c; }
#endif

// ---------------------------------------------------------------------------
// K0: weights -> bf16: in_proj [512][128]; x_proj padded [2][48][256];
// out_proj [128][256].
// ---------------------------------------------------------------------------
__global__ __launch_bounds__(256) void k_prep_w(
    const float* __restrict__ wip, unsigned short* __restrict__ wipbf,
    const float* __restrict__ xwf, const float* __restrict__ xwb, unsigned short* __restrict__ xwbf,
    const float* __restrict__ wop, unsigned short* __restrict__ wopbf)
{
  int i = blockIdx.x*256 + threadIdx.x;      // 0..122879
  if (i < 65536) {
    wipbf[i] = f2bf(wip[i]);
  } else if (i < 90112) {
    int j = i - 65536;                       // 0..24575
    int dirw = j / 12288;
    int rem = j - dirw*12288;
    int row = rem >> 8, k = rem & 255;
    const float* src = dirw ? xwb : xwf;
    xwbf[j] = (row < 40) ? f2bf(src[row*256 + k]) : (unsigned short)0;
  } else {
    int j = i - 90112;                       // 0..32767
    wopbf[j] = f2bf(wop[j]);
  }
}

// ---------------------------------------------------------------------------
// K1a: LN1 -> xn bf16 [MTOT][128]. Reads x [B,128,L] coalesced.
// ---------------------------------------------------------------------------
__global__ __launch_bounds__(256) void k_ln(
    const float* __restrict__ x, const float* __restrict__ ln1w, const float* __restrict__ ln1b,
    unsigned short* __restrict__ xnbf)
{
  __shared__ float a_s[DM][65];
  __shared__ float mS[64], rS[64];
  const int tid = threadIdx.x;
  const int m0 = blockIdx.x * 64;
  const int b = m0 >> 13, l0 = m0 & (LSEQ-1);
  const float* xb = x + b*DM*LSEQ;
#pragma unroll
  for (int i = 0; i < 32; ++i) {
    int idx = tid + i*256;
    int d = idx >> 6, l = idx & 63;
    a_s[d][l] = xb[d*LSEQ + l0 + l];
  }
  __syncthreads();
  {
    int p = tid & 3, l = tid >> 2;
    float s = 0.f, q = 0.f;
#pragma unroll
    for (int jj = 0; jj < 32; ++jj) {
      float v = a_s[p + 4*jj][l];
      s += v; q += v*v;
    }
    s += __shfl_xor(s,1); s += __shfl_xor(s,2);
    q += __shfl_xor(q,1); q += __shfl_xor(q,2);
    float m = s*(1.f/DM);
    float var = q*(1.f/DM) - m*m;
    if (p == 0) { mS[l] = m; rS[l] = rsqrtf(var + 1e-5f); }
  }
  __syncthreads();
#pragma unroll
  for (int i = 0; i < 32; ++i) {
    int idx = tid + i*256;
    int l = idx >> 7, d = idx & 127;
    float v = (a_s[d][l] - mS[l])*rS[l]*ln1w[d] + ln1b[d];
    xnbf[(m0+l)*DM + d] = f2bf(v);
  }
}

// ---------------------------------------------------------------------------
// K1b: in_proj GEMM via bf16 MFMA (single plane). Tile 64x64, K=128.
// n0<256 -> xib (bf16); n0>=256 -> zzb = silu(z) bf16 (silu hoisted here,
// where the VALU is idle under MFMA, out of the VALU-bound scan).
// ---------------------------------------------------------------------------
__global__ __launch_bounds__(256) void k_gemm_in(
    const unsigned short* __restrict__ xnbf, const unsigned short* __restrict__ wipbf,
    unsigned short* __restrict__ xib, unsigned short* __restrict__ zzb)
{
  __shared__ char lds[32768];                 // 2 planes x 16KB (64 rows x 128 bf16)
  const int tid = threadIdx.x;
  const int m0 = blockIdx.x * 64;
  const int n0 = blockIdx.y * 64;
  const unsigned short* srcs[2] = { xnbf + m0*DM, wipbf + n0*DM };
#pragma unroll
  for (int p = 0; p < 2; ++p) {
#pragma unroll
    for (int i = 0; i < 4; ++i) {
      int u = tid + i*256;                    // 16B unit within plane
      int row = u >> 4, c = u & 15;
      int dstu = p*1024 + row*16 + (c ^ (row & 7));
      *(uint4*)(lds + dstu*16) = *(const uint4*)(srcs[p] + row*DM + c*8);
    }
  }
  __syncthreads();
  const int wid = tid >> 6, lane = tid & 63;
  const int m0w = (wid & 1)*32, n0w = (wid >> 1)*32;
  const int lr = lane & 15, kg = lane >> 4;
  bf16x8 af[2][4], bfv[2][4];
#pragma unroll
  for (int mi = 0; mi < 2; ++mi) {
    int row = m0w + mi*16 + lr;
#pragma unroll
    for (int kk = 0; kk < 4; ++kk) {
      int slot = (kk*4 + kg) ^ (row & 7);
      af[mi][kk] = *(const bf16x8*)(lds + row*256 + slot*16);
    }
  }
#pragma unroll
  for (int nj = 0; nj < 2; ++nj) {
    int row = n0w + nj*16 + lr;
#pragma unroll
    for (int kk = 0; kk < 4; ++kk) {
      int slot = (kk*4 + kg) ^ (row & 7);
      bfv[nj][kk] = *(const bf16x8*)(lds + 16384 + row*256 + slot*16);
    }
  }
  f32x4 acc[2][2];
#pragma unroll
  for (int mi = 0; mi < 2; ++mi)
#pragma unroll
    for (int nj = 0; nj < 2; ++nj) acc[mi][nj] = 0.f;
#pragma unroll
  for (int kk = 0; kk < 4; ++kk)
#pragma unroll
    for (int mi = 0; mi < 2; ++mi)
#pragma unroll
      for (int nj = 0; nj < 2; ++nj)
        acc[mi][nj] = __builtin_amdgcn_mfma_f32_16x16x32_bf16(af[mi][kk], bfv[nj][kk], acc[mi][nj], 0,0,0);
  // C/D: col = lane&15 (n), row = (lane>>4)*4 + r (m)
  if (n0 < 256) {
#pragma unroll
    for (int mi = 0; mi < 2; ++mi)
#pragma unroll
      for (int nj = 0; nj < 2; ++nj) {
        int n_g = n0 + n0w + nj*16 + lr;
#pragma unroll
        for (int r = 0; r < 4; ++r) {
          int m_g = m0 + m0w + mi*16 + kg*4 + r;
          xib[(size_t)m_g*DI + n_g] = f2bf(acc[mi][nj][r]);
        }
      }
  } else {
#pragma unroll
    for (int mi = 0; mi < 2; ++mi)
#pragma unroll
      for (int nj = 0; nj < 2; ++nj) {
        int n_g = (n0 - 256) + n0w + nj*16 + lr;
#pragma unroll
        for (int r = 0; r < 4; ++r) {
          int m_g = m0 + m0w + mi*16 + kg*4 + r;
          zzb[(size_t)m_g*DI + n_g] = f2bf(fsilu(acc[mi][nj][r]));
        }
      }
  }
}

// ---------------------------------------------------------------------------
// K2: conv4+SiLU -> xc into LDS A-plane (phase1); x_proj MFMA (phase2,
// dt_r -> LDS, B/C -> global); phase3: dt = softplus(dt_r@dtw+b), read xc
// back from LDS, ONE packed 4B store per (l,d): lo = xc bf16, hi = dt bf16.
// ---------------------------------------------------------------------------
__global__ __launch_bounds__(256) void k_conv_xproj(
  const unsigned short* __restrict__ xib,
  const float* __restrict__ cwf, const float* __restrict__ cbf,
  const float* __restrict__ cwb, const float* __restrict__ cbb,
  const unsigned short* __restrict__ xwbf,   // [2][48][256] bf16
  const float* __restrict__ dtwf, const float* __restrict__ dtbf,
  const float* __restrict__ dtwb, const float* __restrict__ dtbb,
  float* __restrict__ Bm, float* __restrict__ Cm,
  unsigned int* __restrict__ xdt)
{
  __shared__ char lds[57344];   // A: 64x512B @0; W: 48x512B @32768
  __shared__ float dtr_s[64][8];
  const int tid = threadIdx.x, bid = blockIdx.x;
  const int lt = bid & (LSEQ/64 - 1);
  const int b  = (bid >> 7) & 3;
  const int dir = bid >> 9;
  const int l0 = lt*64;
  const int db = dir*NB + b;
  const unsigned short* xwp = xwbf + dir*48*256;
#pragma unroll
  for (int i = 0; i < 6; ++i) {
    int u = tid + i*256;
    int row = u >> 5, s = u & 31;
    *(uint4*)(lds + 32768 + row*512 + ((s ^ (row & 7))<<4)) =
        *(const uint4*)(xwp + row*256 + s*8);
  }
  const float* cw  = dir ? cwb : cwf;
  const float* cbp = dir ? cbb : cbf;
  const int d = tid;
  const float w0 = cw[d*4+0], w1 = cw[d*4+1], w2 = cw[d*4+2], w3 = cw[d*4+3];
  const float bias = cbp[d];
  const int g0 = dir ? (LSEQ-1-l0) : l0;
  const int stp = dir ? -DI : DI;
  const unsigned short* xp = xib + (size_t)(b*LSEQ)*DI + d + (size_t)g0*DI;
  float h3 = 0.f, h2 = 0.f, h1 = 0.f;
  if (l0 >= 3) { h3 = bf2f(xp[-3*stp]); h2 = bf2f(xp[-2*stp]); h1 = bf2f(xp[-1*stp]); }
  float r0 = bf2f(xp[0]), r1 = bf2f(xp[stp]), r2 = bf2f(xp[2*stp]), r3 = bf2f(xp[3*stp]);
  for (int j = 0; j < 64; j += 4) {
    float v0 = r0, v1 = r1, v2 = r2, v3 = r3;
    if (j + 4 < 64) {
      const unsigned short* q = xp + (j+4)*stp;
      r0 = bf2f(q[0]); r1 = bf2f(q[stp]); r2 = bf2f(q[2*stp]); r3 = bf2f(q[3*stp]);
    }
#pragma unroll
    for (int u = 0; u < 4; ++u) {
      float vv = (u==0)?v0:(u==1)?v1:(u==2)?v2:v3;
      float a = bias + w0*h3 + w1*h2 + w2*h1 + w3*vv;
      int row = j + u;
      *(unsigned short*)(lds + row*512 + ((((d>>3) ^ (row&7))<<4) + ((d&7)<<1))) = f2bf(fsilu(a));
      h3 = h2; h2 = h1; h1 = vv;
    }
  }
  __syncthreads();
  // ---- phase 2: MFMA [64 rows] x [48 cols], K=256 ----
  const int wid = tid >> 6, lane = tid & 63;
  const int lr = lane & 15, kg = lane >> 4;
  const int arow = wid*16 + lr;
  f32x4 acc[3];
#pragma unroll
  for (int j = 0; j < 3; ++j) acc[j] = 0.f;
#pragma unroll
  for (int t = 0; t < 8; ++t) {
    bf16x8 afv = *(const bf16x8*)(lds + arow*512 + (((t*4+kg) ^ (arow&7))<<4));
#pragma unroll
    for (int j = 0; j < 3; ++j) {
      int wrow = j*16 + lr;
      bf16x8 bfr = *(const bf16x8*)(lds + 32768 + wrow*512 + (((t*4+kg) ^ (wrow&7))<<4));
      acc[j] = __builtin_amdgcn_mfma_f32_16x16x32_bf16(afv, bfr, acc[j], 0,0,0);
    }
  }
  const int base_l = (db*LSEQ + l0) + wid*16 + kg*4;
  const int rloc = wid*16 + kg*4;
#pragma unroll
  for (int j = 0; j < 3; ++j) {
    int col = j*16 + lr;
#pragma unroll
    for (int r = 0; r < 4; ++r) {
      float v = acc[j][r];
      if (col < 8)       dtr_s[rloc + r][col] = v;
      else if (col < 24) Bm[(size_t)(base_l + r)*NS + col - 8] = v;
      else if (col < 40) Cm[(size_t)(base_l + r)*NS + col - 24] = v;
    }
  }
  __syncthreads();
  // ---- phase 3: dt = softplus(dtr @ dtw[d] + b[d]); pack with xc (from LDS)
  // into ONE coalesced uint store per row.
  const float* dtw = dir ? dtwb : dtwf;
  const float* dtbp= dir ? dtbb : dtbf;
  float dwv[8];
  *(float4*)(dwv+0) = *(const float4*)&dtw[d*RK];
  *(float4*)(dwv+4) = *(const float4*)&dtw[d*RK+4];
  const float dtbv = dtbp[d];
  unsigned int* xdtp = xdt + (size_t)(db*LSEQ + l0)*DI + d;
  for (int row = 0; row < 64; ++row) {
    float sd = dtbv;
#pragma unroll
    for (int r = 0; r < RK; ++r) sd = fmaf(dtr_s[row][r], dwv[r], sd);
    unsigned short dtb = f2bf(fsoftplus(sd));
    unsigned short xcb = *(const unsigned short*)(lds + row*512 + ((((d>>3) ^ (row&7))<<4) + ((d&7)<<1)));
    xdtp[(size_t)row*DI] = (unsigned int)xcb | ((unsigned int)dtb << 16);
  }
}

// ---------------------------------------------------------------------------
// K3: chunk-local scan from h=0 -> h_local (bf16) + sum(dt).
// Packed-fp32 state math (f32x2 -> v_pk_fma_f32).
// ---------------------------------------------------------------------------
__global__ __launch_bounds__(256) void k_scan_local(
  const unsigned int* __restrict__ xdt, const float* __restrict__ Bm,
  const float* __restrict__ alogf, const float* __restrict__ alogb,
  unsigned short* __restrict__ hloc, float* __restrict__ sumdt)
{
  __shared__ float Bc[LC][NS];
  const int tid = threadIdx.x, bid = blockIdx.x;
  const int c = bid & (NCH-1), b = (bid>>8)&3, dir = bid>>10;
  const int db = dir*NB + b;
  const int l0 = c*LC;
  for (int i = tid; i < LC*NS; i += 256) (&Bc[0][0])[i] = Bm[(size_t)(db*LSEQ + l0)*NS + i];
  const float* alog = dir ? alogb : alogf;
  const int d = tid;
  float A2[NS];
#pragma unroll
  for (int n = 0; n < NS; ++n) A2[n] = -fexpn(alog[d*NS+n]) * LOG2E;
  const float a20 = A2[0];
  bool pw = true;
#pragma unroll
  for (int n = 1; n < NS; ++n) pw = pw && (fabsf(A2[n] - (n+1)*a20) <= 1e-3f*fabsf(A2[n]));
  f32x2 h2[8];
#pragma unroll
  for (int k = 0; k < 8; ++k) h2[k] = 0.f;
  const unsigned int* xp = xdt + (size_t)(db*LSEQ + l0)*DI + d;
  unsigned int u0 = xp[0], u1 = xp[DI], u2 = xp[2*DI], u3 = xp[3*DI];
  __syncthreads();
  float sac = 0.f;
  for (int j = 0; j < LC; j += 4) {
    unsigned int w0=u0, w1=u1, w2=u2, w3=u3;
    if (j + 4 < LC) {
      const unsigned int* q = xp + (size_t)(j+4)*DI;
      u0=q[0]; u1=q[DI]; u2=q[2*DI]; u3=q[3*DI];
    }
#pragma unroll
    for (int u = 0; u < 4; ++u) {
      unsigned int uu = (u==0)?w0:(u==1)?w1:(u==2)?w2:w3;
      float xc = __uint_as_float(uu << 16);
      float dt = __uint_as_float(uu & 0xffff0000u);
      sac += dt;
      float dx = dt*xc;
      f32x2 e2[8];
      if (pw) {
        float e1 = fexp2(a20*dt);
        float es = e1*e1;
        f32x2 esq = {es, es};
        e2[0] = (f32x2){e1, es};
#pragma unroll
        for (int k = 1; k < 8; ++k) e2[k] = e2[k-1]*esq;
      } else {
#pragma unroll
        for (int k = 0; k < 8; ++k)
          e2[k] = (f32x2){fexp2(A2[2*k]*dt), fexp2(A2[2*k+1]*dt)};
      }
      const f32x2* bb2 = (const f32x2*)&Bc[j+u][0];
      f32x2 dx2 = {dx, dx};
#pragma unroll
      for (int k = 0; k < 8; ++k) h2[k] = pkfma(h2[k], e2[k], bb2[k]*dx2);
    }
  }
  // pack h -> bf16, 32B store
  unsigned int hp8[8];
#pragma unroll
  for (int k = 0; k < 8; ++k)
    hp8[k] = (unsigned int)f2bf(h2[k].x) | ((unsigned int)f2bf(h2[k].y) << 16);
  unsigned short* dst = hloc + ((size_t)(db*NCH + c)*DI + d)*NS;
  *(uint4*)(dst)   = *(uint4*)(hp8);
  *(uint4*)(dst+8) = *(uint4*)(hp8+4);
  sumdt[(size_t)(db*NCH + c)*DI + d] = sac;
}

// ---------------------------------------------------------------------------
// K4: sequential prefix over chunks (bf16 h, fp32 carry), 16-deep prefetch,
// IN-PLACE: hloc[c] becomes h_in[c].
// ---------------------------------------------------------------------------
__global__ __launch_bounds__(64) void k_prefix(
  unsigned short* __restrict__ hloc, const float* __restrict__ sumdt,
  const float* __restrict__ alogf, const float* __restrict__ alogb)
{
  const int gid = blockIdx.x*64 + threadIdx.x;   // 32768
  const int n = gid & 15;
  const int d = (gid >> 4) & 255;
  const int db = gid >> 12;
  const float* alog = (db >= NB) ? alogb : alogf;
  const float a2 = -fexpn(alog[d*NS+n]) * LOG2E;
  const int HS = DI*NS;                          // per-chunk stride (ushorts)
  unsigned short* hp = hloc + (size_t)db*NCH*HS + d*NS + n;
  const float* sp = sumdt + (size_t)db*NCH*DI + d;
  float hr = 0.f;
  float bl[16], bs[16];
#pragma unroll
  for (int j = 0; j < 16; ++j) { bl[j] = bf2f(hp[(size_t)j*HS]); bs[j] = sp[(size_t)j*DI]; }
  for (int blk = 0; blk < NCH/16; ++blk) {
    float nl[16], nsv[16];
    if (blk < NCH/16 - 1) {
#pragma unroll
      for (int j = 0; j < 16; ++j) {
        nl[j]  = bf2f(hp[(size_t)(blk*16+16+j)*HS]);
        nsv[j] = sp[(size_t)(blk*16+16+j)*DI];
      }
    }
#pragma unroll
    for (int j = 0; j < 16; ++j) {
      float hl = bl[j];
      hp[(size_t)(blk*16+j)*HS] = f2bf(hr);
      hr = fmaf(fexp2(a2*bs[j]), hr, hl);
    }
    if (blk < NCH/16 - 1) {
#pragma unroll
      for (int j = 0; j < 16; ++j) { bl[j] = nl[j]; bs[j] = nsv[j]; }
    }
  }
}

// ---------------------------------------------------------------------------
// K5: rescan from h_in producing y, + D-skip, * pre-silu'd z -> s (bf16).
// Packed-fp32 state math (f32x2 -> v_pk_fma_f32).
// ---------------------------------------------------------------------------
__global__ __launch_bounds__(256) void k_scan_out(
  const unsigned int* __restrict__ xdt, const unsigned short* __restrict__ zzb,
  const float* __restrict__ Bm, const float* __restrict__ Cm,
  const unsigned short* __restrict__ hinb,
  const float* __restrict__ alogf, const float* __restrict__ alogb,
  const float* __restrict__ Dskf, const float* __restrict__ Dskb,
  unsigned short* __restrict__ s2bf)
{
  __shared__ float Bc[LC][NS];
  __shared__ float Cc[LC][NS];
  const int tid = threadIdx.x, bid = blockIdx.x;
  const int c = bid & (NCH-1), b = (bid>>8)&3, dir = bid>>10;
  const int db = dir*NB + b;
  const int l0 = c*LC;
  for (int i = tid; i < LC*NS; i += 256) (&Bc[0][0])[i] = Bm[(size_t)(db*LSEQ + l0)*NS + i];
  for (int i = tid; i < LC*NS; i += 256) (&Cc[0][0])[i] = Cm[(size_t)(db*LSEQ + l0)*NS + i];
  const float* alog = dir ? alogb : alogf;
  const int d = tid;
  const float Dd = (dir ? Dskb : Dskf)[d];
  float A2[NS];
#pragma unroll
  for (int n = 0; n < NS; ++n) A2[n] = -fexpn(alog[d*NS+n]) * LOG2E;
  const float a20 = A2[0];
  bool pw = true;
#pragma unroll
  for (int n = 1; n < NS; ++n) pw = pw && (fabsf(A2[n] - (n+1)*a20) <= 1e-3f*fabsf(A2[n]));
  // h_in (bf16 -> fp32)
  f32x2 h2[8];
  {
    const unsigned short* hb = hinb + ((size_t)(db*NCH + c)*DI + d)*NS;
    uint4 p0 = *(const uint4*)(hb);
    uint4 p1 = *(const uint4*)(hb+8);
    unsigned int w[8] = {p0.x,p0.y,p0.z,p0.w,p1.x,p1.y,p1.z,p1.w};
#pragma unroll
    for (int k = 0; k < 8; ++k)
      h2[k] = (f32x2){__uint_as_float(w[k] << 16), __uint_as_float(w[k] & 0xffff0000u)};
  }
  const int g0 = dir ? (LSEQ-1-l0) : l0;
  const int stp = dir ? -DI : DI;
  const unsigned int* xp = xdt + (size_t)(db*LSEQ + l0)*DI + d;
  const unsigned short* zp = zzb + (size_t)(b*LSEQ + g0)*DI + d;
  unsigned short* sp = s2bf + (size_t)(db*LSEQ + l0)*DI + d;
  unsigned int u0 = xp[0], u1 = xp[DI], u2 = xp[2*DI], u3 = xp[3*DI];
  unsigned short z0 = zp[0], z1 = zp[stp], z2 = zp[2*stp], z3 = zp[3*stp];
  __syncthreads();
  for (int j = 0; j < LC; j += 4) {
    unsigned int w0=u0, w1=u1, w2=u2, w3=u3;
    unsigned short y0=z0, y1=z1, y2=z2, y3=z3;
    if (j + 4 < LC) {
      const unsigned int* q = xp + (size_t)(j+4)*DI;
      u0=q[0]; u1=q[DI]; u2=q[2*DI]; u3=q[3*DI];
      const unsigned short* qz = zp + (j+4)*stp;
      z0=qz[0]; z1=qz[stp]; z2=qz[2*stp]; z3=qz[3*stp];
    }
#pragma unroll
    for (int u = 0; u < 4; ++u) {
      unsigned int uu = (u==0)?w0:(u==1)?w1:(u==2)?w2:w3;
      unsigned short zu = (u==0)?y0:(u==1)?y1:(u==2)?y2:y3;
      float xc = __uint_as_float(uu << 16);
      float dt = __uint_as_float(uu & 0xffff0000u);
      float dx = dt*xc;
      f32x2 e2[8];
      if (pw) {
        float e1 = fexp2(a20*dt);
        float es = e1*e1;
        f32x2 esq = {es, es};
        e2[0] = (f32x2){e1, es};
#pragma unroll
        for (int k = 1; k < 8; ++k) e2[k] = e2[k-1]*esq;
      } else {
#pragma unroll
        for (int k = 0; k < 8; ++k)
          e2[k] = (f32x2){fexp2(A2[2*k]*dt), fexp2(A2[2*k+1]*dt)};
      }
      const f32x2* bb2 = (const f32x2*)&Bc[j+u][0];
      const f32x2* cc2 = (const f32x2*)&Cc[j+u][0];
      f32x2 dx2 = {dx, dx};
      f32x2 yv2 = {0.f, 0.f};
#pragma unroll
      for (int k = 0; k < 8; ++k) {
        h2[k] = pkfma(h2[k], e2[k], bb2[k]*dx2);
        yv2 = pkfma(h2[k], cc2[k], yv2);
      }
      float yv = yv2.x + yv2.y;
      yv = fmaf(xc, Dd, yv);
      sp[(size_t)(j+u)*DI] = f2bf(yv * bf2f(zu));   // z pre-silu'd in k_gemm_in
    }
  }
}

// ---------------------------------------------------------------------------
// K6: MFMA out_proj. (sF + rev(sB)) @ W^T == [sF | rev(sB)] @ [W;W]^T.
// Epilogue: +residual, LN2, transposed store.
// ---------------------------------------------------------------------------
__global__ __launch_bounds__(512) void k_out(
  const unsigned short* __restrict__ s2bf,  // [2][NB][LSEQ][DI] bf16
  const unsigned short* __restrict__ wopbf, // [DM][DI] bf16
  const float* __restrict__ x, const float* __restrict__ ln2w, const float* __restrict__ ln2b,
  float* __restrict__ out)
{
  __shared__ char lds[65536];
  const int tid = threadIdx.x;
  const int m0 = blockIdx.x*64;
  const int b = m0 >> 13, l0 = m0 & (LSEQ-1);
  const unsigned short* sF = s2bf + (size_t)b*LSEQ*DI;
  const unsigned short* sB = s2bf + (size_t)(NB + b)*LSEQ*DI;
#pragma unroll
  for (int i = 0; i < 8; ++i) {
    int u = tid + i*512;
    int row = u >> 6, c = u & 63;
    int l = l0 + row;
    const unsigned short* src = (c < 32) ? (sF + (size_t)l*DI + c*8)
                                         : (sB + (size_t)(LSEQ-1-l)*DI + (c-32)*8);
    *(uint4*)(lds + row*1024 + ((c ^ (row & 7))<<4)) = *(const uint4*)src;
  }
  const int wid = tid >> 6;
  const int wr = wid >> 2, wc = wid & 3;
  const int lane = tid & 63, lr = lane & 15, kg = lane >> 4;
  bf16x8 wf[2][8];
#pragma unroll
  for (int nt = 0; nt < 2; ++nt) {
    int n = wc*32 + nt*16 + lr;
#pragma unroll
    for (int kt = 0; kt < 8; ++kt)
      wf[nt][kt] = *(const bf16x8*)(wopbf + n*DI + kt*32 + kg*8);
  }
  __syncthreads();
  f32x4 acc[2][2];
#pragma unroll
  for (int mt = 0; mt < 2; ++mt)
#pragma unroll
    for (int nt = 0; nt < 2; ++nt) acc[mt][nt] = 0.f;
#pragma unroll
  for (int kt2 = 0; kt2 < 16; ++kt2) {
#pragma unroll
    for (int mt = 0; mt < 2; ++mt) {
      int row = wr*32 + mt*16 + lr;
      int slot = (kt2*4 + kg) ^ (row & 7);
      bf16x8 af = *(const bf16x8*)(lds + row*1024 + (slot<<4));
#pragma unroll
      for (int nt = 0; nt < 2; ++nt)
        acc[mt][nt] = __builtin_amdgcn_mfma_f32_16x16x32_bf16(af, wf[nt][kt2 & 7], acc[mt][nt], 0,0,0);
    }
  }
  __syncthreads();
  float* smem = (float*)lds;
  const int RP = 133;
  float* mS = smem + 64*RP;
  float* rS = mS + 64;
  const float* xb = x + b*DM*LSEQ + l0;
#pragma unroll
  for (int mt = 0; mt < 2; ++mt) {
    int mbase = wr*32 + mt*16 + kg*4;
#pragma unroll
    for (int nt = 0; nt < 2; ++nt) {
      int n = wc*32 + nt*16 + lr;
      float4 rx = *(const float4*)&xb[n*LSEQ + mbase];
      smem[(mbase+0)*RP + n] = acc[mt][nt][0] + rx.x;
      smem[(mbase+1)*RP + n] = acc[mt][nt][1] + rx.y;
      smem[(mbase+2)*RP + n] = acc[mt][nt][2] + rx.z;
      smem[(mbase+3)*RP + n] = acc[mt][nt][3] + rx.w;
    }
  }
  __syncthreads();
  {
    int row = tid >> 3, p = tid & 7;
    float s = 0.f, q = 0.f;
#pragma unroll
    for (int jj = 0; jj < 16; ++jj) {
      float v = smem[row*RP + p*16 + jj];
      s += v; q += v*v;
    }
    s += __shfl_xor(s,1); s += __shfl_xor(s,2); s += __shfl_xor(s,4);
    q += __shfl_xor(q,1); q += __shfl_xor(q,2); q += __shfl_xor(q,4);
    if (p == 0) {
      float m = s*(1.f/DM);
      float var = q*(1.f/DM) - m*m;
      mS[row] = m; rS[row] = rsqrtf(var + 1e-5f);
    }
  }
  __syncthreads();
  float* ob = out + b*DM*LSEQ + l0;
#pragma unroll
  for (int i = 0; i < 16; ++i) {
    int idx = tid + i*512;
    int col = idx >> 6, l = idx & 63;
    float v = (smem[l*RP + col] - mS[l])*rS[l]*ln2w[col] + ln2b[col];
    ob[col*LSEQ + l] = v;
  }
}

// ---------------------------------------------------------------------------
extern "C" void kernel_launch(void* const* d_in, const int* in_sizes, int n_in,
                              void* d_out, int out_size, void* d_ws, size_t ws_size,
                              hipStream_t stream)
{
  (void)in_sizes; (void)n_in; (void)out_size; (void)ws_size;
  const float* x     = (const float*)d_in[0];
  const float* ln1w  = (const float*)d_in[1];
  const float* ln1b  = (const float*)d_in[2];
  const float* ln2w  = (const float*)d_in[3];
  const float* ln2b  = (const float*)d_in[4];
  const float* wip   = (const float*)d_in[5];
  const float* wop   = (const float*)d_in[6];
  const float* cwf   = (const float*)d_in[7];
  const float* cbf   = (const float*)d_in[8];
  const float* xwf   = (const float*)d_in[9];
  const float* dtwf  = (const float*)d_in[10];
  const float* dtbf  = (const float*)d_in[11];
  const float* alogf = (const float*)d_in[12];
  const float* Dskf  = (const float*)d_in[13];
  const float* cwb   = (const float*)d_in[14];
  const float* cbb   = (const float*)d_in[15];
  const float* xwb   = (const float*)d_in[16];
  const float* dtwb  = (const float*)d_in[17];
  const float* dtbb  = (const float*)d_in[18];
  const float* alogb = (const float*)d_in[19];
  const float* Dskb  = (const float*)d_in[20];

  // workspace layout (float units)
  float* ws    = (float*)d_ws;
  float* xibF  = ws;                    //  4,194,304 (xib: 8.4M ushort)
  float* zzbF  = xibF  + 4194304;       //  4,194,304 (zzb: 8.4M ushort)
  float* Bm    = zzbF  + 4194304;       //  1,048,576
  float* Cm    = Bm    + 1048576;       //  1,048,576
  float* s2F   = Cm    + 1048576;       //  8,388,608 (s2bf: 16.8M ushort)
  float* xdtF  = s2F   + 8388608;       // 16,777,216 (packed uint xc|dt)
  float* hlocF = xdtF  + 16777216;      //  4,194,304 (bf16: 8.4M ushort)
  float* sumdt = hlocF + 4194304;       //    524,288
  float* xwbfF = sumdt + 524288;        //     12,288 (24,576 bf16)
  float* wopbfF= xwbfF + 12288;         //     16,384 (32,768 bf16)
  float* out   = (float*)d_out;
  // aliases in s2F region (fully rewritten by k_scan_out each call):
  unsigned short* xnbf  = (unsigned short*)s2F;             // 4,194,304 ush
  unsigned short* wipbf = (unsigned short*)(s2F + 2097152); //    65,536 ush
  unsigned short* s2bf  = (unsigned short*)s2F;
  unsigned short* xib   = (unsigned short*)xibF;
  unsigned short* zzb   = (unsigned short*)zzbF;
  unsigned int*   xdt   = (unsigned int*)xdtF;
  unsigned short* hloc  = (unsigned short*)hlocF;
  unsigned short* xwbf  = (unsigned short*)xwbfF;
  unsigned short* wopbf = (unsigned short*)wopbfF;

  k_prep_w<<<480, 256, 0, stream>>>(wip, wipbf, xwf, xwb, xwbf, wop, wopbf);
  k_ln<<<512, 256, 0, stream>>>(x, ln1w, ln1b, xnbf);
  k_gemm_in<<<dim3(512,8), 256, 0, stream>>>(xnbf, wipbf, xib, zzb);
  k_conv_xproj<<<1024, 256, 0, stream>>>(xib, cwf,cbf,cwb,cbb, xwbf,
                                         dtwf,dtbf,dtwb,dtbb, Bm, Cm, xdt);
  k_scan_local<<<2048, 256, 0, stream>>>(xdt, Bm, alogf, alogb, hloc, sumdt);
  k_prefix<<<512, 64, 0, stream>>>(hloc, sumdt, alogf, alogb);
  k_scan_out<<<2048, 256, 0, stream>>>(xdt, zzb, Bm, Cm, hloc,
                                       alogf, alogb, Dskf, Dskb, s2bf);
  k_out<<<512, 512, 0, stream>>>(s2bf, wopbf, x, ln2w, ln2b, out);
}